// Round 1
// baseline (1981.980 us; speedup 1.0000x reference)
//
#include <hip/hip_runtime.h>

#define B 8
#define C 512
#define CQ 64
#define H 96
#define W 96
#define HW (H*W)   // 9216

// ---------------------------------------------------------------------------
// Kernel 1: 1x1-conv projection GEMM.  out[m,n] = sum_k Wm[m,k]*X[b,k,n] + bias[m]
// X viewed as (B, C, HW).  transOut=0 -> out (B,M,HW); transOut=1 -> out (B,HW,M)
// ---------------------------------------------------------------------------
__global__ __launch_bounds__(256) void proj_gemm(
    const float* __restrict__ X, const float* __restrict__ Wm,
    const float* __restrict__ bias, float* __restrict__ out,
    int M, int transOut)
{
    int n0 = blockIdx.x * 64;
    int m0 = blockIdx.y * 64;
    int b  = blockIdx.z;
    __shared__ float Ws[32][65];
    __shared__ float Xs[32][64];
    int tid = threadIdx.x;
    int tx = tid & 15, ty = tid >> 4;
    float acc[4][4] = {};
    const float* Xb = X + (size_t)b * C * HW;

    for (int k0 = 0; k0 < C; k0 += 32) {
        for (int idx = tid; idx < 64*32; idx += 256) {
            int mm = idx >> 5, kk = idx & 31;
            Ws[kk][mm] = Wm[(size_t)(m0 + mm) * C + k0 + kk];
        }
        for (int idx = tid; idx < 32*64; idx += 256) {
            int kk = idx >> 6, nn = idx & 63;
            Xs[kk][nn] = Xb[(size_t)(k0 + kk) * HW + n0 + nn];
        }
        __syncthreads();
        #pragma unroll
        for (int kk = 0; kk < 32; ++kk) {
            float a[4], bb[4];
            #pragma unroll
            for (int i = 0; i < 4; ++i) a[i]  = Ws[kk][ty*4 + i];
            #pragma unroll
            for (int j = 0; j < 4; ++j) bb[j] = Xs[kk][tx*4 + j];
            #pragma unroll
            for (int i = 0; i < 4; ++i)
                #pragma unroll
                for (int j = 0; j < 4; ++j)
                    acc[i][j] += a[i] * bb[j];
        }
        __syncthreads();
    }

    if (!transOut) {
        #pragma unroll
        for (int i = 0; i < 4; ++i) {
            int m = m0 + ty*4 + i;
            float bv = bias[m];
            float4 r = make_float4(acc[i][0]+bv, acc[i][1]+bv, acc[i][2]+bv, acc[i][3]+bv);
            *(float4*)&out[((size_t)b*M + m)*HW + n0 + tx*4] = r;
        }
    } else {
        #pragma unroll
        for (int i = 0; i < 4; ++i) {
            int m = m0 + ty*4 + i;
            float bv = bias[m];
            #pragma unroll
            for (int j = 0; j < 4; ++j) {
                int n = n0 + tx*4 + j;
                out[((size_t)b*HW + n)*M + m] = acc[i][j] + bv;
            }
        }
    }
}

// ---------------------------------------------------------------------------
// Kernel 2: energies + joint softmax over 192 (96 column "H" + 96 row "W").
// One block (256 thr) per (b,h,w). q_t/k_t are (B,HW,64).
// attH written TRANSPOSED (B,W,H,96); attW written (B,H,W,96).
// ---------------------------------------------------------------------------
__global__ __launch_bounds__(256) void att_kernel(
    const float* __restrict__ q_t, const float* __restrict__ k_t,
    float* __restrict__ attH_t, float* __restrict__ attW)
{
    int idx = blockIdx.x;
    int b  = idx / HW;
    int hw = idx % HW;
    int h = hw / W, w = hw % W;
    __shared__ float qs[64];
    __shared__ float red[256];
    int tid = threadIdx.x;
    if (tid < 64) qs[tid] = q_t[((size_t)b*HW + hw)*64 + tid];
    __syncthreads();

    float e = -1e30f;
    if (tid < 192) {
        const float* kv;
        if (tid < 96) kv = &k_t[((size_t)b*HW + tid*W + w)*64];      // column: k[:, j, w]
        else          kv = &k_t[((size_t)b*HW + h*W + (tid-96))*64]; // row:    k[:, h, j]
        float s = 0.f;
        #pragma unroll
        for (int c = 0; c < 64; c += 4) {
            float4 kk = *(const float4*)&kv[c];
            s += qs[c]*kk.x + qs[c+1]*kk.y + qs[c+2]*kk.z + qs[c+3]*kk.w;
        }
        e = s;
    }
    red[tid] = e;
    __syncthreads();
    for (int s = 128; s > 0; s >>= 1) {
        if (tid < s) red[tid] = fmaxf(red[tid], red[tid+s]);
        __syncthreads();
    }
    float m = red[0];
    __syncthreads();
    float p = (tid < 192) ? __expf(e - m) : 0.f;
    red[tid] = p;
    __syncthreads();
    for (int s = 128; s > 0; s >>= 1) {
        if (tid < s) red[tid] += red[tid+s];
        __syncthreads();
    }
    float inv = 1.f / red[0];
    if (tid < 96)       attH_t[(((size_t)b*W + w)*H + h)*96 + tid]      = p * inv;
    else if (tid < 192) attW  [(((size_t)b*H + h)*W + w)*96 + (tid-96)] = p * inv;
}

// ---------------------------------------------------------------------------
// Kernel 3/5: row aggregation.  dst[b,c,r,s] = gamma * sum_j att[b,r,s,j] * vsrc[b,c,r,j]
// One block per (b, r).  dst may alias vsrc (in-place): each c-chunk is fully
// staged into LDS before being overwritten, and blocks touch disjoint r-slabs.
// ---------------------------------------------------------------------------
__global__ __launch_bounds__(256) void row_agg(
    const float* __restrict__ att,
    const float* vsrc, float* dst,
    const float* __restrict__ gamma)
{
    int r = blockIdx.x, b = blockIdx.y;
    __shared__ float sAtt[96][97];
    __shared__ float sV[64][97];
    int tid = threadIdx.x;
    float g = gamma[0];
    int wg = tid & 15;   // s-group (consecutive lanes -> consecutive s)
    int cg = tid >> 4;   // c-group

    const float* ab = &att[(((size_t)b*96 + r)*96)*96];
    for (int i = tid; i < 96*96; i += 256) sAtt[i/96][i%96] = ab[i];

    for (int c0 = 0; c0 < C; c0 += 64) {
        __syncthreads();
        for (int i = tid; i < 64*96; i += 256) {
            int cc = i/96, j = i%96;
            sV[cc][j] = vsrc[(((size_t)b*C + c0 + cc)*96 + r)*96 + j];
        }
        __syncthreads();
        float acc[4][6] = {};
        #pragma unroll 4
        for (int j = 0; j < 96; ++j) {
            float vv[4], av[6];
            #pragma unroll
            for (int ci = 0; ci < 4; ++ci) vv[ci] = sV[cg*4 + ci][j];
            #pragma unroll
            for (int si = 0; si < 6; ++si) av[si] = sAtt[wg + 16*si][j];
            #pragma unroll
            for (int ci = 0; ci < 4; ++ci)
                #pragma unroll
                for (int si = 0; si < 6; ++si)
                    acc[ci][si] += vv[ci] * av[si];
        }
        #pragma unroll
        for (int ci = 0; ci < 4; ++ci) {
            int c = c0 + cg*4 + ci;
            #pragma unroll
            for (int si = 0; si < 6; ++si) {
                int s = wg + 16*si;
                dst[(((size_t)b*C + c)*96 + r)*96 + s] = g * acc[ci][si];
            }
        }
    }
}

// ---------------------------------------------------------------------------
// Kernel 4: per-(b,c) in-place 96x96 transpose of v  ->  (B,C,W,H)
// ---------------------------------------------------------------------------
__global__ __launch_bounds__(256) void transpose_inplace(float* __restrict__ v)
{
    size_t base = (size_t)blockIdx.x * (96*96);
    __shared__ float t[96][97];
    int tid = threadIdx.x;
    for (int i = tid; i < 96*96; i += 256) t[i/96][i%96] = v[base + i];
    __syncthreads();
    for (int i = tid; i < 96*96; i += 256) v[base + i] = t[i%96][i/96];
}

// ---------------------------------------------------------------------------
// Kernel 6: out[b,c,h,w] += outT[b,c,w,h]
// ---------------------------------------------------------------------------
__global__ __launch_bounds__(256) void transpose_add(
    const float* __restrict__ outT, float* __restrict__ out)
{
    size_t base = (size_t)blockIdx.x * (96*96);
    __shared__ float t[96][97];
    int tid = threadIdx.x;
    for (int i = tid; i < 96*96; i += 256) t[i/96][i%96] = outT[base + i];
    __syncthreads();
    for (int i = tid; i < 96*96; i += 256) out[base + i] += t[i%96][i/96];
}

// ---------------------------------------------------------------------------
extern "C" void kernel_launch(void* const* d_in, const int* in_sizes, int n_in,
                              void* d_out, int out_size, void* d_ws, size_t ws_size,
                              hipStream_t stream)
{
    const float* x     = (const float*)d_in[0];
    const float* Wq    = (const float*)d_in[1];
    const float* bq    = (const float*)d_in[2];
    const float* Wk    = (const float*)d_in[3];
    const float* bk    = (const float*)d_in[4];
    const float* Wv    = (const float*)d_in[5];
    const float* bv    = (const float*)d_in[6];
    const float* gamma = (const float*)d_in[7];
    float* out = (float*)d_out;

    float* ws     = (float*)d_ws;
    float* q_t    = ws;                                  // (B,HW,64)   18.9 MB
    float* k_t    = q_t    + (size_t)B*HW*64;            // (B,HW,64)   18.9 MB
    float* v      = k_t    + (size_t)B*HW*64;            // (B,C,H,W)  151.0 MB
    float* attH_t = v      + (size_t)B*C*HW;             // (B,W,H,96)  28.3 MB
    float* attW   = attH_t + (size_t)B*HW*96;            // (B,H,W,96)  28.3 MB
    // total ws: ~234 MiB

    dim3 blk(256);

    // q, k, v projections
    proj_gemm<<<dim3(HW/64, 1,    B), blk, 0, stream>>>(x, Wq, bq, q_t, CQ, 1);
    proj_gemm<<<dim3(HW/64, 1,    B), blk, 0, stream>>>(x, Wk, bk, k_t, CQ, 1);
    proj_gemm<<<dim3(HW/64, C/64, B), blk, 0, stream>>>(x, Wv, bv, v,   C,  0);

    // energies + joint softmax
    att_kernel<<<dim3(B*HW), blk, 0, stream>>>(q_t, k_t, attH_t, attW);

    // out_W: block (b, r=h): out[b,c,h,w] = g * sum_j attW[b,h,w,j] * v[b,c,h,j]
    row_agg<<<dim3(96, B), blk, 0, stream>>>(attW, v, out, gamma);

    // transpose v in place: (B,C,H,W) -> (B,C,W,H)
    transpose_inplace<<<dim3(B*C), blk, 0, stream>>>(v);

    // out_H (transposed domain, IN PLACE into v's buffer):
    // v'[b,c,w,h] := g * sum_j attH[b,h,w,j] * v_orig[b,c,j,w]
    row_agg<<<dim3(96, B), blk, 0, stream>>>(attH_t, v, v, gamma);

    // out[b,c,h,w] += v'[b,c,w,h]
    transpose_add<<<dim3(B*C), blk, 0, stream>>>(v, out);
}

// Round 2
// 1186.627 us; speedup vs baseline: 1.6703x; 1.6703x over previous
//
#include <hip/hip_runtime.h>

#define B 8
#define C 512
#define H 96
#define W 96
#define HW (H*W)       // 9216
#define KD 512
#define NSP 9216

typedef __attribute__((ext_vector_type(8))) short bf16x8;
typedef __attribute__((ext_vector_type(4))) short short4v;
typedef __attribute__((ext_vector_type(4))) float f32x4;

static __device__ __forceinline__ unsigned short f2bf(float f) {
    unsigned u = __float_as_uint(f);
    return (unsigned short)((u + 0x7FFFu + ((u >> 16) & 1u)) >> 16);
}
static __device__ __forceinline__ float bf2f(unsigned short h) {
    return __uint_as_float(((unsigned)h) << 16);
}
// swizzled short-index within a [128 rows][32 k] bf16 tile (row stride 64B)
static __device__ __forceinline__ int tidx(int row, int kgrp) {
    return row * 32 + ((kgrp ^ ((row >> 1) & 3)) << 3);
}

// ---------------------------------------------------------------------------
// Split weights into bf16 hi/lo. Wqk = [Wq ; Wk] stacked (128 x 512).
// ---------------------------------------------------------------------------
__global__ __launch_bounds__(256) void split_w(
    const float* __restrict__ Wv, const float* __restrict__ Wq, const float* __restrict__ Wk,
    unsigned short* __restrict__ Wv_hi, unsigned short* __restrict__ Wv_lo,
    unsigned short* __restrict__ Wqk_hi, unsigned short* __restrict__ Wqk_lo)
{
    int i = blockIdx.x * 256 + threadIdx.x;
    if (i < C * C) {
        float f = Wv[i];
        unsigned short h = f2bf(f);
        Wv_hi[i] = h;
        Wv_lo[i] = f2bf(f - bf2f(h));
    }
    if (i < 128 * C) {
        int m = i / C, k = i % C;
        float f = (m < 64) ? Wq[m * C + k] : Wk[(m - 64) * C + k];
        unsigned short h = f2bf(f);
        Wqk_hi[i] = h;
        Wqk_lo[i] = f2bf(f - bf2f(h));
    }
}

// ---------------------------------------------------------------------------
// 3-pass split-bf16 MFMA GEMM.
// MODE 0 (v):  out0[b, m, n] = sum_k W[m,k] x[b,k,n] + bias0[m]      (B,C,HW)
// MODE 1 (qk): q_t[b, n, m] (m<64) / k_t[b, n, m-64]  = sum_k x[b,k,n] Wqk[m,k] + bias
// 128x128 tile, BK=32, 4 waves (2x2), each wave 64x64 via 4x4 16x16x32 frags.
// ---------------------------------------------------------------------------
template<int MODE>
__global__ __launch_bounds__(256, 2) void mfma_gemm(
    const float* __restrict__ x,
    const unsigned short* __restrict__ Wh,
    const unsigned short* __restrict__ Wl,
    const float* __restrict__ bias0,
    const float* __restrict__ bias1,
    float* __restrict__ out0,
    float* __restrict__ out1)
{
    __shared__ short smem[16384];                     // 32 KB
    const int X_HI = 0, X_LO = 4096, W_HI = 8192, W_LO = 12288;

    int tid = threadIdx.x;
    int n0 = blockIdx.x * 128;     // spatial tile
    int m0 = blockIdx.y * 128;     // weight-row tile
    int b  = blockIdx.z;

    int lane = tid & 63, wave = tid >> 6;
    int wr = wave >> 1, wc = wave & 1;
    int l15 = lane & 15, l4 = lane >> 4;

    // x staging: thread handles 4 n's x 4 k's
    int tn = tid & 31, tk = tid >> 5;
    int nloc = tn * 4, kloc = tk * 4;
    const float* xp = x + ((size_t)b * KD + kloc) * NSP + n0 + nloc;
    int kg = tk >> 1, khalf = tk & 1;

    f32x4 acc[4][4];
    #pragma unroll
    for (int i = 0; i < 4; ++i)
        #pragma unroll
        for (int j = 0; j < 4; ++j)
            acc[i][j] = (f32x4){0.f, 0.f, 0.f, 0.f};

    for (int k0 = 0; k0 < KD; k0 += 32) {
        // ---- stage x tile: load fp32, split to bf16 hi/lo, transpose to [n][k] ----
        float v4[4][4];
        #pragma unroll
        for (int kk = 0; kk < 4; ++kk) {
            float4 t = *(const float4*)(xp + (size_t)(k0 + kk) * NSP);
            v4[kk][0] = t.x; v4[kk][1] = t.y; v4[kk][2] = t.z; v4[kk][3] = t.w;
        }
        #pragma unroll
        for (int nn = 0; nn < 4; ++nn) {
            int n = nloc + nn;
            short4v hi, lo;
            #pragma unroll
            for (int kk = 0; kk < 4; ++kk) {
                float f = v4[kk][nn];
                unsigned short h = f2bf(f);
                hi[kk] = (short)h;
                lo[kk] = (short)f2bf(f - bf2f(h));
            }
            int base = tidx(n, kg) + khalf * 4;
            *(short4v*)&smem[X_HI + base] = hi;
            *(short4v*)&smem[X_LO + base] = lo;
        }
        // ---- stage W hi/lo tiles (already bf16 in global) ----
        #pragma unroll
        for (int it = 0; it < 4; ++it) {
            int gi = tid + it * 256;          // 1024 granules of 8 shorts
            int sel = gi >> 9;                // 0 = hi, 1 = lo
            int t = gi & 511;
            int row = t >> 2, kg2 = t & 3;
            const unsigned short* src = (sel ? Wl : Wh) + (size_t)(m0 + row) * KD + k0 + kg2 * 8;
            bf16x8 d = *(const bf16x8*)src;
            *(bf16x8*)&smem[(sel ? W_LO : W_HI) + tidx(row, kg2)] = d;
        }
        __syncthreads();

        const int A_HI = MODE ? X_HI : W_HI;
        const int A_LO = MODE ? X_LO : W_LO;
        const int B_HI = MODE ? W_HI : X_HI;
        const int B_LO = MODE ? W_LO : X_LO;

        bf16x8 af[4], bf_[4], bl_[4];
        #pragma unroll
        for (int f = 0; f < 4; ++f) {
            int ra = wr * 64 + f * 16 + l15;
            int rb = wc * 64 + f * 16 + l15;
            af[f]  = *(const bf16x8*)&smem[A_HI + tidx(ra, l4)];
            bf_[f] = *(const bf16x8*)&smem[B_HI + tidx(rb, l4)];
        }
        #pragma unroll
        for (int i = 0; i < 4; ++i)
            #pragma unroll
            for (int j = 0; j < 4; ++j)
                acc[i][j] = __builtin_amdgcn_mfma_f32_16x16x32_bf16(af[i], bf_[j], acc[i][j], 0, 0, 0);
        #pragma unroll
        for (int f = 0; f < 4; ++f) {
            int rb = wc * 64 + f * 16 + l15;
            bl_[f] = *(const bf16x8*)&smem[B_LO + tidx(rb, l4)];
        }
        #pragma unroll
        for (int i = 0; i < 4; ++i)
            #pragma unroll
            for (int j = 0; j < 4; ++j)
                acc[i][j] = __builtin_amdgcn_mfma_f32_16x16x32_bf16(af[i], bl_[j], acc[i][j], 0, 0, 0);
        #pragma unroll
        for (int f = 0; f < 4; ++f) {
            int ra = wr * 64 + f * 16 + l15;
            af[f] = *(const bf16x8*)&smem[A_LO + tidx(ra, l4)];   // reuse regs
        }
        #pragma unroll
        for (int i = 0; i < 4; ++i)
            #pragma unroll
            for (int j = 0; j < 4; ++j)
                acc[i][j] = __builtin_amdgcn_mfma_f32_16x16x32_bf16(af[i], bf_[j], acc[i][j], 0, 0, 0);
        __syncthreads();
    }

    // ---- epilogue ----
    if (MODE == 0) {
        #pragma unroll
        for (int i = 0; i < 4; ++i) {
            #pragma unroll
            for (int r = 0; r < 4; ++r) {
                int row = m0 + wr * 64 + i * 16 + l4 * 4 + r;
                float bv = bias0[row];
                #pragma unroll
                for (int j = 0; j < 4; ++j) {
                    int col = n0 + wc * 64 + j * 16 + l15;
                    out0[((size_t)b * C + row) * NSP + col] = acc[i][j][r] + bv;
                }
            }
        }
    } else {
        #pragma unroll
        for (int i = 0; i < 4; ++i) {
            #pragma unroll
            for (int r = 0; r < 4; ++r) {
                int sp = n0 + wr * 64 + i * 16 + l4 * 4 + r;   // spatial index
                #pragma unroll
                for (int j = 0; j < 4; ++j) {
                    int wcol = wc * 64 + j * 16 + l15;          // 0..127
                    float val = acc[i][j][r] + (wcol < 64 ? bias0[wcol] : bias1[wcol - 64]);
                    if (wcol < 64)
                        out0[((size_t)b * NSP + sp) * 64 + wcol] = val;
                    else
                        out1[((size_t)b * NSP + sp) * 64 + (wcol - 64)] = val;
                }
            }
        }
    }
}

// ---------------------------------------------------------------------------
// energies + joint softmax (unchanged from R1)
// ---------------------------------------------------------------------------
__global__ __launch_bounds__(256) void att_kernel(
    const float* __restrict__ q_t, const float* __restrict__ k_t,
    float* __restrict__ attH_t, float* __restrict__ attW)
{
    int idx = blockIdx.x;
    int b = idx / HW;
    int hw = idx % HW;
    int h = hw / W, w = hw % W;
    __shared__ float qs[64];
    __shared__ float red[256];
    int tid = threadIdx.x;
    if (tid < 64) qs[tid] = q_t[((size_t)b * HW + hw) * 64 + tid];
    __syncthreads();

    float e = -1e30f;
    if (tid < 192) {
        const float* kv;
        if (tid < 96) kv = &k_t[((size_t)b * HW + tid * W + w) * 64];
        else          kv = &k_t[((size_t)b * HW + h * W + (tid - 96)) * 64];
        float s = 0.f;
        #pragma unroll
        for (int c = 0; c < 64; c += 4) {
            float4 kk = *(const float4*)&kv[c];
            s += qs[c] * kk.x + qs[c + 1] * kk.y + qs[c + 2] * kk.z + qs[c + 3] * kk.w;
        }
        e = s;
    }
    red[tid] = e;
    __syncthreads();
    for (int s = 128; s > 0; s >>= 1) {
        if (tid < s) red[tid] = fmaxf(red[tid], red[tid + s]);
        __syncthreads();
    }
    float m = red[0];
    __syncthreads();
    float p = (tid < 192) ? __expf(e - m) : 0.f;
    red[tid] = p;
    __syncthreads();
    for (int s = 128; s > 0; s >>= 1) {
        if (tid < s) red[tid] += red[tid + s];
        __syncthreads();
    }
    float inv = 1.f / red[0];
    if (tid < 96)       attH_t[(((size_t)b * W + w) * H + h) * 96 + tid]        = p * inv;
    else if (tid < 192) attW[(((size_t)b * H + h) * W + w) * 96 + (tid - 96)]   = p * inv;
}

// ---------------------------------------------------------------------------
// row aggregation (unchanged from R1)
// ---------------------------------------------------------------------------
__global__ __launch_bounds__(256) void row_agg(
    const float* __restrict__ att,
    const float* vsrc, float* dst,
    const float* __restrict__ gamma)
{
    int r = blockIdx.x, b = blockIdx.y;
    __shared__ float sAtt[96][97];
    __shared__ float sV[64][97];
    int tid = threadIdx.x;
    float g = gamma[0];
    int wg = tid & 15;
    int cg = tid >> 4;

    const float* ab = &att[(((size_t)b * 96 + r) * 96) * 96];
    for (int i = tid; i < 96 * 96; i += 256) sAtt[i / 96][i % 96] = ab[i];

    for (int c0 = 0; c0 < C; c0 += 64) {
        __syncthreads();
        for (int i = tid; i < 64 * 96; i += 256) {
            int cc = i / 96, j = i % 96;
            sV[cc][j] = vsrc[(((size_t)b * C + c0 + cc) * 96 + r) * 96 + j];
        }
        __syncthreads();
        float acc[4][6] = {};
        #pragma unroll 4
        for (int j = 0; j < 96; ++j) {
            float vv[4], av[6];
            #pragma unroll
            for (int ci = 0; ci < 4; ++ci) vv[ci] = sV[cg * 4 + ci][j];
            #pragma unroll
            for (int si = 0; si < 6; ++si) av[si] = sAtt[wg + 16 * si][j];
            #pragma unroll
            for (int ci = 0; ci < 4; ++ci)
                #pragma unroll
                for (int si = 0; si < 6; ++si)
                    acc[ci][si] += vv[ci] * av[si];
        }
        #pragma unroll
        for (int ci = 0; ci < 4; ++ci) {
            int c = c0 + cg * 4 + ci;
            #pragma unroll
            for (int si = 0; si < 6; ++si) {
                int s = wg + 16 * si;
                dst[(((size_t)b * C + c) * 96 + r) * 96 + s] = g * acc[ci][si];
            }
        }
    }
}

__global__ __launch_bounds__(256) void transpose_inplace(float* __restrict__ v)
{
    size_t base = (size_t)blockIdx.x * (96 * 96);
    __shared__ float t[96][97];
    int tid = threadIdx.x;
    for (int i = tid; i < 96 * 96; i += 256) t[i / 96][i % 96] = v[base + i];
    __syncthreads();
    for (int i = tid; i < 96 * 96; i += 256) v[base + i] = t[i % 96][i / 96];
}

__global__ __launch_bounds__(256) void transpose_add(
    const float* __restrict__ outT, float* __restrict__ out)
{
    size_t base = (size_t)blockIdx.x * (96 * 96);
    __shared__ float t[96][97];
    int tid = threadIdx.x;
    for (int i = tid; i < 96 * 96; i += 256) t[i / 96][i % 96] = outT[base + i];
    __syncthreads();
    for (int i = tid; i < 96 * 96; i += 256) out[base + i] += t[i % 96][i / 96];
}

// ---------------------------------------------------------------------------
extern "C" void kernel_launch(void* const* d_in, const int* in_sizes, int n_in,
                              void* d_out, int out_size, void* d_ws, size_t ws_size,
                              hipStream_t stream)
{
    const float* x     = (const float*)d_in[0];
    const float* Wq    = (const float*)d_in[1];
    const float* bq    = (const float*)d_in[2];
    const float* Wk    = (const float*)d_in[3];
    const float* bk    = (const float*)d_in[4];
    const float* Wv    = (const float*)d_in[5];
    const float* bv    = (const float*)d_in[6];
    const float* gamma = (const float*)d_in[7];
    float* out = (float*)d_out;

    float* ws     = (float*)d_ws;
    float* q_t    = ws;                                  // (B,HW,64)
    float* k_t    = q_t    + (size_t)B*HW*64;            // (B,HW,64)
    float* v      = k_t    + (size_t)B*HW*64;            // (B,C,H,W)
    float* attH_t = v      + (size_t)B*C*HW;             // (B,W,H,96)
    float* attW   = attH_t + (size_t)B*HW*96;            // (B,H,W,96)

    // W splits live in the attH_t region (dead until att_kernel overwrites it)
    unsigned short* Wv_hi  = (unsigned short*)attH_t;
    unsigned short* Wv_lo  = Wv_hi  + (size_t)C*C;
    unsigned short* Wqk_hi = Wv_lo  + (size_t)C*C;
    unsigned short* Wqk_lo = Wqk_hi + (size_t)128*C;

    dim3 blk(256);

    split_w<<<dim3((C*C + 255)/256), blk, 0, stream>>>(Wv, Wq, Wk, Wv_hi, Wv_lo, Wqk_hi, Wqk_lo);

    // v projection: (B,C,HW) = Wv * x
    mfma_gemm<0><<<dim3(NSP/128, C/128, B), blk, 0, stream>>>(x, Wv_hi, Wv_lo, bv, nullptr, v, nullptr);
    // q,k projections (stacked, transposed output)
    mfma_gemm<1><<<dim3(NSP/128, 1, B), blk, 0, stream>>>(x, Wqk_hi, Wqk_lo, bq, bk, q_t, k_t);

    att_kernel<<<dim3(B*HW), blk, 0, stream>>>(q_t, k_t, attH_t, attW);
    row_agg<<<dim3(96, B), blk, 0, stream>>>(attW, v, out, gamma);
    transpose_inplace<<<dim3(B*C), blk, 0, stream>>>(v);
    row_agg<<<dim3(96, B), blk, 0, stream>>>(attH_t, v, v, gamma);
    transpose_add<<<dim3(B*C), blk, 0, stream>>>(v, out);
}

// Round 3
// 853.437 us; speedup vs baseline: 2.3223x; 1.3904x over previous
//
#include <hip/hip_runtime.h>

#define B 8
#define C 512
#define H 96
#define W 96
#define HW (H*W)       // 9216
#define KD 512
#define NSP 9216

typedef __attribute__((ext_vector_type(8))) short bf16x8;
typedef __attribute__((ext_vector_type(4))) short short4v;
typedef __attribute__((ext_vector_type(4))) float f32x4;

static __device__ __forceinline__ unsigned short f2bf(float f) {
    unsigned u = __float_as_uint(f);
    return (unsigned short)((u + 0x7FFFu + ((u >> 16) & 1u)) >> 16);
}
static __device__ __forceinline__ float bf2f(unsigned short h) {
    return __uint_as_float(((unsigned)h) << 16);
}
// swizzle for [rows][32-short] tiles (64B rows, 4 granules)
static __device__ __forceinline__ int tidx(int row, int kgrp) {
    return row * 32 + ((kgrp ^ ((row >> 1) & 3)) << 3);
}
// swizzle for [rows][64-short] tiles (128B rows, 8 granules)
static __device__ __forceinline__ int tidx64(int row, int gr) {
    return row * 64 + ((gr ^ (row & 7)) << 3);
}

// ---------------------------------------------------------------------------
// Split weights into bf16 hi/lo. Wqk = [Wq ; Wk] stacked (128 x 512).
// ---------------------------------------------------------------------------
__global__ __launch_bounds__(256) void split_w(
    const float* __restrict__ Wv, const float* __restrict__ Wq, const float* __restrict__ Wk,
    unsigned short* __restrict__ Wv_hi, unsigned short* __restrict__ Wv_lo,
    unsigned short* __restrict__ Wqk_hi, unsigned short* __restrict__ Wqk_lo)
{
    int i = blockIdx.x * 256 + threadIdx.x;
    if (i < C * C) {
        float f = Wv[i];
        unsigned short h = f2bf(f);
        Wv_hi[i] = h;
        Wv_lo[i] = f2bf(f - bf2f(h));
    }
    if (i < 128 * C) {
        int m = i / C, k = i % C;
        float f = (m < 64) ? Wq[m * C + k] : Wk[(m - 64) * C + k];
        unsigned short h = f2bf(f);
        Wqk_hi[i] = h;
        Wqk_lo[i] = f2bf(f - bf2f(h));
    }
}

// ---------------------------------------------------------------------------
// 3-pass split-bf16 MFMA GEMM for projections.
// MODE 0 (v):  out0[b,m,n] = sum_k W[m,k] x[b,k,n] + bias0[m]   -> (B,C,HW) fp32
// MODE 1 (qk): q/k[b,n,m]  = sum_k x[b,k,n] Wqk[m,k] + bias     -> bf16 hi/lo
// ---------------------------------------------------------------------------
template<int MODE>
__global__ __launch_bounds__(256, 2) void mfma_gemm(
    const float* __restrict__ x,
    const unsigned short* __restrict__ Wh,
    const unsigned short* __restrict__ Wl,
    const float* __restrict__ bias0,
    const float* __restrict__ bias1,
    float* __restrict__ out0,
    unsigned short* __restrict__ qh, unsigned short* __restrict__ ql,
    unsigned short* __restrict__ kh, unsigned short* __restrict__ kl)
{
    __shared__ short smem[16384];                     // 32 KB
    const int X_HI = 0, X_LO = 4096, W_HI = 8192, W_LO = 12288;

    int tid = threadIdx.x;
    int n0 = blockIdx.x * 128;
    int m0 = blockIdx.y * 128;
    int b  = blockIdx.z;

    int lane = tid & 63, wave = tid >> 6;
    int wr = wave >> 1, wc = wave & 1;
    int l15 = lane & 15, l4 = lane >> 4;

    int tn = tid & 31, tk = tid >> 5;
    int nloc = tn * 4, kloc = tk * 4;
    const float* xp = x + ((size_t)b * KD + kloc) * NSP + n0 + nloc;
    int kg = tk >> 1, khalf = tk & 1;

    f32x4 acc[4][4];
    #pragma unroll
    for (int i = 0; i < 4; ++i)
        #pragma unroll
        for (int j = 0; j < 4; ++j)
            acc[i][j] = (f32x4){0.f, 0.f, 0.f, 0.f};

    for (int k0 = 0; k0 < KD; k0 += 32) {
        float v4[4][4];
        #pragma unroll
        for (int kk = 0; kk < 4; ++kk) {
            float4 t = *(const float4*)(xp + (size_t)(k0 + kk) * NSP);
            v4[kk][0] = t.x; v4[kk][1] = t.y; v4[kk][2] = t.z; v4[kk][3] = t.w;
        }
        #pragma unroll
        for (int nn = 0; nn < 4; ++nn) {
            int n = nloc + nn;
            short4v hi, lo;
            #pragma unroll
            for (int kk = 0; kk < 4; ++kk) {
                float f = v4[kk][nn];
                unsigned short h = f2bf(f);
                hi[kk] = (short)h;
                lo[kk] = (short)f2bf(f - bf2f(h));
            }
            int base = tidx(n, kg) + khalf * 4;
            *(short4v*)&smem[X_HI + base] = hi;
            *(short4v*)&smem[X_LO + base] = lo;
        }
        #pragma unroll
        for (int it = 0; it < 4; ++it) {
            int gi = tid + it * 256;
            int sel = gi >> 9;
            int t = gi & 511;
            int row = t >> 2, kg2 = t & 3;
            const unsigned short* src = (sel ? Wl : Wh) + (size_t)(m0 + row) * KD + k0 + kg2 * 8;
            bf16x8 d = *(const bf16x8*)src;
            *(bf16x8*)&smem[(sel ? W_LO : W_HI) + tidx(row, kg2)] = d;
        }
        __syncthreads();

        const int A_HI = MODE ? X_HI : W_HI;
        const int A_LO = MODE ? X_LO : W_LO;
        const int B_HI = MODE ? W_HI : X_HI;
        const int B_LO = MODE ? W_LO : X_LO;

        bf16x8 af[4], bf_[4], bl_[4];
        #pragma unroll
        for (int f = 0; f < 4; ++f) {
            int ra = wr * 64 + f * 16 + l15;
            int rb = wc * 64 + f * 16 + l15;
            af[f]  = *(const bf16x8*)&smem[A_HI + tidx(ra, l4)];
            bf_[f] = *(const bf16x8*)&smem[B_HI + tidx(rb, l4)];
        }
        #pragma unroll
        for (int i = 0; i < 4; ++i)
            #pragma unroll
            for (int j = 0; j < 4; ++j)
                acc[i][j] = __builtin_amdgcn_mfma_f32_16x16x32_bf16(af[i], bf_[j], acc[i][j], 0, 0, 0);
        #pragma unroll
        for (int f = 0; f < 4; ++f) {
            int rb = wc * 64 + f * 16 + l15;
            bl_[f] = *(const bf16x8*)&smem[B_LO + tidx(rb, l4)];
        }
        #pragma unroll
        for (int i = 0; i < 4; ++i)
            #pragma unroll
            for (int j = 0; j < 4; ++j)
                acc[i][j] = __builtin_amdgcn_mfma_f32_16x16x32_bf16(af[i], bl_[j], acc[i][j], 0, 0, 0);
        #pragma unroll
        for (int f = 0; f < 4; ++f) {
            int ra = wr * 64 + f * 16 + l15;
            af[f] = *(const bf16x8*)&smem[A_LO + tidx(ra, l4)];
        }
        #pragma unroll
        for (int i = 0; i < 4; ++i)
            #pragma unroll
            for (int j = 0; j < 4; ++j)
                acc[i][j] = __builtin_amdgcn_mfma_f32_16x16x32_bf16(af[i], bf_[j], acc[i][j], 0, 0, 0);
        __syncthreads();
    }

    if (MODE == 0) {
        #pragma unroll
        for (int i = 0; i < 4; ++i) {
            #pragma unroll
            for (int r = 0; r < 4; ++r) {
                int row = m0 + wr * 64 + i * 16 + l4 * 4 + r;
                float bv = bias0[row];
                #pragma unroll
                for (int j = 0; j < 4; ++j) {
                    int col = n0 + wc * 64 + j * 16 + l15;
                    out0[((size_t)b * C + row) * NSP + col] = acc[i][j][r] + bv;
                }
            }
        }
    } else {
        #pragma unroll
        for (int i = 0; i < 4; ++i) {
            #pragma unroll
            for (int r = 0; r < 4; ++r) {
                int sp = n0 + wr * 64 + i * 16 + l4 * 4 + r;
                #pragma unroll
                for (int j = 0; j < 4; ++j) {
                    int wcol = wc * 64 + j * 16 + l15;
                    float val = acc[i][j][r] + (wcol < 64 ? bias0[wcol] : bias1[wcol - 64]);
                    unsigned short hi = f2bf(val);
                    unsigned short lo = f2bf(val - bf2f(hi));
                    size_t off = ((size_t)b * NSP + sp) * 64 + (wcol & 63);
                    if (wcol < 64) { qh[off] = hi; ql[off] = lo; }
                    else           { kh[off] = hi; kl[off] = lo; }
                }
            }
        }
    }
}

// ---------------------------------------------------------------------------
// Energy MFMA: per block (p, b), E[row,col] = q_panel[row,:] . k_panel[col,:]
// Panel rows r map to spatial index p*pMul + r*rMul.  96x96x64, 3-pass hi/lo.
// W-mode (pMul=96,rMul=1): out=E_W[b,p=h,w,j].  H-mode (1,96): out=E_H[b,p=w,h,j].
// ---------------------------------------------------------------------------
__global__ __launch_bounds__(256, 2) void energy_mfma(
    const unsigned short* __restrict__ qh, const unsigned short* __restrict__ ql,
    const unsigned short* __restrict__ kh, const unsigned short* __restrict__ kl,
    float* __restrict__ out, int pMul, int rMul)
{
    __shared__ short sm[4 * 96 * 64];   // 48 KB
    const int T_QH = 0, T_QL = 6144, T_KH = 12288, T_KL = 18432;
    int p = blockIdx.x, b = blockIdx.y;
    int tid = threadIdx.x;
    size_t base = ((size_t)b * HW + (size_t)p * pMul) * 64;
    size_t rstride = (size_t)rMul * 64;

    #pragma unroll
    for (int tile = 0; tile < 4; ++tile) {
        const unsigned short* src = (tile == 0) ? qh : (tile == 1) ? ql : (tile == 2) ? kh : kl;
        int tb = tile * 6144;
        #pragma unroll
        for (int sub = 0; sub < 3; ++sub) {
            int s = sub * 256 + tid;        // 0..767
            int row = s >> 3, g = s & 7;
            bf16x8 d = *(const bf16x8*)&src[base + row * rstride + g * 8];
            *(bf16x8*)&sm[tb + tidx64(row, g)] = d;
        }
    }
    __syncthreads();

    int lane = tid & 63, wave = tid >> 6;
    int wr = wave >> 1, wc = wave & 1;
    int l15 = lane & 15, l4 = lane >> 4;

    f32x4 acc[3][3];
    #pragma unroll
    for (int i = 0; i < 3; ++i)
        #pragma unroll
        for (int j = 0; j < 3; ++j)
            acc[i][j] = (f32x4){0.f, 0.f, 0.f, 0.f};

    #pragma unroll
    for (int ks = 0; ks < 2; ++ks) {
        bf16x8 Ah[3], Al[3], Bh[3], Bl[3];
        int gr = ks * 4 + l4;
        #pragma unroll
        for (int i = 0; i < 3; ++i) {
            int ra = wr * 48 + i * 16 + l15;
            int sa = tidx64(ra, gr);
            Ah[i] = *(const bf16x8*)&sm[T_QH + sa];
            Al[i] = *(const bf16x8*)&sm[T_QL + sa];
            int rb = wc * 48 + i * 16 + l15;
            int sb = tidx64(rb, gr);
            Bh[i] = *(const bf16x8*)&sm[T_KH + sb];
            Bl[i] = *(const bf16x8*)&sm[T_KL + sb];
        }
        #pragma unroll
        for (int i = 0; i < 3; ++i)
            #pragma unroll
            for (int j = 0; j < 3; ++j) {
                acc[i][j] = __builtin_amdgcn_mfma_f32_16x16x32_bf16(Ah[i], Bh[j], acc[i][j], 0, 0, 0);
                acc[i][j] = __builtin_amdgcn_mfma_f32_16x16x32_bf16(Ah[i], Bl[j], acc[i][j], 0, 0, 0);
                acc[i][j] = __builtin_amdgcn_mfma_f32_16x16x32_bf16(Al[i], Bh[j], acc[i][j], 0, 0, 0);
            }
    }

    size_t ob = (size_t)(b * 96 + p) * 9216;
    #pragma unroll
    for (int i = 0; i < 3; ++i)
        #pragma unroll
        for (int r = 0; r < 4; ++r) {
            int row = wr * 48 + i * 16 + l4 * 4 + r;
            #pragma unroll
            for (int j = 0; j < 3; ++j) {
                int col = wc * 48 + j * 16 + l15;
                out[ob + (size_t)row * 96 + col] = acc[i][j][r];
            }
        }
}

// ---------------------------------------------------------------------------
// Joint softmax max/sum: one wave per (b,h,w) row over [E_H row | E_W row].
// Writes ms[row] = (max, gamma/sum).
// ---------------------------------------------------------------------------
__global__ __launch_bounds__(256) void maxsum(
    const float* __restrict__ EW, const float* __restrict__ EH,
    const float* __restrict__ gamma, float* __restrict__ ms)
{
    int gw = (blockIdx.x * 256 + threadIdx.x) >> 6;
    int lane = threadIdx.x & 63;
    int b = gw / HW, hw = gw % HW;
    int h = hw / 96, w = hw % 96;
    const float* ew = &EW[((size_t)(b * 96 + h) * 96 + w) * 96];
    const float* eh = &EH[((size_t)(b * 96 + w) * 96 + h) * 96];
    float v0 = ew[lane];
    float v1 = (lane < 32) ? ew[64 + lane] : eh[lane - 32];
    float v2 = eh[32 + lane];
    float m = fmaxf(fmaxf(v0, v1), v2);
    #pragma unroll
    for (int s = 32; s; s >>= 1) m = fmaxf(m, __shfl_xor(m, s));
    float pp = __expf(v0 - m) + __expf(v1 - m) + __expf(v2 - m);
    #pragma unroll
    for (int s = 32; s; s >>= 1) pp += __shfl_xor(pp, s);
    if (lane == 0) {
        ms[(size_t)gw * 2]     = m;
        ms[(size_t)gw * 2 + 1] = gamma[0] / pp;
    }
}

// ---------------------------------------------------------------------------
// Row aggregation with on-the-fly softmax normalization.
// dst[b,c,r,s] = sum_j exp(E[b,r,s,j]-m)*scale * vsrc[b,c,r,j]
// msMode 0 (W): ms row = b*HW + r*96 + s ; msMode 1 (H): b*HW + s*96 + r.
// ---------------------------------------------------------------------------
__global__ __launch_bounds__(256) void row_agg(
    const float* __restrict__ att, const float* __restrict__ ms,
    const float* vsrc, float* dst, int msMode)
{
    int r = blockIdx.x, b = blockIdx.y;
    __shared__ float sAtt[96][97];
    __shared__ float sV[64][97];
    int tid = threadIdx.x;
    int wg = tid & 15;
    int cg = tid >> 4;
    int msBase = b * HW;

    const float* ab = &att[(((size_t)b * 96 + r) * 96) * 96];
    for (int i = tid; i < 96 * 96; i += 256) {
        int rrow = i / 96;
        int mi = msMode ? (msBase + rrow * 96 + r) : (msBase + r * 96 + rrow);
        float m  = ms[(size_t)mi * 2];
        float sc = ms[(size_t)mi * 2 + 1];
        sAtt[rrow][i % 96] = __expf(ab[i] - m) * sc;
    }

    for (int c0 = 0; c0 < C; c0 += 64) {
        __syncthreads();
        for (int i = tid; i < 64 * 96; i += 256) {
            int cc = i / 96, j = i % 96;
            sV[cc][j] = vsrc[(((size_t)b * C + c0 + cc) * 96 + r) * 96 + j];
        }
        __syncthreads();
        float acc[4][6] = {};
        #pragma unroll 4
        for (int j = 0; j < 96; ++j) {
            float vv[4], av[6];
            #pragma unroll
            for (int ci = 0; ci < 4; ++ci) vv[ci] = sV[cg * 4 + ci][j];
            #pragma unroll
            for (int si = 0; si < 6; ++si) av[si] = sAtt[wg + 16 * si][j];
            #pragma unroll
            for (int ci = 0; ci < 4; ++ci)
                #pragma unroll
                for (int si = 0; si < 6; ++si)
                    acc[ci][si] += vv[ci] * av[si];
        }
        #pragma unroll
        for (int ci = 0; ci < 4; ++ci) {
            int c = c0 + cg * 4 + ci;
            #pragma unroll
            for (int si = 0; si < 6; ++si) {
                int s = wg + 16 * si;
                dst[(((size_t)b * C + c) * 96 + r) * 96 + s] = acc[ci][si];
            }
        }
    }
}

__global__ __launch_bounds__(256) void transpose_inplace(float* __restrict__ v)
{
    size_t base = (size_t)blockIdx.x * (96 * 96);
    __shared__ float t[96][97];
    int tid = threadIdx.x;
    for (int i = tid; i < 96 * 96; i += 256) t[i / 96][i % 96] = v[base + i];
    __syncthreads();
    for (int i = tid; i < 96 * 96; i += 256) v[base + i] = t[i % 96][i / 96];
}

__global__ __launch_bounds__(256) void transpose_add(
    const float* __restrict__ outT, float* __restrict__ out)
{
    size_t base = (size_t)blockIdx.x * (96 * 96);
    __shared__ float t[96][97];
    int tid = threadIdx.x;
    for (int i = tid; i < 96 * 96; i += 256) t[i / 96][i % 96] = outT[base + i];
    __syncthreads();
    for (int i = tid; i < 96 * 96; i += 256) out[base + i] += t[i % 96][i / 96];
}

// ---------------------------------------------------------------------------
extern "C" void kernel_launch(void* const* d_in, const int* in_sizes, int n_in,
                              void* d_out, int out_size, void* d_ws, size_t ws_size,
                              hipStream_t stream)
{
    const float* x     = (const float*)d_in[0];
    const float* Wq    = (const float*)d_in[1];
    const float* bq    = (const float*)d_in[2];
    const float* Wk    = (const float*)d_in[3];
    const float* bk    = (const float*)d_in[4];
    const float* Wv    = (const float*)d_in[5];
    const float* bv    = (const float*)d_in[6];
    const float* gamma = (const float*)d_in[7];
    float* out = (float*)d_out;

    // workspace layout (bytes match R2's 245.4 MB footprint)
    unsigned short* qh = (unsigned short*)d_ws;          // B*HW*64 bf16  9.44 MB
    unsigned short* ql = qh + (size_t)B*HW*64;
    unsigned short* kh = ql + (size_t)B*HW*64;
    unsigned short* kl = kh + (size_t)B*HW*64;
    float* v    = (float*)(kl + (size_t)B*HW*64);        // (B,C,H,W) 151 MB
    float* EH   = v  + (size_t)B*C*HW;                   // (B,W,H,96) 28.3 MB
    float* EW   = EH + (size_t)B*HW*96;                  // (B,H,W,96) 28.3 MB
    float* ms   = (float*)d_ws;                          // aliases qh (dead after energies)

    // W splits alias the EW region (dead until energy_mfma W-mode writes it)
    unsigned short* Wv_hi  = (unsigned short*)EW;
    unsigned short* Wv_lo  = Wv_hi  + (size_t)C*C;
    unsigned short* Wqk_hi = Wv_lo  + (size_t)C*C;
    unsigned short* Wqk_lo = Wqk_hi + (size_t)128*C;

    dim3 blk(256);

    split_w<<<dim3((C*C + 255)/256), blk, 0, stream>>>(Wv, Wq, Wk, Wv_hi, Wv_lo, Wqk_hi, Wqk_lo);

    mfma_gemm<0><<<dim3(NSP/128, C/128, B), blk, 0, stream>>>(
        x, Wv_hi, Wv_lo, bv, nullptr, v, nullptr, nullptr, nullptr, nullptr);
    mfma_gemm<1><<<dim3(NSP/128, 1, B), blk, 0, stream>>>(
        x, Wqk_hi, Wqk_lo, bq, bk, nullptr, qh, ql, kh, kl);

    // energies: E_W (pMul=96,rMul=1) and E_H (pMul=1,rMul=96)
    energy_mfma<<<dim3(96, B), blk, 0, stream>>>(qh, ql, kh, kl, EW, 96, 1);
    energy_mfma<<<dim3(96, B), blk, 0, stream>>>(qh, ql, kh, kl, EH, 1, 96);

    // per-row joint max & gamma/sum  (ms aliases q/k splits — dead now)
    maxsum<<<dim3(B*HW/4), blk, 0, stream>>>(EW, EH, gamma, ms);

    row_agg<<<dim3(96, B), blk, 0, stream>>>(EW, ms, v, out, 0);
    transpose_inplace<<<dim3(B*C), blk, 0, stream>>>(v);
    row_agg<<<dim3(96, B), blk, 0, stream>>>(EH, ms, v, v, 1);
    transpose_add<<<dim3(B*C), blk, 0, stream>>>(v, out);
}

// Round 4
// 543.440 us; speedup vs baseline: 3.6471x; 1.5704x over previous
//
#include <hip/hip_runtime.h>

#define B 8
#define C 512
#define H 96
#define W 96
#define HW (H*W)       // 9216
#define KD 512
#define NSP 9216

typedef __attribute__((ext_vector_type(8))) short bf16x8;
typedef __attribute__((ext_vector_type(4))) short short4v;
typedef __attribute__((ext_vector_type(4))) float f32x4;

static __device__ __forceinline__ unsigned short f2bf(float f) {
    unsigned u = __float_as_uint(f);
    return (unsigned short)((u + 0x7FFFu + ((u >> 16) & 1u)) >> 16);
}
static __device__ __forceinline__ float bf2f(unsigned short h) {
    return __uint_as_float(((unsigned)h) << 16);
}
// swizzle for [rows][32-short] tiles (64B rows, 4 granules)
static __device__ __forceinline__ int tidx(int row, int kgrp) {
    return row * 32 + ((kgrp ^ ((row >> 1) & 3)) << 3);
}
// swizzle for [rows][64-short] tiles (128B rows, 8 granules)
static __device__ __forceinline__ int tidx64(int row, int gr) {
    return row * 64 + ((gr ^ (row & 7)) << 3);
}

// ---------------------------------------------------------------------------
// Split weights into bf16 hi/lo. Wqk = [Wq ; Wk] stacked (128 x 512).
// ---------------------------------------------------------------------------
__global__ __launch_bounds__(256) void split_w(
    const float* __restrict__ Wv, const float* __restrict__ Wq, const float* __restrict__ Wk,
    unsigned short* __restrict__ Wv_hi, unsigned short* __restrict__ Wv_lo,
    unsigned short* __restrict__ Wqk_hi, unsigned short* __restrict__ Wqk_lo)
{
    int i = blockIdx.x * 256 + threadIdx.x;
    if (i < C * C) {
        float f = Wv[i];
        unsigned short h = f2bf(f);
        Wv_hi[i] = h;
        Wv_lo[i] = f2bf(f - bf2f(h));
    }
    if (i < 128 * C) {
        int m = i / C, k = i % C;
        float f = (m < 64) ? Wq[m * C + k] : Wk[(m - 64) * C + k];
        unsigned short h = f2bf(f);
        Wqk_hi[i] = h;
        Wqk_lo[i] = f2bf(f - bf2f(h));
    }
}

// ---------------------------------------------------------------------------
// 3-pass split-bf16 MFMA GEMM for projections.
// MODE 0 (v):  out0[b,m,n] = sum_k W[m,k] x[b,k,n] + bias0[m]   -> (B,C,HW) fp32
// MODE 1 (qk): q/k[b,n,m]  = sum_k x[b,k,n] Wqk[m,k] + bias     -> bf16 hi/lo
// ---------------------------------------------------------------------------
template<int MODE>
__global__ __launch_bounds__(256, 2) void mfma_gemm(
    const float* __restrict__ x,
    const unsigned short* __restrict__ Wh,
    const unsigned short* __restrict__ Wl,
    const float* __restrict__ bias0,
    const float* __restrict__ bias1,
    float* __restrict__ out0,
    unsigned short* __restrict__ qh, unsigned short* __restrict__ ql,
    unsigned short* __restrict__ kh, unsigned short* __restrict__ kl)
{
    __shared__ short smem[16384];                     // 32 KB
    const int X_HI = 0, X_LO = 4096, W_HI = 8192, W_LO = 12288;

    int tid = threadIdx.x;
    int n0 = blockIdx.x * 128;
    int m0 = blockIdx.y * 128;
    int b  = blockIdx.z;

    int lane = tid & 63, wave = tid >> 6;
    int wr = wave >> 1, wc = wave & 1;
    int l15 = lane & 15, l4 = lane >> 4;

    int tn = tid & 31, tk = tid >> 5;
    int nloc = tn * 4, kloc = tk * 4;
    const float* xp = x + ((size_t)b * KD + kloc) * NSP + n0 + nloc;
    int kg = tk >> 1, khalf = tk & 1;

    f32x4 acc[4][4];
    #pragma unroll
    for (int i = 0; i < 4; ++i)
        #pragma unroll
        for (int j = 0; j < 4; ++j)
            acc[i][j] = (f32x4){0.f, 0.f, 0.f, 0.f};

    for (int k0 = 0; k0 < KD; k0 += 32) {
        float v4[4][4];
        #pragma unroll
        for (int kk = 0; kk < 4; ++kk) {
            float4 t = *(const float4*)(xp + (size_t)(k0 + kk) * NSP);
            v4[kk][0] = t.x; v4[kk][1] = t.y; v4[kk][2] = t.z; v4[kk][3] = t.w;
        }
        #pragma unroll
        for (int nn = 0; nn < 4; ++nn) {
            int n = nloc + nn;
            short4v hi, lo;
            #pragma unroll
            for (int kk = 0; kk < 4; ++kk) {
                float f = v4[kk][nn];
                unsigned short h = f2bf(f);
                hi[kk] = (short)h;
                lo[kk] = (short)f2bf(f - bf2f(h));
            }
            int base = tidx(n, kg) + khalf * 4;
            *(short4v*)&smem[X_HI + base] = hi;
            *(short4v*)&smem[X_LO + base] = lo;
        }
        #pragma unroll
        for (int it = 0; it < 4; ++it) {
            int gi = tid + it * 256;
            int sel = gi >> 9;
            int t = gi & 511;
            int row = t >> 2, kg2 = t & 3;
            const unsigned short* src = (sel ? Wl : Wh) + (size_t)(m0 + row) * KD + k0 + kg2 * 8;
            bf16x8 d = *(const bf16x8*)src;
            *(bf16x8*)&smem[(sel ? W_LO : W_HI) + tidx(row, kg2)] = d;
        }
        __syncthreads();

        const int A_HI = MODE ? X_HI : W_HI;
        const int A_LO = MODE ? X_LO : W_LO;
        const int B_HI = MODE ? W_HI : X_HI;
        const int B_LO = MODE ? W_LO : X_LO;

        bf16x8 af[4], bf_[4], bl_[4];
        #pragma unroll
        for (int f = 0; f < 4; ++f) {
            int ra = wr * 64 + f * 16 + l15;
            int rb = wc * 64 + f * 16 + l15;
            af[f]  = *(const bf16x8*)&smem[A_HI + tidx(ra, l4)];
            bf_[f] = *(const bf16x8*)&smem[B_HI + tidx(rb, l4)];
        }
        #pragma unroll
        for (int i = 0; i < 4; ++i)
            #pragma unroll
            for (int j = 0; j < 4; ++j)
                acc[i][j] = __builtin_amdgcn_mfma_f32_16x16x32_bf16(af[i], bf_[j], acc[i][j], 0, 0, 0);
        #pragma unroll
        for (int f = 0; f < 4; ++f) {
            int rb = wc * 64 + f * 16 + l15;
            bl_[f] = *(const bf16x8*)&smem[B_LO + tidx(rb, l4)];
        }
        #pragma unroll
        for (int i = 0; i < 4; ++i)
            #pragma unroll
            for (int j = 0; j < 4; ++j)
                acc[i][j] = __builtin_amdgcn_mfma_f32_16x16x32_bf16(af[i], bl_[j], acc[i][j], 0, 0, 0);
        #pragma unroll
        for (int f = 0; f < 4; ++f) {
            int ra = wr * 64 + f * 16 + l15;
            af[f] = *(const bf16x8*)&smem[A_LO + tidx(ra, l4)];
        }
        #pragma unroll
        for (int i = 0; i < 4; ++i)
            #pragma unroll
            for (int j = 0; j < 4; ++j)
                acc[i][j] = __builtin_amdgcn_mfma_f32_16x16x32_bf16(af[i], bf_[j], acc[i][j], 0, 0, 0);
        __syncthreads();
    }

    if (MODE == 0) {
        #pragma unroll
        for (int i = 0; i < 4; ++i) {
            #pragma unroll
            for (int r = 0; r < 4; ++r) {
                int row = m0 + wr * 64 + i * 16 + l4 * 4 + r;
                float bv = bias0[row];
                #pragma unroll
                for (int j = 0; j < 4; ++j) {
                    int col = n0 + wc * 64 + j * 16 + l15;
                    out0[((size_t)b * C + row) * NSP + col] = acc[i][j][r] + bv;
                }
            }
        }
    } else {
        #pragma unroll
        for (int i = 0; i < 4; ++i) {
            #pragma unroll
            for (int r = 0; r < 4; ++r) {
                int sp = n0 + wr * 64 + i * 16 + l4 * 4 + r;
                #pragma unroll
                for (int j = 0; j < 4; ++j) {
                    int wcol = wc * 64 + j * 16 + l15;
                    float val = acc[i][j][r] + (wcol < 64 ? bias0[wcol] : bias1[wcol - 64]);
                    unsigned short hi = f2bf(val);
                    unsigned short lo = f2bf(val - bf2f(hi));
                    size_t off = ((size_t)b * NSP + sp) * 64 + (wcol & 63);
                    if (wcol < 64) { qh[off] = hi; ql[off] = lo; }
                    else           { kh[off] = hi; kl[off] = lo; }
                }
            }
        }
    }
}

// ---------------------------------------------------------------------------
// Energy MFMA (unchanged from R3)
// ---------------------------------------------------------------------------
__global__ __launch_bounds__(256, 2) void energy_mfma(
    const unsigned short* __restrict__ qh, const unsigned short* __restrict__ ql,
    const unsigned short* __restrict__ kh, const unsigned short* __restrict__ kl,
    float* __restrict__ out, int pMul, int rMul)
{
    __shared__ short sm[4 * 96 * 64];   // 48 KB
    const int T_QH = 0, T_QL = 6144, T_KH = 12288, T_KL = 18432;
    int p = blockIdx.x, b = blockIdx.y;
    int tid = threadIdx.x;
    size_t base = ((size_t)b * HW + (size_t)p * pMul) * 64;
    size_t rstride = (size_t)rMul * 64;

    #pragma unroll
    for (int tile = 0; tile < 4; ++tile) {
        const unsigned short* src = (tile == 0) ? qh : (tile == 1) ? ql : (tile == 2) ? kh : kl;
        int tb = tile * 6144;
        #pragma unroll
        for (int sub = 0; sub < 3; ++sub) {
            int s = sub * 256 + tid;
            int row = s >> 3, g = s & 7;
            bf16x8 d = *(const bf16x8*)&src[base + row * rstride + g * 8];
            *(bf16x8*)&sm[tb + tidx64(row, g)] = d;
        }
    }
    __syncthreads();

    int lane = tid & 63, wave = tid >> 6;
    int wr = wave >> 1, wc = wave & 1;
    int l15 = lane & 15, l4 = lane >> 4;

    f32x4 acc[3][3];
    #pragma unroll
    for (int i = 0; i < 3; ++i)
        #pragma unroll
        for (int j = 0; j < 3; ++j)
            acc[i][j] = (f32x4){0.f, 0.f, 0.f, 0.f};

    #pragma unroll
    for (int ks = 0; ks < 2; ++ks) {
        bf16x8 Ah[3], Al[3], Bh[3], Bl[3];
        int gr = ks * 4 + l4;
        #pragma unroll
        for (int i = 0; i < 3; ++i) {
            int ra = wr * 48 + i * 16 + l15;
            int sa = tidx64(ra, gr);
            Ah[i] = *(const bf16x8*)&sm[T_QH + sa];
            Al[i] = *(const bf16x8*)&sm[T_QL + sa];
            int rb = wc * 48 + i * 16 + l15;
            int sb = tidx64(rb, gr);
            Bh[i] = *(const bf16x8*)&sm[T_KH + sb];
            Bl[i] = *(const bf16x8*)&sm[T_KL + sb];
        }
        #pragma unroll
        for (int i = 0; i < 3; ++i)
            #pragma unroll
            for (int j = 0; j < 3; ++j) {
                acc[i][j] = __builtin_amdgcn_mfma_f32_16x16x32_bf16(Ah[i], Bh[j], acc[i][j], 0, 0, 0);
                acc[i][j] = __builtin_amdgcn_mfma_f32_16x16x32_bf16(Ah[i], Bl[j], acc[i][j], 0, 0, 0);
                acc[i][j] = __builtin_amdgcn_mfma_f32_16x16x32_bf16(Al[i], Bh[j], acc[i][j], 0, 0, 0);
            }
    }

    size_t ob = (size_t)(b * 96 + p) * 9216;
    #pragma unroll
    for (int i = 0; i < 3; ++i)
        #pragma unroll
        for (int r = 0; r < 4; ++r) {
            int row = wr * 48 + i * 16 + l4 * 4 + r;
            #pragma unroll
            for (int j = 0; j < 3; ++j) {
                int col = wc * 48 + j * 16 + l15;
                out[ob + (size_t)row * 96 + col] = acc[i][j][r];
            }
        }
}

// ---------------------------------------------------------------------------
// Joint softmax max/sum (unchanged from R3)
// ---------------------------------------------------------------------------
__global__ __launch_bounds__(256) void maxsum(
    const float* __restrict__ EW, const float* __restrict__ EH,
    const float* __restrict__ gamma, float* __restrict__ ms)
{
    int gw = (blockIdx.x * 256 + threadIdx.x) >> 6;
    int lane = threadIdx.x & 63;
    int b = gw / HW, hw = gw % HW;
    int h = hw / 96, w = hw % 96;
    const float* ew = &EW[((size_t)(b * 96 + h) * 96 + w) * 96];
    const float* eh = &EH[((size_t)(b * 96 + w) * 96 + h) * 96];
    float v0 = ew[lane];
    float v1 = (lane < 32) ? ew[64 + lane] : eh[lane - 32];
    float v2 = eh[32 + lane];
    float m = fmaxf(fmaxf(v0, v1), v2);
    #pragma unroll
    for (int s = 32; s; s >>= 1) m = fmaxf(m, __shfl_xor(m, s));
    float pp = __expf(v0 - m) + __expf(v1 - m) + __expf(v2 - m);
    #pragma unroll
    for (int s = 32; s; s >>= 1) pp += __shfl_xor(pp, s);
    if (lane == 0) {
        ms[(size_t)gw * 2]     = m;
        ms[(size_t)gw * 2 + 1] = gamma[0] / pp;
    }
}

// ---------------------------------------------------------------------------
// MFMA aggregation with fused softmax normalization.
// Block (r, c-quarter, b): dst[b, c0+cl, r, s] = sum_j p[s,j] * vsrc[b, c0+cl, r, j]
// where p[s,j] = exp(E[b,r,s,j]-m)*sc, split to bf16 hi/lo, 3-pass MFMA.
// In-place safe for H-mode: read set == write set, all reads precede writes.
// ---------------------------------------------------------------------------
__global__ __launch_bounds__(256, 2) void agg_mfma(
    const float* __restrict__ E, const float* __restrict__ ms,
    const float* vsrc, float* dst, int msMode)
{
    __shared__ short satt[2][3][96 * 32];   // 36 KB  [hi/lo][kchunk][tidx(s,g)]
    __shared__ short sv[2][128 * 32];       // 16 KB  [hi/lo][tidx(cl,g)]

    int r  = blockIdx.x;
    int c0 = blockIdx.y * 128;
    int b  = blockIdx.z;
    int tid = threadIdx.x;
    int lane = tid & 63, wave = tid >> 6;
    int l15 = lane & 15, l4 = lane >> 4;

    // ---- stage att: exp-normalize, split bf16 hi/lo into K-chunked swizzled LDS ----
    const float* Eb = &E[(size_t)(b * 96 + r) * 9216];
    int msBase = b * HW;
    #pragma unroll
    for (int it = 0; it < 5; ++it) {
        int g_id = tid + it * 256;
        if (g_id < 1152) {
            int s = g_id / 12, gj = g_id % 12;
            int mi = msMode ? (msBase + s * 96 + r) : (msBase + r * 96 + s);
            float m  = ms[(size_t)mi * 2];
            float sc = ms[(size_t)mi * 2 + 1];
            float4 e0 = *(const float4*)&Eb[s * 96 + gj * 8];
            float4 e1 = *(const float4*)&Eb[s * 96 + gj * 8 + 4];
            float pv[8] = {e0.x, e0.y, e0.z, e0.w, e1.x, e1.y, e1.z, e1.w};
            bf16x8 hi, lo;
            #pragma unroll
            for (int u = 0; u < 8; ++u) {
                float p = __expf(pv[u] - m) * sc;
                unsigned short hh = f2bf(p);
                hi[u] = (short)hh;
                lo[u] = (short)f2bf(p - bf2f(hh));
            }
            int pos = tidx(s, gj & 3);
            *(bf16x8*)&satt[0][gj >> 2][pos] = hi;
            *(bf16x8*)&satt[1][gj >> 2][pos] = lo;
        }
    }

    // v element (cl, j) at vb[cl*9216 + j]
    const float* vb = &vsrc[(((size_t)b * C + c0) * 96 + r) * 96];
    int vrow = tid >> 1, jh = tid & 1;
    const float* vpb = vb + (size_t)vrow * 9216 + jh * 16;

    f32x4 acc[2][6];
    #pragma unroll
    for (int i = 0; i < 2; ++i)
        #pragma unroll
        for (int n = 0; n < 6; ++n)
            acc[i][n] = (f32x4){0.f, 0.f, 0.f, 0.f};

    for (int kc = 0; kc < 3; ++kc) {
        // load v chunk to regs (before barrier — overlaps with prior MFMA)
        float4 f0 = *(const float4*)(vpb + kc * 32);
        float4 f1 = *(const float4*)(vpb + kc * 32 + 4);
        float4 f2 = *(const float4*)(vpb + kc * 32 + 8);
        float4 f3 = *(const float4*)(vpb + kc * 32 + 12);
        float fv[16] = {f0.x, f0.y, f0.z, f0.w, f1.x, f1.y, f1.z, f1.w,
                        f2.x, f2.y, f2.z, f2.w, f3.x, f3.y, f3.z, f3.w};
        __syncthreads();   // prior iteration's MFMA reads done (also att stores visible at kc=0)
        #pragma unroll
        for (int gg = 0; gg < 2; ++gg) {
            bf16x8 hi, lo;
            #pragma unroll
            for (int u = 0; u < 8; ++u) {
                float f = fv[gg * 8 + u];
                unsigned short hh = f2bf(f);
                hi[u] = (short)hh;
                lo[u] = (short)f2bf(f - bf2f(hh));
            }
            int pos = tidx(vrow, jh * 2 + gg);
            *(bf16x8*)&sv[0][pos] = hi;
            *(bf16x8*)&sv[1][pos] = lo;
        }
        __syncthreads();

        bf16x8 Bh[6], Bl[6];
        #pragma unroll
        for (int n = 0; n < 6; ++n) {
            int pos = tidx(n * 16 + l15, l4);
            Bh[n] = *(const bf16x8*)&satt[0][kc][pos];
            Bl[n] = *(const bf16x8*)&satt[1][kc][pos];
        }
        bf16x8 Ah[2], Al[2];
        #pragma unroll
        for (int i = 0; i < 2; ++i) {
            int pos = tidx(wave * 32 + i * 16 + l15, l4);
            Ah[i] = *(const bf16x8*)&sv[0][pos];
            Al[i] = *(const bf16x8*)&sv[1][pos];
        }
        #pragma unroll
        for (int i = 0; i < 2; ++i)
            #pragma unroll
            for (int n = 0; n < 6; ++n) {
                acc[i][n] = __builtin_amdgcn_mfma_f32_16x16x32_bf16(Ah[i], Bh[n], acc[i][n], 0, 0, 0);
                acc[i][n] = __builtin_amdgcn_mfma_f32_16x16x32_bf16(Ah[i], Bl[n], acc[i][n], 0, 0, 0);
                acc[i][n] = __builtin_amdgcn_mfma_f32_16x16x32_bf16(Al[i], Bh[n], acc[i][n], 0, 0, 0);
            }
    }

    // ---- epilogue: dst[b, c, r, s] ----
    float* db = &dst[(((size_t)b * C + c0) * 96 + r) * 96];
    #pragma unroll
    for (int i = 0; i < 2; ++i)
        #pragma unroll
        for (int r4 = 0; r4 < 4; ++r4) {
            int cl = wave * 32 + i * 16 + l4 * 4 + r4;
            #pragma unroll
            for (int n = 0; n < 6; ++n) {
                int s = n * 16 + l15;
                db[(size_t)cl * 9216 + s] = acc[i][n][r4];
            }
        }
}

__global__ __launch_bounds__(256) void transpose_inplace(float* __restrict__ v)
{
    size_t base = (size_t)blockIdx.x * (96 * 96);
    __shared__ float t[96][97];
    int tid = threadIdx.x;
    for (int i = tid; i < 96 * 96; i += 256) t[i / 96][i % 96] = v[base + i];
    __syncthreads();
    for (int i = tid; i < 96 * 96; i += 256) v[base + i] = t[i % 96][i / 96];
}

__global__ __launch_bounds__(256) void transpose_add(
    const float* __restrict__ outT, float* __restrict__ out)
{
    size_t base = (size_t)blockIdx.x * (96 * 96);
    __shared__ float t[96][97];
    int tid = threadIdx.x;
    for (int i = tid; i < 96 * 96; i += 256) t[i / 96][i % 96] = outT[base + i];
    __syncthreads();
    for (int i = tid; i < 96 * 96; i += 256) out[base + i] += t[i % 96][i / 96];
}

// ---------------------------------------------------------------------------
extern "C" void kernel_launch(void* const* d_in, const int* in_sizes, int n_in,
                              void* d_out, int out_size, void* d_ws, size_t ws_size,
                              hipStream_t stream)
{
    const float* x     = (const float*)d_in[0];
    const float* Wq    = (const float*)d_in[1];
    const float* bq    = (const float*)d_in[2];
    const float* Wk    = (const float*)d_in[3];
    const float* bk    = (const float*)d_in[4];
    const float* Wv    = (const float*)d_in[5];
    const float* bv    = (const float*)d_in[6];
    const float* gamma = (const float*)d_in[7];
    float* out = (float*)d_out;

    unsigned short* qh = (unsigned short*)d_ws;          // B*HW*64 bf16
    unsigned short* ql = qh + (size_t)B*HW*64;
    unsigned short* kh = ql + (size_t)B*HW*64;
    unsigned short* kl = kh + (size_t)B*HW*64;
    float* v    = (float*)(kl + (size_t)B*HW*64);        // (B,C,H,W) 151 MB
    float* EH   = v  + (size_t)B*C*HW;                   // (B,W,H,96) 28.3 MB
    float* EW   = EH + (size_t)B*HW*96;                  // (B,H,W,96) 28.3 MB
    float* ms   = (float*)d_ws;                          // aliases qh (dead after energies)

    unsigned short* Wv_hi  = (unsigned short*)EW;        // splits alias EW (dead until energy W-mode)
    unsigned short* Wv_lo  = Wv_hi  + (size_t)C*C;
    unsigned short* Wqk_hi = Wv_lo  + (size_t)C*C;
    unsigned short* Wqk_lo = Wqk_hi + (size_t)128*C;

    dim3 blk(256);

    split_w<<<dim3((C*C + 255)/256), blk, 0, stream>>>(Wv, Wq, Wk, Wv_hi, Wv_lo, Wqk_hi, Wqk_lo);

    mfma_gemm<0><<<dim3(NSP/128, C/128, B), blk, 0, stream>>>(
        x, Wv_hi, Wv_lo, bv, nullptr, v, nullptr, nullptr, nullptr, nullptr);
    mfma_gemm<1><<<dim3(NSP/128, 1, B), blk, 0, stream>>>(
        x, Wqk_hi, Wqk_lo, bq, bk, nullptr, qh, ql, kh, kl);

    energy_mfma<<<dim3(96, B), blk, 0, stream>>>(qh, ql, kh, kl, EW, 96, 1);
    energy_mfma<<<dim3(96, B), blk, 0, stream>>>(qh, ql, kh, kl, EH, 1, 96);

    maxsum<<<dim3(B*HW/4), blk, 0, stream>>>(EW, EH, gamma, ms);

    // out_W
    agg_mfma<<<dim3(96, 4, B), blk, 0, stream>>>(EW, ms, v, out, 0);
    // v -> (B,C,W,H)
    transpose_inplace<<<dim3(B*C), blk, 0, stream>>>(v);
    // out_H in transposed domain, in place
    agg_mfma<<<dim3(96, 4, B), blk, 0, stream>>>(EH, ms, v, v, 1);
    // out += transpose(v')
    transpose_add<<<dim3(B*C), blk, 0, stream>>>(v, out);
}

// Round 5
// 523.356 us; speedup vs baseline: 3.7871x; 1.0384x over previous
//
#include <hip/hip_runtime.h>

#define B 8
#define C 512
#define H 96
#define W 96
#define HW (H*W)       // 9216
#define KD 512
#define NSP 9216

typedef __attribute__((ext_vector_type(8))) short bf16x8;
typedef __attribute__((ext_vector_type(4))) short short4v;
typedef __attribute__((ext_vector_type(4))) float f32x4;
typedef __attribute__((ext_vector_type(8))) _Float16 f16x8;
typedef __attribute__((ext_vector_type(4))) _Float16 f16x4v;

static __device__ __forceinline__ unsigned short f2bf(float f) {
    unsigned u = __float_as_uint(f);
    return (unsigned short)((u + 0x7FFFu + ((u >> 16) & 1u)) >> 16);
}
static __device__ __forceinline__ float bf2f(unsigned short h) {
    return __uint_as_float(((unsigned)h) << 16);
}
// swizzle for [rows][32-elem] tiles (64B rows, 4 granules of 8 elems)
static __device__ __forceinline__ int tidx(int row, int kgrp) {
    return row * 32 + ((kgrp ^ ((row >> 1) & 3)) << 3);
}
// swizzle for [rows][64-elem] tiles (128B rows, 8 granules)
static __device__ __forceinline__ int tidx64(int row, int gr) {
    return row * 64 + ((gr ^ (row & 7)) << 3);
}

// ---------------------------------------------------------------------------
// Split weights: Wv -> fp16 (single, for 2-pass v GEMM);
// Wqk = [Wq;Wk] -> bf16 hi/lo (3-pass, precision-critical energy path).
// ---------------------------------------------------------------------------
__global__ __launch_bounds__(256) void split_w(
    const float* __restrict__ Wv, const float* __restrict__ Wq, const float* __restrict__ Wk,
    _Float16* __restrict__ Wv_h,
    unsigned short* __restrict__ Wqk_hi, unsigned short* __restrict__ Wqk_lo)
{
    int i = blockIdx.x * 256 + threadIdx.x;
    if (i < C * C) {
        Wv_h[i] = (_Float16)Wv[i];
    }
    if (i < 128 * C) {
        int m = i / C, k = i % C;
        float f = (m < 64) ? Wq[m * C + k] : Wk[(m - 64) * C + k];
        unsigned short h = f2bf(f);
        Wqk_hi[i] = h;
        Wqk_lo[i] = f2bf(f - bf2f(h));
    }
}

// ---------------------------------------------------------------------------
// v projection: 2-pass split-fp16 MFMA GEMM.
// out[b,m,n] = sum_k Wv[m,k] x[b,k,n] + bias[m]   -> (B,C,HW) fp32
// passes: Wh*xh + Wh*xl  (dropped (W-Wh)*x term ~2^-12 relative)
// ---------------------------------------------------------------------------
__global__ __launch_bounds__(256, 2) void gemm_v_f16(
    const float* __restrict__ x,
    const _Float16* __restrict__ Wh,
    const float* __restrict__ bias,
    float* __restrict__ out)
{
    __shared__ _Float16 smem[12288];                  // 24 KB
    const int X_HI = 0, X_LO = 4096, W_H = 8192;

    int tid = threadIdx.x;
    int n0 = blockIdx.x * 128;
    int m0 = blockIdx.y * 128;
    int b  = blockIdx.z;

    int lane = tid & 63, wave = tid >> 6;
    int wr = wave >> 1, wc = wave & 1;
    int l15 = lane & 15, l4 = lane >> 4;

    int tn = tid & 31, tk = tid >> 5;
    int nloc = tn * 4, kloc = tk * 4;
    const float* xp = x + ((size_t)b * KD + kloc) * NSP + n0 + nloc;
    int kg = tk >> 1, khalf = tk & 1;

    f32x4 acc[4][4];
    #pragma unroll
    for (int i = 0; i < 4; ++i)
        #pragma unroll
        for (int j = 0; j < 4; ++j)
            acc[i][j] = (f32x4){0.f, 0.f, 0.f, 0.f};

    for (int k0 = 0; k0 < KD; k0 += 32) {
        // ---- stage x tile: fp32 load, split fp16 hi/lo, transpose to [n][k] ----
        float v4[4][4];
        #pragma unroll
        for (int kk = 0; kk < 4; ++kk) {
            float4 t = *(const float4*)(xp + (size_t)(k0 + kk) * NSP);
            v4[kk][0] = t.x; v4[kk][1] = t.y; v4[kk][2] = t.z; v4[kk][3] = t.w;
        }
        #pragma unroll
        for (int nn = 0; nn < 4; ++nn) {
            int n = nloc + nn;
            f16x4v hi, lo;
            #pragma unroll
            for (int kk = 0; kk < 4; ++kk) {
                float f = v4[kk][nn];
                _Float16 hh = (_Float16)f;
                hi[kk] = hh;
                lo[kk] = (_Float16)(f - (float)hh);
            }
            int base = tidx(n, kg) + khalf * 4;
            *(f16x4v*)&smem[X_HI + base] = hi;
            *(f16x4v*)&smem[X_LO + base] = lo;
        }
        // ---- stage W tile (fp16 in global, single) ----
        #pragma unroll
        for (int it = 0; it < 2; ++it) {
            int gi = tid + it * 256;          // 512 granules of 8 halves
            int row = gi >> 2, kg2 = gi & 3;
            f16x8 d = *(const f16x8*)&Wh[(size_t)(m0 + row) * KD + k0 + kg2 * 8];
            *(f16x8*)&smem[W_H + tidx(row, kg2)] = d;
        }
        __syncthreads();

        f16x8 af[4], bh_[4], bl_[4];
        #pragma unroll
        for (int f = 0; f < 4; ++f) {
            int ra = wr * 64 + f * 16 + l15;       // W rows (m)
            int rb = wc * 64 + f * 16 + l15;       // x rows (n)
            af[f]  = *(const f16x8*)&smem[W_H  + tidx(ra, l4)];
            bh_[f] = *(const f16x8*)&smem[X_HI + tidx(rb, l4)];
        }
        #pragma unroll
        for (int i = 0; i < 4; ++i)
            #pragma unroll
            for (int j = 0; j < 4; ++j)
                acc[i][j] = __builtin_amdgcn_mfma_f32_16x16x32_f16(af[i], bh_[j], acc[i][j], 0, 0, 0);
        #pragma unroll
        for (int f = 0; f < 4; ++f) {
            int rb = wc * 64 + f * 16 + l15;
            bl_[f] = *(const f16x8*)&smem[X_LO + tidx(rb, l4)];
        }
        #pragma unroll
        for (int i = 0; i < 4; ++i)
            #pragma unroll
            for (int j = 0; j < 4; ++j)
                acc[i][j] = __builtin_amdgcn_mfma_f32_16x16x32_f16(af[i], bl_[j], acc[i][j], 0, 0, 0);
        __syncthreads();
    }

    #pragma unroll
    for (int i = 0; i < 4; ++i) {
        #pragma unroll
        for (int r = 0; r < 4; ++r) {
            int row = m0 + wr * 64 + i * 16 + l4 * 4 + r;
            float bv = bias[row];
            #pragma unroll
            for (int j = 0; j < 4; ++j) {
                int col = n0 + wc * 64 + j * 16 + l15;
                out[((size_t)b * C + row) * NSP + col] = acc[i][j][r] + bv;
            }
        }
    }
}

// ---------------------------------------------------------------------------
// q/k projection: 3-pass split-bf16 MFMA GEMM (precision-critical).
// q/k[b,n,m] = sum_k x[b,k,n] Wqk[m,k] + bias  -> bf16 hi/lo pairs
// ---------------------------------------------------------------------------
__global__ __launch_bounds__(256, 2) void gemm_qk_bf16(
    const float* __restrict__ x,
    const unsigned short* __restrict__ Wh,
    const unsigned short* __restrict__ Wl,
    const float* __restrict__ bias0,
    const float* __restrict__ bias1,
    unsigned short* __restrict__ qh, unsigned short* __restrict__ ql,
    unsigned short* __restrict__ kh, unsigned short* __restrict__ kl)
{
    __shared__ short smem[16384];                     // 32 KB
    const int X_HI = 0, X_LO = 4096, W_HI = 8192, W_LO = 12288;

    int tid = threadIdx.x;
    int n0 = blockIdx.x * 128;
    int b  = blockIdx.z;

    int lane = tid & 63, wave = tid >> 6;
    int wr = wave >> 1, wc = wave & 1;
    int l15 = lane & 15, l4 = lane >> 4;

    int tn = tid & 31, tk = tid >> 5;
    int nloc = tn * 4, kloc = tk * 4;
    const float* xp = x + ((size_t)b * KD + kloc) * NSP + n0 + nloc;
    int kg = tk >> 1, khalf = tk & 1;

    f32x4 acc[4][4];
    #pragma unroll
    for (int i = 0; i < 4; ++i)
        #pragma unroll
        for (int j = 0; j < 4; ++j)
            acc[i][j] = (f32x4){0.f, 0.f, 0.f, 0.f};

    for (int k0 = 0; k0 < KD; k0 += 32) {
        float v4[4][4];
        #pragma unroll
        for (int kk = 0; kk < 4; ++kk) {
            float4 t = *(const float4*)(xp + (size_t)(k0 + kk) * NSP);
            v4[kk][0] = t.x; v4[kk][1] = t.y; v4[kk][2] = t.z; v4[kk][3] = t.w;
        }
        #pragma unroll
        for (int nn = 0; nn < 4; ++nn) {
            int n = nloc + nn;
            short4v hi, lo;
            #pragma unroll
            for (int kk = 0; kk < 4; ++kk) {
                float f = v4[kk][nn];
                unsigned short h = f2bf(f);
                hi[kk] = (short)h;
                lo[kk] = (short)f2bf(f - bf2f(h));
            }
            int base = tidx(n, kg) + khalf * 4;
            *(short4v*)&smem[X_HI + base] = hi;
            *(short4v*)&smem[X_LO + base] = lo;
        }
        #pragma unroll
        for (int it = 0; it < 4; ++it) {
            int gi = tid + it * 256;
            int sel = gi >> 9;
            int t = gi & 511;
            int row = t >> 2, kg2 = t & 3;
            if (row < 128) {
                const unsigned short* src = (sel ? Wl : Wh) + (size_t)row * KD + k0 + kg2 * 8;
                bf16x8 d = *(const bf16x8*)src;
                *(bf16x8*)&smem[(sel ? W_LO : W_HI) + tidx(row, kg2)] = d;
            }
        }
        __syncthreads();

        // A = x (rows n), B = W (rows m): 3-pass Ah*Bh + Ah*Bl + Al*Bh
        bf16x8 af[4], bf_[4], bl_[4];
        #pragma unroll
        for (int f = 0; f < 4; ++f) {
            int ra = wr * 64 + f * 16 + l15;
            int rb = wc * 64 + f * 16 + l15;
            af[f]  = *(const bf16x8*)&smem[X_HI + tidx(ra, l4)];
            bf_[f] = *(const bf16x8*)&smem[W_HI + tidx(rb, l4)];
        }
        #pragma unroll
        for (int i = 0; i < 4; ++i)
            #pragma unroll
            for (int j = 0; j < 4; ++j)
                acc[i][j] = __builtin_amdgcn_mfma_f32_16x16x32_bf16(af[i], bf_[j], acc[i][j], 0, 0, 0);
        #pragma unroll
        for (int f = 0; f < 4; ++f) {
            int rb = wc * 64 + f * 16 + l15;
            bl_[f] = *(const bf16x8*)&smem[W_LO + tidx(rb, l4)];
        }
        #pragma unroll
        for (int i = 0; i < 4; ++i)
            #pragma unroll
            for (int j = 0; j < 4; ++j)
                acc[i][j] = __builtin_amdgcn_mfma_f32_16x16x32_bf16(af[i], bl_[j], acc[i][j], 0, 0, 0);
        #pragma unroll
        for (int f = 0; f < 4; ++f) {
            int ra = wr * 64 + f * 16 + l15;
            af[f] = *(const bf16x8*)&smem[X_LO + tidx(ra, l4)];
        }
        #pragma unroll
        for (int i = 0; i < 4; ++i)
            #pragma unroll
            for (int j = 0; j < 4; ++j)
                acc[i][j] = __builtin_amdgcn_mfma_f32_16x16x32_bf16(af[i], bf_[j], acc[i][j], 0, 0, 0);
        __syncthreads();
    }

    #pragma unroll
    for (int i = 0; i < 4; ++i) {
        #pragma unroll
        for (int r = 0; r < 4; ++r) {
            int sp = n0 + wr * 64 + i * 16 + l4 * 4 + r;
            #pragma unroll
            for (int j = 0; j < 4; ++j) {
                int wcol = wc * 64 + j * 16 + l15;
                float val = acc[i][j][r] + (wcol < 64 ? bias0[wcol] : bias1[wcol - 64]);
                unsigned short hi = f2bf(val);
                unsigned short lo = f2bf(val - bf2f(hi));
                size_t off = ((size_t)b * NSP + sp) * 64 + (wcol & 63);
                if (wcol < 64) { qh[off] = hi; ql[off] = lo; }
                else           { kh[off] = hi; kl[off] = lo; }
            }
        }
    }
}

// ---------------------------------------------------------------------------
// Energy MFMA (3-pass bf16, unchanged)
// ---------------------------------------------------------------------------
__global__ __launch_bounds__(256, 2) void energy_mfma(
    const unsigned short* __restrict__ qh, const unsigned short* __restrict__ ql,
    const unsigned short* __restrict__ kh, const unsigned short* __restrict__ kl,
    float* __restrict__ out, int pMul, int rMul)
{
    __shared__ short sm[4 * 96 * 64];   // 48 KB
    const int T_QH = 0, T_QL = 6144, T_KH = 12288, T_KL = 18432;
    int p = blockIdx.x, b = blockIdx.y;
    int tid = threadIdx.x;
    size_t base = ((size_t)b * HW + (size_t)p * pMul) * 64;
    size_t rstride = (size_t)rMul * 64;

    #pragma unroll
    for (int tile = 0; tile < 4; ++tile) {
        const unsigned short* src = (tile == 0) ? qh : (tile == 1) ? ql : (tile == 2) ? kh : kl;
        int tb = tile * 6144;
        #pragma unroll
        for (int sub = 0; sub < 3; ++sub) {
            int s = sub * 256 + tid;
            int row = s >> 3, g = s & 7;
            bf16x8 d = *(const bf16x8*)&src[base + row * rstride + g * 8];
            *(bf16x8*)&sm[tb + tidx64(row, g)] = d;
        }
    }
    __syncthreads();

    int lane = tid & 63, wave = tid >> 6;
    int wr = wave >> 1, wc = wave & 1;
    int l15 = lane & 15, l4 = lane >> 4;

    f32x4 acc[3][3];
    #pragma unroll
    for (int i = 0; i < 3; ++i)
        #pragma unroll
        for (int j = 0; j < 3; ++j)
            acc[i][j] = (f32x4){0.f, 0.f, 0.f, 0.f};

    #pragma unroll
    for (int ks = 0; ks < 2; ++ks) {
        bf16x8 Ah[3], Al[3], Bh[3], Bl[3];
        int gr = ks * 4 + l4;
        #pragma unroll
        for (int i = 0; i < 3; ++i) {
            int ra = wr * 48 + i * 16 + l15;
            int sa = tidx64(ra, gr);
            Ah[i] = *(const bf16x8*)&sm[T_QH + sa];
            Al[i] = *(const bf16x8*)&sm[T_QL + sa];
            int rb = wc * 48 + i * 16 + l15;
            int sb = tidx64(rb, gr);
            Bh[i] = *(const bf16x8*)&sm[T_KH + sb];
            Bl[i] = *(const bf16x8*)&sm[T_KL + sb];
        }
        #pragma unroll
        for (int i = 0; i < 3; ++i)
            #pragma unroll
            for (int j = 0; j < 3; ++j) {
                acc[i][j] = __builtin_amdgcn_mfma_f32_16x16x32_bf16(Ah[i], Bh[j], acc[i][j], 0, 0, 0);
                acc[i][j] = __builtin_amdgcn_mfma_f32_16x16x32_bf16(Ah[i], Bl[j], acc[i][j], 0, 0, 0);
                acc[i][j] = __builtin_amdgcn_mfma_f32_16x16x32_bf16(Al[i], Bh[j], acc[i][j], 0, 0, 0);
            }
    }

    size_t ob = (size_t)(b * 96 + p) * 9216;
    #pragma unroll
    for (int i = 0; i < 3; ++i)
        #pragma unroll
        for (int r = 0; r < 4; ++r) {
            int row = wr * 48 + i * 16 + l4 * 4 + r;
            #pragma unroll
            for (int j = 0; j < 3; ++j) {
                int col = wc * 48 + j * 16 + l15;
                out[ob + (size_t)row * 96 + col] = acc[i][j][r];
            }
        }
}

// ---------------------------------------------------------------------------
// Joint softmax max/sum (unchanged)
// ---------------------------------------------------------------------------
__global__ __launch_bounds__(256) void maxsum(
    const float* __restrict__ EW, const float* __restrict__ EH,
    const float* __restrict__ gamma, float* __restrict__ ms)
{
    int gw = (blockIdx.x * 256 + threadIdx.x) >> 6;
    int lane = threadIdx.x & 63;
    int b = gw / HW, hw = gw % HW;
    int h = hw / 96, w = hw % 96;
    const float* ew = &EW[((size_t)(b * 96 + h) * 96 + w) * 96];
    const float* eh = &EH[((size_t)(b * 96 + w) * 96 + h) * 96];
    float v0 = ew[lane];
    float v1 = (lane < 32) ? ew[64 + lane] : eh[lane - 32];
    float v2 = eh[32 + lane];
    float m = fmaxf(fmaxf(v0, v1), v2);
    #pragma unroll
    for (int s = 32; s; s >>= 1) m = fmaxf(m, __shfl_xor(m, s));
    float pp = __expf(v0 - m) + __expf(v1 - m) + __expf(v2 - m);
    #pragma unroll
    for (int s = 32; s; s >>= 1) pp += __shfl_xor(pp, s);
    if (lane == 0) {
        ms[(size_t)gw * 2]     = m;
        ms[(size_t)gw * 2 + 1] = gamma[0] / pp;
    }
}

// ---------------------------------------------------------------------------
// MFMA aggregation, 2-pass fp16: att single tile, v hi/lo.
// dst[b,c0+cl,r,s] = sum_j Ph[s,j] * (vh+vl)[cl,j]
// ---------------------------------------------------------------------------
__global__ __launch_bounds__(256, 2) void agg_mfma(
    const float* __restrict__ E, const float* __restrict__ ms,
    const float* vsrc, float* dst, int msMode)
{
    __shared__ _Float16 satt[3][96 * 32];   // 18 KB  [kchunk][tidx(s,g)]
    __shared__ _Float16 sv[2][128 * 32];    // 16 KB  [hi/lo][tidx(cl,g)]

    int r  = blockIdx.x;
    int c0 = blockIdx.y * 128;
    int b  = blockIdx.z;
    int tid = threadIdx.x;
    int lane = tid & 63, wave = tid >> 6;
    int l15 = lane & 15, l4 = lane >> 4;

    // ---- stage att: exp-normalize to fp16, K-chunked swizzled LDS ----
    const float* Eb = &E[(size_t)(b * 96 + r) * 9216];
    int msBase = b * HW;
    #pragma unroll
    for (int it = 0; it < 5; ++it) {
        int g_id = tid + it * 256;
        if (g_id < 1152) {
            int s = g_id / 12, gj = g_id % 12;
            int mi = msMode ? (msBase + s * 96 + r) : (msBase + r * 96 + s);
            float m  = ms[(size_t)mi * 2];
            float sc = ms[(size_t)mi * 2 + 1];
            float4 e0 = *(const float4*)&Eb[s * 96 + gj * 8];
            float4 e1 = *(const float4*)&Eb[s * 96 + gj * 8 + 4];
            float pv[8] = {e0.x, e0.y, e0.z, e0.w, e1.x, e1.y, e1.z, e1.w};
            f16x8 ph;
            #pragma unroll
            for (int u = 0; u < 8; ++u)
                ph[u] = (_Float16)(__expf(pv[u] - m) * sc);
            *(f16x8*)&satt[gj >> 2][tidx(s, gj & 3)] = ph;
        }
    }

    const float* vb = &vsrc[(((size_t)b * C + c0) * 96 + r) * 96];
    int vrow = tid >> 1, jh = tid & 1;
    const float* vpb = vb + (size_t)vrow * 9216 + jh * 16;

    f32x4 acc[2][6];
    #pragma unroll
    for (int i = 0; i < 2; ++i)
        #pragma unroll
        for (int n = 0; n < 6; ++n)
            acc[i][n] = (f32x4){0.f, 0.f, 0.f, 0.f};

    for (int kc = 0; kc < 3; ++kc) {
        float4 f0 = *(const float4*)(vpb + kc * 32);
        float4 f1 = *(const float4*)(vpb + kc * 32 + 4);
        float4 f2 = *(const float4*)(vpb + kc * 32 + 8);
        float4 f3 = *(const float4*)(vpb + kc * 32 + 12);
        float fv[16] = {f0.x, f0.y, f0.z, f0.w, f1.x, f1.y, f1.z, f1.w,
                        f2.x, f2.y, f2.z, f2.w, f3.x, f3.y, f3.z, f3.w};
        __syncthreads();   // prior iteration's MFMA reads done
        #pragma unroll
        for (int gg = 0; gg < 2; ++gg) {
            f16x8 hi, lo;
            #pragma unroll
            for (int u = 0; u < 8; ++u) {
                float f = fv[gg * 8 + u];
                _Float16 hh = (_Float16)f;
                hi[u] = hh;
                lo[u] = (_Float16)(f - (float)hh);
            }
            int pos = tidx(vrow, jh * 2 + gg);
            *(f16x8*)&sv[0][pos] = hi;
            *(f16x8*)&sv[1][pos] = lo;
        }
        __syncthreads();

        f16x8 Bp[6];
        #pragma unroll
        for (int n = 0; n < 6; ++n)
            Bp[n] = *(const f16x8*)&satt[kc][tidx(n * 16 + l15, l4)];
        f16x8 Ah[2], Al[2];
        #pragma unroll
        for (int i = 0; i < 2; ++i) {
            int pos = tidx(wave * 32 + i * 16 + l15, l4);
            Ah[i] = *(const f16x8*)&sv[0][pos];
            Al[i] = *(const f16x8*)&sv[1][pos];
        }
        #pragma unroll
        for (int i = 0; i < 2; ++i)
            #pragma unroll
            for (int n = 0; n < 6; ++n) {
                acc[i][n] = __builtin_amdgcn_mfma_f32_16x16x32_f16(Ah[i], Bp[n], acc[i][n], 0, 0, 0);
                acc[i][n] = __builtin_amdgcn_mfma_f32_16x16x32_f16(Al[i], Bp[n], acc[i][n], 0, 0, 0);
            }
    }

    float* db = &dst[(((size_t)b * C + c0) * 96 + r) * 96];
    #pragma unroll
    for (int i = 0; i < 2; ++i)
        #pragma unroll
        for (int r4 = 0; r4 < 4; ++r4) {
            int cl = wave * 32 + i * 16 + l4 * 4 + r4;
            #pragma unroll
            for (int n = 0; n < 6; ++n) {
                int s = n * 16 + l15;
                db[(size_t)cl * 9216 + s] = acc[i][n][r4];
            }
        }
}

__global__ __launch_bounds__(256) void transpose_inplace(float* __restrict__ v)
{
    size_t base = (size_t)blockIdx.x * (96 * 96);
    __shared__ float t[96][97];
    int tid = threadIdx.x;
    for (int i = tid; i < 96 * 96; i += 256) t[i / 96][i % 96] = v[base + i];
    __syncthreads();
    for (int i = tid; i < 96 * 96; i += 256) v[base + i] = t[i % 96][i / 96];
}

__global__ __launch_bounds__(256) void transpose_add(
    const float* __restrict__ outT, float* __restrict__ out)
{
    size_t base = (size_t)blockIdx.x * (96 * 96);
    __shared__ float t[96][97];
    int tid = threadIdx.x;
    for (int i = tid; i < 96 * 96; i += 256) t[i / 96][i % 96] = outT[base + i];
    __syncthreads();
    for (int i = tid; i < 96 * 96; i += 256) out[base + i] += t[i % 96][i / 96];
}

// ---------------------------------------------------------------------------
extern "C" void kernel_launch(void* const* d_in, const int* in_sizes, int n_in,
                              void* d_out, int out_size, void* d_ws, size_t ws_size,
                              hipStream_t stream)
{
    const float* x     = (const float*)d_in[0];
    const float* Wq    = (const float*)d_in[1];
    const float* bq    = (const float*)d_in[2];
    const float* Wk    = (const float*)d_in[3];
    const float* bk    = (const float*)d_in[4];
    const float* Wv    = (const float*)d_in[5];
    const float* bv    = (const float*)d_in[6];
    const float* gamma = (const float*)d_in[7];
    float* out = (float*)d_out;

    unsigned short* qh = (unsigned short*)d_ws;          // B*HW*64 bf16
    unsigned short* ql = qh + (size_t)B*HW*64;
    unsigned short* kh = ql + (size_t)B*HW*64;
    unsigned short* kl = kh + (size_t)B*HW*64;
    float* v    = (float*)(kl + (size_t)B*HW*64);        // (B,C,H,W) 151 MB
    float* EH   = v  + (size_t)B*C*HW;                   // (B,W,H,96) 28.3 MB
    float* EW   = EH + (size_t)B*HW*96;                  // (B,H,W,96) 28.3 MB
    float* ms   = (float*)d_ws;                          // aliases qh (dead after energies)

    _Float16* Wv_h = (_Float16*)EW;                      // splits alias EW (dead until energy W-mode)
    unsigned short* Wqk_hi = (unsigned short*)(Wv_h + (size_t)C*C);
    unsigned short* Wqk_lo = Wqk_hi + (size_t)128*C;

    dim3 blk(256);

    split_w<<<dim3((C*C + 255)/256), blk, 0, stream>>>(Wv, Wq, Wk, Wv_h, Wqk_hi, Wqk_lo);

    gemm_v_f16<<<dim3(NSP/128, C/128, B), blk, 0, stream>>>(x, Wv_h, bv, v);
    gemm_qk_bf16<<<dim3(NSP/128, 1, B), blk, 0, stream>>>(x, Wqk_hi, Wqk_lo, bq, bk, qh, ql, kh, kl);

    energy_mfma<<<dim3(96, B), blk, 0, stream>>>(qh, ql, kh, kl, EW, 96, 1);
    energy_mfma<<<dim3(96, B), blk, 0, stream>>>(qh, ql, kh, kl, EH, 1, 96);

    maxsum<<<dim3(B*HW/4), blk, 0, stream>>>(EW, EH, gamma, ms);

    agg_mfma<<<dim3(96, 4, B), blk, 0, stream>>>(EW, ms, v, out, 0);
    transpose_inplace<<<dim3(B*C), blk, 0, stream>>>(v);
    agg_mfma<<<dim3(96, 4, B), blk, 0, stream>>>(EH, ms, v, v, 1);
    transpose_add<<<dim3(B*C), blk, 0, stream>>>(v, out);
}

// Round 6
// 487.107 us; speedup vs baseline: 4.0689x; 1.0744x over previous
//
#include <hip/hip_runtime.h>

#define B 8
#define C 512
#define H 96
#define W 96
#define HW (H*W)       // 9216
#define KD 512
#define NSP 9216

typedef __attribute__((ext_vector_type(8))) short bf16x8;
typedef __attribute__((ext_vector_type(4))) short short4v;
typedef __attribute__((ext_vector_type(4))) float f32x4;
typedef __attribute__((ext_vector_type(8))) _Float16 f16x8;
typedef __attribute__((ext_vector_type(4))) _Float16 f16x4v;

static __device__ __forceinline__ unsigned short f2bf(float f) {
    unsigned u = __float_as_uint(f);
    return (unsigned short)((u + 0x7FFFu + ((u >> 16) & 1u)) >> 16);
}
static __device__ __forceinline__ float bf2f(unsigned short h) {
    return __uint_as_float(((unsigned)h) << 16);
}
// swizzle for [rows][32-elem] tiles (64B rows, 4 granules of 8 elems).
// (row>>2) variant: spreads the stride-4-row transpose stores 8-ways
// (granule 4 x khalf 2) instead of 4 -> halves store serialization.
// Fragment reads (16 consecutive rows, fixed granule) stay <=2-way.
static __device__ __forceinline__ int tidx(int row, int kgrp) {
    return row * 32 + ((kgrp ^ ((row >> 2) & 3)) << 3);
}
// swizzle for [rows][64-elem] tiles (128B rows, 8 granules) - energy kernel
static __device__ __forceinline__ int tidx64(int row, int gr) {
    return row * 64 + ((gr ^ (row & 7)) << 3);
}

// ---------------------------------------------------------------------------
// Split weights: Wv -> fp16 (single); Wqk = [Wq;Wk] -> bf16 hi/lo.
// ---------------------------------------------------------------------------
__global__ __launch_bounds__(256) void split_w(
    const float* __restrict__ Wv, const float* __restrict__ Wq, const float* __restrict__ Wk,
    _Float16* __restrict__ Wv_h,
    unsigned short* __restrict__ Wqk_hi, unsigned short* __restrict__ Wqk_lo)
{
    int i = blockIdx.x * 256 + threadIdx.x;
    if (i < C * C) {
        Wv_h[i] = (_Float16)Wv[i];
    }
    if (i < 128 * C) {
        int m = i / C, k = i % C;
        float f = (m < 64) ? Wq[m * C + k] : Wk[(m - 64) * C + k];
        unsigned short h = f2bf(f);
        Wqk_hi[i] = h;
        Wqk_lo[i] = f2bf(f - bf2f(h));
    }
}

// ---------------------------------------------------------------------------
// v projection: 2-pass split-fp16 MFMA GEMM, prefetched staging.
// out[b,m,n] = sum_k Wv[m,k] x[b,k,n] + bias[m]   -> (B,C,HW) fp32
// ---------------------------------------------------------------------------
__global__ __launch_bounds__(256, 2) void gemm_v_f16(
    const float* __restrict__ x,
    const _Float16* __restrict__ Wh,
    const float* __restrict__ bias,
    float* __restrict__ out)
{
    __shared__ _Float16 smem[12288];                  // 24 KB
    const int X_HI = 0, X_LO = 4096, W_H = 8192;

    int tid = threadIdx.x;
    int n0 = blockIdx.x * 128;
    int m0 = blockIdx.y * 128;
    int b  = blockIdx.z;

    int lane = tid & 63, wave = tid >> 6;
    int wr = wave >> 1, wc = wave & 1;
    int l15 = lane & 15, l4 = lane >> 4;

    int tn = tid & 31, tk = tid >> 5;
    int nloc = tn * 4, kloc = tk * 4;
    const float* xp = x + ((size_t)b * KD + kloc) * NSP + n0 + nloc;
    int kg = tk >> 1, khalf = tk & 1;

    // W staging: thread handles 2 granules per K-step
    int wrow0 = tid >> 2, wkg0 = tid & 3;             // granules 0..255
    int wrow1 = (tid + 256) >> 2, wkg1 = (tid + 256) & 3;
    const _Float16* wp0 = Wh + (size_t)(m0 + wrow0) * KD + wkg0 * 8;
    const _Float16* wp1 = Wh + (size_t)(m0 + wrow1) * KD + wkg1 * 8;

    f32x4 acc[4][4];
    #pragma unroll
    for (int i = 0; i < 4; ++i)
        #pragma unroll
        for (int j = 0; j < 4; ++j)
            acc[i][j] = (f32x4){0.f, 0.f, 0.f, 0.f};

    // prologue: prefetch first tiles
    float4 t4[4];
    f16x8 wv0, wv1;
    #pragma unroll
    for (int kk = 0; kk < 4; ++kk) t4[kk] = *(const float4*)(xp + (size_t)kk * NSP);
    wv0 = *(const f16x8*)wp0;
    wv1 = *(const f16x8*)wp1;

    for (int k0 = 0; k0 < KD; k0 += 32) {
        // ---- issue next-tile global loads (T14: hide latency under MFMA) ----
        float4 t4n[4];
        f16x8 wv0n, wv1n;
        if (k0 + 32 < KD) {
            #pragma unroll
            for (int kk = 0; kk < 4; ++kk)
                t4n[kk] = *(const float4*)(xp + (size_t)(k0 + 32 + kk) * NSP);
            wv0n = *(const f16x8*)(wp0 + k0 + 32);
            wv1n = *(const f16x8*)(wp1 + k0 + 32);
        }
        // ---- stage current x tile: split fp16 hi/lo, transpose to [n][k] ----
        #pragma unroll
        for (int nn = 0; nn < 4; ++nn) {
            int n = nloc + nn;
            f16x4v hi, lo;
            #pragma unroll
            for (int kk = 0; kk < 4; ++kk) {
                float f = ((const float*)&t4[kk])[nn];
                _Float16 hh = (_Float16)f;
                hi[kk] = hh;
                lo[kk] = (_Float16)(f - (float)hh);
            }
            int base = tidx(n, kg) + khalf * 4;
            *(f16x4v*)&smem[X_HI + base] = hi;
            *(f16x4v*)&smem[X_LO + base] = lo;
        }
        // ---- stage current W tile ----
        *(f16x8*)&smem[W_H + tidx(wrow0, wkg0)] = wv0;
        *(f16x8*)&smem[W_H + tidx(wrow1, wkg1)] = wv1;
        __syncthreads();

        f16x8 af[4], bh_[4], bl_[4];
        #pragma unroll
        for (int f = 0; f < 4; ++f) {
            int ra = wr * 64 + f * 16 + l15;       // W rows (m)
            int rb = wc * 64 + f * 16 + l15;       // x rows (n)
            af[f]  = *(const f16x8*)&smem[W_H  + tidx(ra, l4)];
            bh_[f] = *(const f16x8*)&smem[X_HI + tidx(rb, l4)];
        }
        #pragma unroll
        for (int i = 0; i < 4; ++i)
            #pragma unroll
            for (int j = 0; j < 4; ++j)
                acc[i][j] = __builtin_amdgcn_mfma_f32_16x16x32_f16(af[i], bh_[j], acc[i][j], 0, 0, 0);
        #pragma unroll
        for (int f = 0; f < 4; ++f) {
            int rb = wc * 64 + f * 16 + l15;
            bl_[f] = *(const f16x8*)&smem[X_LO + tidx(rb, l4)];
        }
        #pragma unroll
        for (int i = 0; i < 4; ++i)
            #pragma unroll
            for (int j = 0; j < 4; ++j)
                acc[i][j] = __builtin_amdgcn_mfma_f32_16x16x32_f16(af[i], bl_[j], acc[i][j], 0, 0, 0);
        __syncthreads();

        #pragma unroll
        for (int kk = 0; kk < 4; ++kk) t4[kk] = t4n[kk];
        wv0 = wv0n; wv1 = wv1n;
    }

    #pragma unroll
    for (int i = 0; i < 4; ++i) {
        #pragma unroll
        for (int r = 0; r < 4; ++r) {
            int row = m0 + wr * 64 + i * 16 + l4 * 4 + r;
            float bv = bias[row];
            #pragma unroll
            for (int j = 0; j < 4; ++j) {
                int col = n0 + wc * 64 + j * 16 + l15;
                out[((size_t)b * C + row) * NSP + col] = acc[i][j][r] + bv;
            }
        }
    }
}

// ---------------------------------------------------------------------------
// q/k projection: 3-pass split-bf16 MFMA GEMM, prefetched staging.
// q/k[b,n,m] = sum_k x[b,k,n] Wqk[m,k] + bias  -> bf16 hi/lo pairs
// ---------------------------------------------------------------------------
__global__ __launch_bounds__(256, 2) void gemm_qk_bf16(
    const float* __restrict__ x,
    const unsigned short* __restrict__ Wh,
    const unsigned short* __restrict__ Wl,
    const float* __restrict__ bias0,
    const float* __restrict__ bias1,
    unsigned short* __restrict__ qh, unsigned short* __restrict__ ql,
    unsigned short* __restrict__ kh, unsigned short* __restrict__ kl)
{
    __shared__ short smem[16384];                     // 32 KB
    const int X_HI = 0, X_LO = 4096, W_HI = 8192, W_LO = 12288;

    int tid = threadIdx.x;
    int n0 = blockIdx.x * 128;
    int b  = blockIdx.z;

    int lane = tid & 63, wave = tid >> 6;
    int wr = wave >> 1, wc = wave & 1;
    int l15 = lane & 15, l4 = lane >> 4;

    int tn = tid & 31, tk = tid >> 5;
    int nloc = tn * 4, kloc = tk * 4;
    const float* xp = x + ((size_t)b * KD + kloc) * NSP + n0 + nloc;
    int kg = tk >> 1, khalf = tk & 1;

    // W staging: 1024 granules (hi 512 + lo 512), 4 per thread
    int wrow[4], wkg[4];
    const unsigned short* wp[4];
    #pragma unroll
    for (int it = 0; it < 4; ++it) {
        int gi = tid + it * 256;
        int sel = gi >> 9;
        int t = gi & 511;
        wrow[it] = t >> 2; wkg[it] = t & 3;
        wp[it] = (sel ? Wl : Wh) + (size_t)wrow[it] * KD + wkg[it] * 8;
    }
    int wdst[4];
    #pragma unroll
    for (int it = 0; it < 4; ++it)
        wdst[it] = ((tid + it * 256) >> 9 ? W_LO : W_HI) + tidx(wrow[it], wkg[it]);

    f32x4 acc[4][4];
    #pragma unroll
    for (int i = 0; i < 4; ++i)
        #pragma unroll
        for (int j = 0; j < 4; ++j)
            acc[i][j] = (f32x4){0.f, 0.f, 0.f, 0.f};

    float4 t4[4];
    bf16x8 wv[4];
    #pragma unroll
    for (int kk = 0; kk < 4; ++kk) t4[kk] = *(const float4*)(xp + (size_t)kk * NSP);
    #pragma unroll
    for (int it = 0; it < 4; ++it) wv[it] = *(const bf16x8*)wp[it];

    for (int k0 = 0; k0 < KD; k0 += 32) {
        float4 t4n[4];
        bf16x8 wvn[4];
        if (k0 + 32 < KD) {
            #pragma unroll
            for (int kk = 0; kk < 4; ++kk)
                t4n[kk] = *(const float4*)(xp + (size_t)(k0 + 32 + kk) * NSP);
            #pragma unroll
            for (int it = 0; it < 4; ++it)
                wvn[it] = *(const bf16x8*)(wp[it] + k0 + 32);
        }
        #pragma unroll
        for (int nn = 0; nn < 4; ++nn) {
            int n = nloc + nn;
            short4v hi, lo;
            #pragma unroll
            for (int kk = 0; kk < 4; ++kk) {
                float f = ((const float*)&t4[kk])[nn];
                unsigned short h = f2bf(f);
                hi[kk] = (short)h;
                lo[kk] = (short)f2bf(f - bf2f(h));
            }
            int base = tidx(n, kg) + khalf * 4;
            *(short4v*)&smem[X_HI + base] = hi;
            *(short4v*)&smem[X_LO + base] = lo;
        }
        #pragma unroll
        for (int it = 0; it < 4; ++it)
            *(bf16x8*)&smem[wdst[it]] = wv[it];
        __syncthreads();

        // A = x (rows n), B = W (rows m): 3-pass Ah*Bh + Ah*Bl + Al*Bh
        bf16x8 af[4], bf_[4], bl_[4];
        #pragma unroll
        for (int f = 0; f < 4; ++f) {
            int ra = wr * 64 + f * 16 + l15;
            int rb = wc * 64 + f * 16 + l15;
            af[f]  = *(const bf16x8*)&smem[X_HI + tidx(ra, l4)];
            bf_[f] = *(const bf16x8*)&smem[W_HI + tidx(rb, l4)];
        }
        #pragma unroll
        for (int i = 0; i < 4; ++i)
            #pragma unroll
            for (int j = 0; j < 4; ++j)
                acc[i][j] = __builtin_amdgcn_mfma_f32_16x16x32_bf16(af[i], bf_[j], acc[i][j], 0, 0, 0);
        #pragma unroll
        for (int f = 0; f < 4; ++f) {
            int rb = wc * 64 + f * 16 + l15;
            bl_[f] = *(const bf16x8*)&smem[W_LO + tidx(rb, l4)];
        }
        #pragma unroll
        for (int i = 0; i < 4; ++i)
            #pragma unroll
            for (int j = 0; j < 4; ++j)
                acc[i][j] = __builtin_amdgcn_mfma_f32_16x16x32_bf16(af[i], bl_[j], acc[i][j], 0, 0, 0);
        #pragma unroll
        for (int f = 0; f < 4; ++f) {
            int ra = wr * 64 + f * 16 + l15;
            af[f] = *(const bf16x8*)&smem[X_LO + tidx(ra, l4)];
        }
        #pragma unroll
        for (int i = 0; i < 4; ++i)
            #pragma unroll
            for (int j = 0; j < 4; ++j)
                acc[i][j] = __builtin_amdgcn_mfma_f32_16x16x32_bf16(af[i], bf_[j], acc[i][j], 0, 0, 0);
        __syncthreads();

        #pragma unroll
        for (int kk = 0; kk < 4; ++kk) t4[kk] = t4n[kk];
        #pragma unroll
        for (int it = 0; it < 4; ++it) wv[it] = wvn[it];
    }

    #pragma unroll
    for (int i = 0; i < 4; ++i) {
        #pragma unroll
        for (int r = 0; r < 4; ++r) {
            int sp = n0 + wr * 64 + i * 16 + l4 * 4 + r;
            #pragma unroll
            for (int j = 0; j < 4; ++j) {
                int wcol = wc * 64 + j * 16 + l15;
                float val = acc[i][j][r] + (wcol < 64 ? bias0[wcol] : bias1[wcol - 64]);
                unsigned short hi = f2bf(val);
                unsigned short lo = f2bf(val - bf2f(hi));
                size_t off = ((size_t)b * NSP + sp) * 64 + (wcol & 63);
                if (wcol < 64) { qh[off] = hi; ql[off] = lo; }
                else           { kh[off] = hi; kl[off] = lo; }
            }
        }
    }
}

// ---------------------------------------------------------------------------
// Energy MFMA (3-pass bf16, unchanged)
// ---------------------------------------------------------------------------
__global__ __launch_bounds__(256, 2) void energy_mfma(
    const unsigned short* __restrict__ qh, const unsigned short* __restrict__ ql,
    const unsigned short* __restrict__ kh, const unsigned short* __restrict__ kl,
    float* __restrict__ out, int pMul, int rMul)
{
    __shared__ short sm[4 * 96 * 64];   // 48 KB
    const int T_QH = 0, T_QL = 6144, T_KH = 12288, T_KL = 18432;
    int p = blockIdx.x, b = blockIdx.y;
    int tid = threadIdx.x;
    size_t base = ((size_t)b * HW + (size_t)p * pMul) * 64;
    size_t rstride = (size_t)rMul * 64;

    #pragma unroll
    for (int tile = 0; tile < 4; ++tile) {
        const unsigned short* src = (tile == 0) ? qh : (tile == 1) ? ql : (tile == 2) ? kh : kl;
        int tb = tile * 6144;
        #pragma unroll
        for (int sub = 0; sub < 3; ++sub) {
            int s = sub * 256 + tid;
            int row = s >> 3, g = s & 7;
            bf16x8 d = *(const bf16x8*)&src[base + row * rstride + g * 8];
            *(bf16x8*)&sm[tb + tidx64(row, g)] = d;
        }
    }
    __syncthreads();

    int lane = tid & 63, wave = tid >> 6;
    int wr = wave >> 1, wc = wave & 1;
    int l15 = lane & 15, l4 = lane >> 4;

    f32x4 acc[3][3];
    #pragma unroll
    for (int i = 0; i < 3; ++i)
        #pragma unroll
        for (int j = 0; j < 3; ++j)
            acc[i][j] = (f32x4){0.f, 0.f, 0.f, 0.f};

    #pragma unroll
    for (int ks = 0; ks < 2; ++ks) {
        bf16x8 Ah[3], Al[3], Bh[3], Bl[3];
        int gr = ks * 4 + l4;
        #pragma unroll
        for (int i = 0; i < 3; ++i) {
            int ra = wr * 48 + i * 16 + l15;
            int sa = tidx64(ra, gr);
            Ah[i] = *(const bf16x8*)&sm[T_QH + sa];
            Al[i] = *(const bf16x8*)&sm[T_QL + sa];
            int rb = wc * 48 + i * 16 + l15;
            int sb = tidx64(rb, gr);
            Bh[i] = *(const bf16x8*)&sm[T_KH + sb];
            Bl[i] = *(const bf16x8*)&sm[T_KL + sb];
        }
        #pragma unroll
        for (int i = 0; i < 3; ++i)
            #pragma unroll
            for (int j = 0; j < 3; ++j) {
                acc[i][j] = __builtin_amdgcn_mfma_f32_16x16x32_bf16(Ah[i], Bh[j], acc[i][j], 0, 0, 0);
                acc[i][j] = __builtin_amdgcn_mfma_f32_16x16x32_bf16(Ah[i], Bl[j], acc[i][j], 0, 0, 0);
                acc[i][j] = __builtin_amdgcn_mfma_f32_16x16x32_bf16(Al[i], Bh[j], acc[i][j], 0, 0, 0);
            }
    }

    size_t ob = (size_t)(b * 96 + p) * 9216;
    #pragma unroll
    for (int i = 0; i < 3; ++i)
        #pragma unroll
        for (int r = 0; r < 4; ++r) {
            int row = wr * 48 + i * 16 + l4 * 4 + r;
            #pragma unroll
            for (int j = 0; j < 3; ++j) {
                int col = wc * 48 + j * 16 + l15;
                out[ob + (size_t)row * 96 + col] = acc[i][j][r];
            }
        }
}

// ---------------------------------------------------------------------------
// Joint softmax max/sum (unchanged)
// ---------------------------------------------------------------------------
__global__ __launch_bounds__(256) void maxsum(
    const float* __restrict__ EW, const float* __restrict__ EH,
    const float* __restrict__ gamma, float* __restrict__ ms)
{
    int gw = (blockIdx.x * 256 + threadIdx.x) >> 6;
    int lane = threadIdx.x & 63;
    int b = gw / HW, hw = gw % HW;
    int h = hw / 96, w = hw % 96;
    const float* ew = &EW[((size_t)(b * 96 + h) * 96 + w) * 96];
    const float* eh = &EH[((size_t)(b * 96 + w) * 96 + h) * 96];
    float v0 = ew[lane];
    float v1 = (lane < 32) ? ew[64 + lane] : eh[lane - 32];
    float v2 = eh[32 + lane];
    float m = fmaxf(fmaxf(v0, v1), v2);
    #pragma unroll
    for (int s = 32; s; s >>= 1) m = fmaxf(m, __shfl_xor(m, s));
    float pp = __expf(v0 - m) + __expf(v1 - m) + __expf(v2 - m);
    #pragma unroll
    for (int s = 32; s; s >>= 1) pp += __shfl_xor(pp, s);
    if (lane == 0) {
        ms[(size_t)gw * 2]     = m;
        ms[(size_t)gw * 2 + 1] = gamma[0] / pp;
    }
}

// ---------------------------------------------------------------------------
// MFMA aggregation, 2-pass fp16 (unchanged from R5 except shared tidx)
// ---------------------------------------------------------------------------
__global__ __launch_bounds__(256, 2) void agg_mfma(
    const float* __restrict__ E, const float* __restrict__ ms,
    const float* vsrc, float* dst, int msMode)
{
    __shared__ _Float16 satt[3][96 * 32];   // 18 KB
    __shared__ _Float16 sv[2][128 * 32];    // 16 KB

    int r  = blockIdx.x;
    int c0 = blockIdx.y * 128;
    int b  = blockIdx.z;
    int tid = threadIdx.x;
    int lane = tid & 63, wave = tid >> 6;
    int l15 = lane & 15, l4 = lane >> 4;

    const float* Eb = &E[(size_t)(b * 96 + r) * 9216];
    int msBase = b * HW;
    #pragma unroll
    for (int it = 0; it < 5; ++it) {
        int g_id = tid + it * 256;
        if (g_id < 1152) {
            int s = g_id / 12, gj = g_id % 12;
            int mi = msMode ? (msBase + s * 96 + r) : (msBase + r * 96 + s);
            float m  = ms[(size_t)mi * 2];
            float sc = ms[(size_t)mi * 2 + 1];
            float4 e0 = *(const float4*)&Eb[s * 96 + gj * 8];
            float4 e1 = *(const float4*)&Eb[s * 96 + gj * 8 + 4];
            float pv[8] = {e0.x, e0.y, e0.z, e0.w, e1.x, e1.y, e1.z, e1.w};
            f16x8 ph;
            #pragma unroll
            for (int u = 0; u < 8; ++u)
                ph[u] = (_Float16)(__expf(pv[u] - m) * sc);
            *(f16x8*)&satt[gj >> 2][tidx(s, gj & 3)] = ph;
        }
    }

    const float* vb = &vsrc[(((size_t)b * C + c0) * 96 + r) * 96];
    int vrow = tid >> 1, jh = tid & 1;
    const float* vpb = vb + (size_t)vrow * 9216 + jh * 16;

    f32x4 acc[2][6];
    #pragma unroll
    for (int i = 0; i < 2; ++i)
        #pragma unroll
        for (int n = 0; n < 6; ++n)
            acc[i][n] = (f32x4){0.f, 0.f, 0.f, 0.f};

    for (int kc = 0; kc < 3; ++kc) {
        float4 f0 = *(const float4*)(vpb + kc * 32);
        float4 f1 = *(const float4*)(vpb + kc * 32 + 4);
        float4 f2 = *(const float4*)(vpb + kc * 32 + 8);
        float4 f3 = *(const float4*)(vpb + kc * 32 + 12);
        float fv[16] = {f0.x, f0.y, f0.z, f0.w, f1.x, f1.y, f1.z, f1.w,
                        f2.x, f2.y, f2.z, f2.w, f3.x, f3.y, f3.z, f3.w};
        __syncthreads();
        #pragma unroll
        for (int gg = 0; gg < 2; ++gg) {
            f16x8 hi, lo;
            #pragma unroll
            for (int u = 0; u < 8; ++u) {
                float f = fv[gg * 8 + u];
                _Float16 hh = (_Float16)f;
                hi[u] = hh;
                lo[u] = (_Float16)(f - (float)hh);
            }
            int pos = tidx(vrow, jh * 2 + gg);
            *(f16x8*)&sv[0][pos] = hi;
            *(f16x8*)&sv[1][pos] = lo;
        }
        __syncthreads();

        f16x8 Bp[6];
        #pragma unroll
        for (int n = 0; n < 6; ++n)
            Bp[n] = *(const f16x8*)&satt[kc][tidx(n * 16 + l15, l4)];
        f16x8 Ah[2], Al[2];
        #pragma unroll
        for (int i = 0; i < 2; ++i) {
            int pos = tidx(wave * 32 + i * 16 + l15, l4);
            Ah[i] = *(const f16x8*)&sv[0][pos];
            Al[i] = *(const f16x8*)&sv[1][pos];
        }
        #pragma unroll
        for (int i = 0; i < 2; ++i)
            #pragma unroll
            for (int n = 0; n < 6; ++n) {
                acc[i][n] = __builtin_amdgcn_mfma_f32_16x16x32_f16(Ah[i], Bp[n], acc[i][n], 0, 0, 0);
                acc[i][n] = __builtin_amdgcn_mfma_f32_16x16x32_f16(Al[i], Bp[n], acc[i][n], 0, 0, 0);
            }
    }

    float* db = &dst[(((size_t)b * C + c0) * 96 + r) * 96];
    #pragma unroll
    for (int i = 0; i < 2; ++i)
        #pragma unroll
        for (int r4 = 0; r4 < 4; ++r4) {
            int cl = wave * 32 + i * 16 + l4 * 4 + r4;
            #pragma unroll
            for (int n = 0; n < 6; ++n) {
                int s = n * 16 + l15;
                db[(size_t)cl * 9216 + s] = acc[i][n][r4];
            }
        }
}

__global__ __launch_bounds__(256) void transpose_inplace(float* __restrict__ v)
{
    size_t base = (size_t)blockIdx.x * (96 * 96);
    __shared__ float t[96][97];
    int tid = threadIdx.x;
    for (int i = tid; i < 96 * 96; i += 256) t[i / 96][i % 96] = v[base + i];
    __syncthreads();
    for (int i = tid; i < 96 * 96; i += 256) v[base + i] = t[i % 96][i / 96];
}

__global__ __launch_bounds__(256) void transpose_add(
    const float* __restrict__ outT, float* __restrict__ out)
{
    size_t base = (size_t)blockIdx.x * (96 * 96);
    __shared__ float t[96][97];
    int tid = threadIdx.x;
    for (int i = tid; i < 96 * 96; i += 256) t[i / 96][i % 96] = outT[base + i];
    __syncthreads();
    for (int i = tid; i < 96 * 96; i += 256) out[base + i] += t[i % 96][i / 96];
}

// ---------------------------------------------------------------------------
extern "C" void kernel_launch(void* const* d_in, const int* in_sizes, int n_in,
                              void* d_out, int out_size, void* d_ws, size_t ws_size,
                              hipStream_t stream)
{
    const float* x     = (const float*)d_in[0];
    const float* Wq    = (const float*)d_in[1];
    const float* bq    = (const float*)d_in[2];
    const float* Wk    = (const float*)d_in[3];
    const float* bk    = (const float*)d_in[4];
    const float* Wv    = (const float*)d_in[5];
    const float* bv    = (const float*)d_in[6];
    const float* gamma = (const float*)d_in[7];
    float* out = (float*)d_out;

    unsigned short* qh = (unsigned short*)d_ws;          // B*HW*64 bf16
    unsigned short* ql = qh + (size_t)B*HW*64;
    unsigned short* kh = ql + (size_t)B*HW*64;
    unsigned short* kl = kh + (size_t)B*HW*64;
    float* v    = (float*)(kl + (size_t)B*HW*64);        // (B,C,H,W) 151 MB
    float* EH   = v  + (size_t)B*C*HW;                   // (B,W,H,96) 28.3 MB
    float* EW   = EH + (size_t)B*HW*96;                  // (B,H,W,96) 28.3 MB
    float* ms   = (float*)d_ws;                          // aliases qh (dead after energies)

    _Float16* Wv_h = (_Float16*)EW;                      // splits alias EW
    unsigned short* Wqk_hi = (unsigned short*)(Wv_h + (size_t)C*C);
    unsigned short* Wqk_lo = Wqk_hi + (size_t)128*C;

    dim3 blk(256);

    split_w<<<dim3((C*C + 255)/256), blk, 0, stream>>>(Wv, Wq, Wk, Wv_h, Wqk_hi, Wqk_lo);

    gemm_v_f16<<<dim3(NSP/128, C/128, B), blk, 0, stream>>>(x, Wv_h, bv, v);
    gemm_qk_bf16<<<dim3(NSP/128, 1, B), blk, 0, stream>>>(x, Wqk_hi, Wqk_lo, bq, bk, qh, ql, kh, kl);

    energy_mfma<<<dim3(96, B), blk, 0, stream>>>(qh, ql, kh, kl, EW, 96, 1);
    energy_mfma<<<dim3(96, B), blk, 0, stream>>>(qh, ql, kh, kl, EH, 1, 96);

    maxsum<<<dim3(B*HW/4), blk, 0, stream>>>(EW, EH, gamma, ms);

    agg_mfma<<<dim3(96, 4, B), blk, 0, stream>>>(EW, ms, v, out, 0);
    transpose_inplace<<<dim3(B*C), blk, 0, stream>>>(v);
    agg_mfma<<<dim3(96, 4, B), blk, 0, stream>>>(EH, ms, v, v, 1);
    transpose_add<<<dim3(B*C), blk, 0, stream>>>(v, out);
}

// Round 7
// 420.528 us; speedup vs baseline: 4.7131x; 1.1583x over previous
//
#include <hip/hip_runtime.h>

#define B 8
#define C 512
#define H 96
#define W 96
#define HW (H*W)       // 9216
#define KD 512
#define NSP 9216

typedef __attribute__((ext_vector_type(8))) short bf16x8;
typedef __attribute__((ext_vector_type(4))) short short4v;
typedef __attribute__((ext_vector_type(4))) float f32x4;
typedef __attribute__((ext_vector_type(8))) _Float16 f16x8;
typedef __attribute__((ext_vector_type(4))) _Float16 f16x4v;

static __device__ __forceinline__ unsigned short f2bf(float f) {
    unsigned u = __float_as_uint(f);
    return (unsigned short)((u + 0x7FFFu + ((u >> 16) & 1u)) >> 16);
}
static __device__ __forceinline__ float bf2f(unsigned short h) {
    return __uint_as_float(((unsigned)h) << 16);
}
// swizzle for [rows][32-elem] tiles (64B rows, 4 granules of 8 elems)
static __device__ __forceinline__ int tidx(int row, int kgrp) {
    return row * 32 + ((kgrp ^ ((row >> 2) & 3)) << 3);
}
// swizzle for [rows][64-elem] tiles (128B rows, 8 granules) - energy kernel
static __device__ __forceinline__ int tidx64(int row, int gr) {
    return row * 64 + ((gr ^ (row & 7)) << 3);
}

// ---------------------------------------------------------------------------
// Split weights: Wv -> fp16 (single); Wqk = [Wq;Wk] -> bf16 hi/lo.
// ---------------------------------------------------------------------------
__global__ __launch_bounds__(256) void split_w(
    const float* __restrict__ Wv, const float* __restrict__ Wq, const float* __restrict__ Wk,
    _Float16* __restrict__ Wv_h,
    unsigned short* __restrict__ Wqk_hi, unsigned short* __restrict__ Wqk_lo)
{
    int i = blockIdx.x * 256 + threadIdx.x;
    if (i < C * C) {
        Wv_h[i] = (_Float16)Wv[i];
    }
    if (i < 128 * C) {
        int m = i / C, k = i % C;
        float f = (m < 64) ? Wq[m * C + k] : Wk[(m - 64) * C + k];
        unsigned short h = f2bf(f);
        Wqk_hi[i] = h;
        Wqk_lo[i] = f2bf(f - bf2f(h));
    }
}

// ---------------------------------------------------------------------------
// v projection: 2-pass split-fp16 MFMA GEMM (fp32 accum), fp16 OUTPUT.
// v16[b,m,n] = sum_k Wv[m,k] x[b,k,n] + bias[m]   -> (B,C,H,W) fp16
// ---------------------------------------------------------------------------
__global__ __launch_bounds__(256, 2) void gemm_v_f16(
    const float* __restrict__ x,
    const _Float16* __restrict__ Wh,
    const float* __restrict__ bias,
    _Float16* __restrict__ out16)
{
    __shared__ _Float16 smem[12288];                  // 24 KB
    const int X_HI = 0, X_LO = 4096, W_H = 8192;

    int tid = threadIdx.x;
    int n0 = blockIdx.x * 128;
    int m0 = blockIdx.y * 128;
    int b  = blockIdx.z;

    int lane = tid & 63, wave = tid >> 6;
    int wr = wave >> 1, wc = wave & 1;
    int l15 = lane & 15, l4 = lane >> 4;

    int tn = tid & 31, tk = tid >> 5;
    int nloc = tn * 4, kloc = tk * 4;
    const float* xp = x + ((size_t)b * KD + kloc) * NSP + n0 + nloc;
    int kg = tk >> 1, khalf = tk & 1;

    int wrow0 = tid >> 2, wkg0 = tid & 3;
    int wrow1 = (tid + 256) >> 2, wkg1 = (tid + 256) & 3;
    const _Float16* wp0 = Wh + (size_t)(m0 + wrow0) * KD + wkg0 * 8;
    const _Float16* wp1 = Wh + (size_t)(m0 + wrow1) * KD + wkg1 * 8;

    f32x4 acc[4][4];
    #pragma unroll
    for (int i = 0; i < 4; ++i)
        #pragma unroll
        for (int j = 0; j < 4; ++j)
            acc[i][j] = (f32x4){0.f, 0.f, 0.f, 0.f};

    float4 t4[4];
    f16x8 wv0, wv1;
    #pragma unroll
    for (int kk = 0; kk < 4; ++kk) t4[kk] = *(const float4*)(xp + (size_t)kk * NSP);
    wv0 = *(const f16x8*)wp0;
    wv1 = *(const f16x8*)wp1;

    for (int k0 = 0; k0 < KD; k0 += 32) {
        float4 t4n[4];
        f16x8 wv0n, wv1n;
        if (k0 + 32 < KD) {
            #pragma unroll
            for (int kk = 0; kk < 4; ++kk)
                t4n[kk] = *(const float4*)(xp + (size_t)(k0 + 32 + kk) * NSP);
            wv0n = *(const f16x8*)(wp0 + k0 + 32);
            wv1n = *(const f16x8*)(wp1 + k0 + 32);
        }
        #pragma unroll
        for (int nn = 0; nn < 4; ++nn) {
            int n = nloc + nn;
            f16x4v hi, lo;
            #pragma unroll
            for (int kk = 0; kk < 4; ++kk) {
                float f = ((const float*)&t4[kk])[nn];
                _Float16 hh = (_Float16)f;
                hi[kk] = hh;
                lo[kk] = (_Float16)(f - (float)hh);
            }
            int base = tidx(n, kg) + khalf * 4;
            *(f16x4v*)&smem[X_HI + base] = hi;
            *(f16x4v*)&smem[X_LO + base] = lo;
        }
        *(f16x8*)&smem[W_H + tidx(wrow0, wkg0)] = wv0;
        *(f16x8*)&smem[W_H + tidx(wrow1, wkg1)] = wv1;
        __syncthreads();

        f16x8 af[4], bh_[4], bl_[4];
        #pragma unroll
        for (int f = 0; f < 4; ++f) {
            int ra = wr * 64 + f * 16 + l15;
            int rb = wc * 64 + f * 16 + l15;
            af[f]  = *(const f16x8*)&smem[W_H  + tidx(ra, l4)];
            bh_[f] = *(const f16x8*)&smem[X_HI + tidx(rb, l4)];
        }
        #pragma unroll
        for (int i = 0; i < 4; ++i)
            #pragma unroll
            for (int j = 0; j < 4; ++j)
                acc[i][j] = __builtin_amdgcn_mfma_f32_16x16x32_f16(af[i], bh_[j], acc[i][j], 0, 0, 0);
        #pragma unroll
        for (int f = 0; f < 4; ++f) {
            int rb = wc * 64 + f * 16 + l15;
            bl_[f] = *(const f16x8*)&smem[X_LO + tidx(rb, l4)];
        }
        #pragma unroll
        for (int i = 0; i < 4; ++i)
            #pragma unroll
            for (int j = 0; j < 4; ++j)
                acc[i][j] = __builtin_amdgcn_mfma_f32_16x16x32_f16(af[i], bl_[j], acc[i][j], 0, 0, 0);
        __syncthreads();

        #pragma unroll
        for (int kk = 0; kk < 4; ++kk) t4[kk] = t4n[kk];
        wv0 = wv0n; wv1 = wv1n;
    }

    #pragma unroll
    for (int i = 0; i < 4; ++i) {
        #pragma unroll
        for (int r = 0; r < 4; ++r) {
            int row = m0 + wr * 64 + i * 16 + l4 * 4 + r;
            float bv = bias[row];
            #pragma unroll
            for (int j = 0; j < 4; ++j) {
                int col = n0 + wc * 64 + j * 16 + l15;
                out16[((size_t)b * C + row) * NSP + col] = (_Float16)(acc[i][j][r] + bv);
            }
        }
    }
}

// ---------------------------------------------------------------------------
// q/k projection: 3-pass split-bf16 MFMA GEMM (unchanged from R6).
// ---------------------------------------------------------------------------
__global__ __launch_bounds__(256, 2) void gemm_qk_bf16(
    const float* __restrict__ x,
    const unsigned short* __restrict__ Wh,
    const unsigned short* __restrict__ Wl,
    const float* __restrict__ bias0,
    const float* __restrict__ bias1,
    unsigned short* __restrict__ qh, unsigned short* __restrict__ ql,
    unsigned short* __restrict__ kh, unsigned short* __restrict__ kl)
{
    __shared__ short smem[16384];                     // 32 KB
    const int X_HI = 0, X_LO = 4096, W_HI = 8192, W_LO = 12288;

    int tid = threadIdx.x;
    int n0 = blockIdx.x * 128;
    int b  = blockIdx.z;

    int lane = tid & 63, wave = tid >> 6;
    int wr = wave >> 1, wc = wave & 1;
    int l15 = lane & 15, l4 = lane >> 4;

    int tn = tid & 31, tk = tid >> 5;
    int nloc = tn * 4, kloc = tk * 4;
    const float* xp = x + ((size_t)b * KD + kloc) * NSP + n0 + nloc;
    int kg = tk >> 1, khalf = tk & 1;

    int wrow[4], wkg[4];
    const unsigned short* wp[4];
    #pragma unroll
    for (int it = 0; it < 4; ++it) {
        int gi = tid + it * 256;
        int sel = gi >> 9;
        int t = gi & 511;
        wrow[it] = t >> 2; wkg[it] = t & 3;
        wp[it] = (sel ? Wl : Wh) + (size_t)wrow[it] * KD + wkg[it] * 8;
    }
    int wdst[4];
    #pragma unroll
    for (int it = 0; it < 4; ++it)
        wdst[it] = ((tid + it * 256) >> 9 ? W_LO : W_HI) + tidx(wrow[it], wkg[it]);

    f32x4 acc[4][4];
    #pragma unroll
    for (int i = 0; i < 4; ++i)
        #pragma unroll
        for (int j = 0; j < 4; ++j)
            acc[i][j] = (f32x4){0.f, 0.f, 0.f, 0.f};

    float4 t4[4];
    bf16x8 wv[4];
    #pragma unroll
    for (int kk = 0; kk < 4; ++kk) t4[kk] = *(const float4*)(xp + (size_t)kk * NSP);
    #pragma unroll
    for (int it = 0; it < 4; ++it) wv[it] = *(const bf16x8*)wp[it];

    for (int k0 = 0; k0 < KD; k0 += 32) {
        float4 t4n[4];
        bf16x8 wvn[4];
        if (k0 + 32 < KD) {
            #pragma unroll
            for (int kk = 0; kk < 4; ++kk)
                t4n[kk] = *(const float4*)(xp + (size_t)(k0 + 32 + kk) * NSP);
            #pragma unroll
            for (int it = 0; it < 4; ++it)
                wvn[it] = *(const bf16x8*)(wp[it] + k0 + 32);
        }
        #pragma unroll
        for (int nn = 0; nn < 4; ++nn) {
            int n = nloc + nn;
            short4v hi, lo;
            #pragma unroll
            for (int kk = 0; kk < 4; ++kk) {
                float f = ((const float*)&t4[kk])[nn];
                unsigned short h = f2bf(f);
                hi[kk] = (short)h;
                lo[kk] = (short)f2bf(f - bf2f(h));
            }
            int base = tidx(n, kg) + khalf * 4;
            *(short4v*)&smem[X_HI + base] = hi;
            *(short4v*)&smem[X_LO + base] = lo;
        }
        #pragma unroll
        for (int it = 0; it < 4; ++it)
            *(bf16x8*)&smem[wdst[it]] = wv[it];
        __syncthreads();

        bf16x8 af[4], bf_[4], bl_[4];
        #pragma unroll
        for (int f = 0; f < 4; ++f) {
            int ra = wr * 64 + f * 16 + l15;
            int rb = wc * 64 + f * 16 + l15;
            af[f]  = *(const bf16x8*)&smem[X_HI + tidx(ra, l4)];
            bf_[f] = *(const bf16x8*)&smem[W_HI + tidx(rb, l4)];
        }
        #pragma unroll
        for (int i = 0; i < 4; ++i)
            #pragma unroll
            for (int j = 0; j < 4; ++j)
                acc[i][j] = __builtin_amdgcn_mfma_f32_16x16x32_bf16(af[i], bf_[j], acc[i][j], 0, 0, 0);
        #pragma unroll
        for (int f = 0; f < 4; ++f) {
            int rb = wc * 64 + f * 16 + l15;
            bl_[f] = *(const bf16x8*)&smem[W_LO + tidx(rb, l4)];
        }
        #pragma unroll
        for (int i = 0; i < 4; ++i)
            #pragma unroll
            for (int j = 0; j < 4; ++j)
                acc[i][j] = __builtin_amdgcn_mfma_f32_16x16x32_bf16(af[i], bl_[j], acc[i][j], 0, 0, 0);
        #pragma unroll
        for (int f = 0; f < 4; ++f) {
            int ra = wr * 64 + f * 16 + l15;
            af[f] = *(const bf16x8*)&smem[X_LO + tidx(ra, l4)];
        }
        #pragma unroll
        for (int i = 0; i < 4; ++i)
            #pragma unroll
            for (int j = 0; j < 4; ++j)
                acc[i][j] = __builtin_amdgcn_mfma_f32_16x16x32_bf16(af[i], bf_[j], acc[i][j], 0, 0, 0);
        __syncthreads();

        #pragma unroll
        for (int kk = 0; kk < 4; ++kk) t4[kk] = t4n[kk];
        #pragma unroll
        for (int it = 0; it < 4; ++it) wv[it] = wvn[it];
    }

    #pragma unroll
    for (int i = 0; i < 4; ++i) {
        #pragma unroll
        for (int r = 0; r < 4; ++r) {
            int sp = n0 + wr * 64 + i * 16 + l4 * 4 + r;
            #pragma unroll
            for (int j = 0; j < 4; ++j) {
                int wcol = wc * 64 + j * 16 + l15;
                float val = acc[i][j][r] + (wcol < 64 ? bias0[wcol] : bias1[wcol - 64]);
                unsigned short hi = f2bf(val);
                unsigned short lo = f2bf(val - bf2f(hi));
                size_t off = ((size_t)b * NSP + sp) * 64 + (wcol & 63);
                if (wcol < 64) { qh[off] = hi; ql[off] = lo; }
                else           { kh[off] = hi; kl[off] = lo; }
            }
        }
    }
}

// ---------------------------------------------------------------------------
// Energy MFMA (3-pass bf16, unchanged)
// ---------------------------------------------------------------------------
__global__ __launch_bounds__(256, 2) void energy_mfma(
    const unsigned short* __restrict__ qh, const unsigned short* __restrict__ ql,
    const unsigned short* __restrict__ kh, const unsigned short* __restrict__ kl,
    float* __restrict__ out, int pMul, int rMul)
{
    __shared__ short sm[4 * 96 * 64];   // 48 KB
    const int T_QH = 0, T_QL = 6144, T_KH = 12288, T_KL = 18432;
    int p = blockIdx.x, b = blockIdx.y;
    int tid = threadIdx.x;
    size_t base = ((size_t)b * HW + (size_t)p * pMul) * 64;
    size_t rstride = (size_t)rMul * 64;

    #pragma unroll
    for (int tile = 0; tile < 4; ++tile) {
        const unsigned short* src = (tile == 0) ? qh : (tile == 1) ? ql : (tile == 2) ? kh : kl;
        int tb = tile * 6144;
        #pragma unroll
        for (int sub = 0; sub < 3; ++sub) {
            int s = sub * 256 + tid;
            int row = s >> 3, g = s & 7;
            bf16x8 d = *(const bf16x8*)&src[base + row * rstride + g * 8];
            *(bf16x8*)&sm[tb + tidx64(row, g)] = d;
        }
    }
    __syncthreads();

    int lane = tid & 63, wave = tid >> 6;
    int wr = wave >> 1, wc = wave & 1;
    int l15 = lane & 15, l4 = lane >> 4;

    f32x4 acc[3][3];
    #pragma unroll
    for (int i = 0; i < 3; ++i)
        #pragma unroll
        for (int j = 0; j < 3; ++j)
            acc[i][j] = (f32x4){0.f, 0.f, 0.f, 0.f};

    #pragma unroll
    for (int ks = 0; ks < 2; ++ks) {
        bf16x8 Ah[3], Al[3], Bh[3], Bl[3];
        int gr = ks * 4 + l4;
        #pragma unroll
        for (int i = 0; i < 3; ++i) {
            int ra = wr * 48 + i * 16 + l15;
            int sa = tidx64(ra, gr);
            Ah[i] = *(const bf16x8*)&sm[T_QH + sa];
            Al[i] = *(const bf16x8*)&sm[T_QL + sa];
            int rb = wc * 48 + i * 16 + l15;
            int sb = tidx64(rb, gr);
            Bh[i] = *(const bf16x8*)&sm[T_KH + sb];
            Bl[i] = *(const bf16x8*)&sm[T_KL + sb];
        }
        #pragma unroll
        for (int i = 0; i < 3; ++i)
            #pragma unroll
            for (int j = 0; j < 3; ++j) {
                acc[i][j] = __builtin_amdgcn_mfma_f32_16x16x32_bf16(Ah[i], Bh[j], acc[i][j], 0, 0, 0);
                acc[i][j] = __builtin_amdgcn_mfma_f32_16x16x32_bf16(Ah[i], Bl[j], acc[i][j], 0, 0, 0);
                acc[i][j] = __builtin_amdgcn_mfma_f32_16x16x32_bf16(Al[i], Bh[j], acc[i][j], 0, 0, 0);
            }
    }

    size_t ob = (size_t)(b * 96 + p) * 9216;
    #pragma unroll
    for (int i = 0; i < 3; ++i)
        #pragma unroll
        for (int r = 0; r < 4; ++r) {
            int row = wr * 48 + i * 16 + l4 * 4 + r;
            #pragma unroll
            for (int j = 0; j < 3; ++j) {
                int col = wc * 48 + j * 16 + l15;
                out[ob + (size_t)row * 96 + col] = acc[i][j][r];
            }
        }
}

// ---------------------------------------------------------------------------
// Joint softmax max/sum (unchanged)
// ---------------------------------------------------------------------------
__global__ __launch_bounds__(256) void maxsum(
    const float* __restrict__ EW, const float* __restrict__ EH,
    const float* __restrict__ gamma, float* __restrict__ ms)
{
    int gw = (blockIdx.x * 256 + threadIdx.x) >> 6;
    int lane = threadIdx.x & 63;
    int b = gw / HW, hw = gw % HW;
    int h = hw / 96, w = hw % 96;
    const float* ew = &EW[((size_t)(b * 96 + h) * 96 + w) * 96];
    const float* eh = &EH[((size_t)(b * 96 + w) * 96 + h) * 96];
    float v0 = ew[lane];
    float v1 = (lane < 32) ? ew[64 + lane] : eh[lane - 32];
    float v2 = eh[32 + lane];
    float m = fmaxf(fmaxf(v0, v1), v2);
    #pragma unroll
    for (int s = 32; s; s >>= 1) m = fmaxf(m, __shfl_xor(m, s));
    float pp = __expf(v0 - m) + __expf(v1 - m) + __expf(v2 - m);
    #pragma unroll
    for (int s = 32; s; s >>= 1) pp += __shfl_xor(pp, s);
    if (lane == 0) {
        ms[(size_t)gw * 2]     = m;
        ms[(size_t)gw * 2 + 1] = gamma[0] / pp;
    }
}

// ---------------------------------------------------------------------------
// MFMA aggregation v2: P staged ONCE in LDS (fp16, exp-normalized);
// v fp16 A-fragments loaded DIRECT from global (no LDS, no inner barriers);
// c-loop over 4 chunks of 128 inside the block (E fetched once, not 4x).
// OUT16=0: dst fp32 (out);  OUT16=1: dst fp16 (outHT).
// ---------------------------------------------------------------------------
template<int OUT16>
__global__ __launch_bounds__(256) void agg_mfma(
    const float* __restrict__ E, const float* __restrict__ ms,
    const _Float16* __restrict__ v16,
    float* __restrict__ dstF, _Float16* __restrict__ dstH, int msMode)
{
    __shared__ _Float16 satt[3][96 * 32];   // 18 KB [kchunk][tidx(s,g)]

    int r  = blockIdx.x;
    int b  = blockIdx.y;
    int tid = threadIdx.x;
    int lane = tid & 63, wave = tid >> 6;
    int l15 = lane & 15, l4 = lane >> 4;

    // ---- stage P: exp-normalize to fp16, once per block ----
    const float* Eb = &E[(size_t)(b * 96 + r) * 9216];
    int msBase = b * HW;
    #pragma unroll
    for (int it = 0; it < 5; ++it) {
        int g_id = tid + it * 256;
        if (g_id < 1152) {
            int s = g_id / 12, gj = g_id % 12;
            int mi = msMode ? (msBase + s * 96 + r) : (msBase + r * 96 + s);
            float m  = ms[(size_t)mi * 2];
            float sc = ms[(size_t)mi * 2 + 1];
            float4 e0 = *(const float4*)&Eb[s * 96 + gj * 8];
            float4 e1 = *(const float4*)&Eb[s * 96 + gj * 8 + 4];
            float pv[8] = {e0.x, e0.y, e0.z, e0.w, e1.x, e1.y, e1.z, e1.w};
            f16x8 ph;
            #pragma unroll
            for (int u = 0; u < 8; ++u)
                ph[u] = (_Float16)(__expf(pv[u] - m) * sc);
            *(f16x8*)&satt[gj >> 2][tidx(s, gj & 3)] = ph;
        }
    }
    __syncthreads();

    // v16[b, c, r, j] at (b*C + c)*9216 + r*96 + j
    const _Float16* vb = v16 + (size_t)b * C * 9216 + r * 96;

    for (int cc = 0; cc < 4; ++cc) {
        int cbase = cc * 128 + wave * 32;

        f32x4 acc[2][6];
        #pragma unroll
        for (int i = 0; i < 2; ++i)
            #pragma unroll
            for (int n = 0; n < 6; ++n)
                acc[i][n] = (f32x4){0.f, 0.f, 0.f, 0.f};

        #pragma unroll
        for (int kc = 0; kc < 3; ++kc) {
            f16x8 af[2];
            #pragma unroll
            for (int i = 0; i < 2; ++i)
                af[i] = *(const f16x8*)&vb[(size_t)(cbase + i * 16 + l15) * 9216 + kc * 32 + l4 * 8];
            f16x8 Bp[6];
            #pragma unroll
            for (int n = 0; n < 6; ++n)
                Bp[n] = *(const f16x8*)&satt[kc][tidx(n * 16 + l15, l4)];
            #pragma unroll
            for (int i = 0; i < 2; ++i)
                #pragma unroll
                for (int n = 0; n < 6; ++n)
                    acc[i][n] = __builtin_amdgcn_mfma_f32_16x16x32_f16(af[i], Bp[n], acc[i][n], 0, 0, 0);
        }

        // ---- epilogue: dst[b, c, r, s] ----
        #pragma unroll
        for (int i = 0; i < 2; ++i)
            #pragma unroll
            for (int r4 = 0; r4 < 4; ++r4) {
                int cl = cbase + i * 16 + l4 * 4 + r4;
                size_t rowb = ((size_t)b * C + cl) * 9216 + r * 96;
                #pragma unroll
                for (int n = 0; n < 6; ++n) {
                    int s = n * 16 + l15;
                    if (OUT16) dstH[rowb + s] = (_Float16)acc[i][n][r4];
                    else       dstF[rowb + s] = acc[i][n][r4];
                }
            }
    }
}

// ---------------------------------------------------------------------------
// Out-of-place fp16 transpose: dst[b,c,w,h] = src[b,c,h,w], per-(b,c) plane.
// ---------------------------------------------------------------------------
__global__ __launch_bounds__(256) void transpose_f16(
    const _Float16* __restrict__ src, _Float16* __restrict__ dst)
{
    size_t base = (size_t)blockIdx.x * (96 * 96);
    __shared__ _Float16 t[96][97];
    int tid = threadIdx.x;
    for (int i = tid; i < 96 * 96; i += 256) t[i / 96][i % 96] = src[base + i];
    __syncthreads();
    for (int i = tid; i < 96 * 96; i += 256) dst[base + i] = t[i % 96][i / 96];
}

// ---------------------------------------------------------------------------
// out[b,c,h,w] += (float) srcT[b,c,w,h]   (srcT fp16)
// ---------------------------------------------------------------------------
__global__ __launch_bounds__(256) void transpose_add(
    const _Float16* __restrict__ srcT, float* __restrict__ out)
{
    size_t base = (size_t)blockIdx.x * (96 * 96);
    __shared__ _Float16 t[96][97];
    int tid = threadIdx.x;
    for (int i = tid; i < 96 * 96; i += 256) t[i / 96][i % 96] = srcT[base + i];
    __syncthreads();
    for (int i = tid; i < 96 * 96; i += 256) out[base + i] += (float)t[i % 96][i / 96];
}

// ---------------------------------------------------------------------------
extern "C" void kernel_launch(void* const* d_in, const int* in_sizes, int n_in,
                              void* d_out, int out_size, void* d_ws, size_t ws_size,
                              hipStream_t stream)
{
    const float* x     = (const float*)d_in[0];
    const float* Wq    = (const float*)d_in[1];
    const float* bq    = (const float*)d_in[2];
    const float* Wk    = (const float*)d_in[3];
    const float* bk    = (const float*)d_in[4];
    const float* Wv    = (const float*)d_in[5];
    const float* bv    = (const float*)d_in[6];
    const float* gamma = (const float*)d_in[7];
    float* out = (float*)d_out;

    // workspace (245.3 MB, same footprint as R6)
    unsigned short* qh = (unsigned short*)d_ws;          // B*HW*64 bf16 x4 = 37.7MB
    unsigned short* ql = qh + (size_t)B*HW*64;
    unsigned short* kh = ql + (size_t)B*HW*64;
    unsigned short* kl = kh + (size_t)B*HW*64;
    _Float16* vA = (_Float16*)(kl + (size_t)B*HW*64);    // (B,C,H,W) fp16  75.5MB
    _Float16* vB = vA + (size_t)B*C*HW;                  // (B,C,W,H) fp16  75.5MB
    float* EH   = (float*)(vB + (size_t)B*C*HW);         // (B,W,H,96) fp32 28.3MB
    float* EW   = EH + (size_t)B*HW*96;                  // (B,H,W,96) fp32 28.3MB
    float* ms   = (float*)d_ws;                          // aliases qh (dead after energies)
    _Float16* outHT = vA;                                // vA dead after agg_W -> reuse for fp16 out_H^T

    _Float16* Wv_h = (_Float16*)EW;                      // W splits alias EW (dead until energy W-mode)
    unsigned short* Wqk_hi = (unsigned short*)(Wv_h + (size_t)C*C);
    unsigned short* Wqk_lo = Wqk_hi + (size_t)128*C;

    dim3 blk(256);

    split_w<<<dim3((C*C + 255)/256), blk, 0, stream>>>(Wv, Wq, Wk, Wv_h, Wqk_hi, Wqk_lo);

    gemm_v_f16<<<dim3(NSP/128, C/128, B), blk, 0, stream>>>(x, Wv_h, bv, vA);
    gemm_qk_bf16<<<dim3(NSP/128, 1, B), blk, 0, stream>>>(x, Wqk_hi, Wqk_lo, bq, bk, qh, ql, kh, kl);

    energy_mfma<<<dim3(96, B), blk, 0, stream>>>(qh, ql, kh, kl, EW, 96, 1);
    energy_mfma<<<dim3(96, B), blk, 0, stream>>>(qh, ql, kh, kl, EH, 1, 96);

    maxsum<<<dim3(B*HW/4), blk, 0, stream>>>(EW, EH, gamma, ms);

    // vT = transpose(v) while v is still live
    transpose_f16<<<dim3(B*C), blk, 0, stream>>>(vA, vB);

    // out_W -> out (fp32)
    agg_mfma<0><<<dim3(96, B), blk, 0, stream>>>(EW, ms, vA, out, nullptr, 0);
    // out_H^T -> outHT (fp16, reuses vA region; vA dead now)
    agg_mfma<1><<<dim3(96, B), blk, 0, stream>>>(EH, ms, vB, nullptr, outHT, 1);
    // out += transpose(outHT)
    transpose_add<<<dim3(B*C), blk, 0, stream>>>(outHT, out);
}

// Round 8
// 382.111 us; speedup vs baseline: 5.1869x; 1.1005x over previous
//
#include <hip/hip_runtime.h>

#define B 8
#define C 512
#define H 96
#define W 96
#define HW (H*W)       // 9216
#define KD 512
#define NSP 9216

typedef __attribute__((ext_vector_type(4))) float f32x4;
typedef __attribute__((ext_vector_type(8))) _Float16 f16x8;

// global -> LDS async copy, 16B per lane. LDS dest must be wave-uniform base
// (HW adds lane*16); global src is per-lane.
typedef __attribute__((address_space(3))) unsigned int lds_u32;
typedef const __attribute__((address_space(1))) unsigned int glb_u32;
static __device__ __forceinline__ void gload16(const void* gsrc, void* ldst) {
    __builtin_amdgcn_global_load_lds((glb_u32*)gsrc, (lds_u32*)ldst, 16, 0, 0);
}

// swizzle for [rows][32-elem] tiles (64B rows, 4 granules of 8) — agg satt only
static __device__ __forceinline__ int tidx(int row, int kgrp) {
    return row * 32 + ((kgrp ^ ((row >> 2) & 3)) << 3);
}
// swizzle for [rows][64-elem] tiles (128B rows, 8 granules) — energy kernel
static __device__ __forceinline__ int tidx64(int row, int gr) {
    return row * 64 + ((gr ^ (row & 7)) << 3);
}

// ---------------------------------------------------------------------------
// Split weights to fp16: Wv single; Wqk = [Wq;Wk] hi/lo pairs.
// ---------------------------------------------------------------------------
__global__ __launch_bounds__(256) void split_w(
    const float* __restrict__ Wv, const float* __restrict__ Wq, const float* __restrict__ Wk,
    _Float16* __restrict__ Wv_h,
    _Float16* __restrict__ Wqk_h, _Float16* __restrict__ Wqk_l)
{
    int i = blockIdx.x * 256 + threadIdx.x;
    if (i < C * C) Wv_h[i] = (_Float16)Wv[i];
    if (i < 128 * C) {
        int m = i / C, k = i % C;
        float f = (m < 64) ? Wq[m * C + k] : Wk[(m - 64) * C + k];
        _Float16 h = (_Float16)f;
        Wqk_h[i] = h;
        Wqk_l[i] = (_Float16)(f - (float)h);
    }
}

// ---------------------------------------------------------------------------
// Global transpose+split of x: (B,K,N) fp32 -> xhT/xlT (B,N,K) fp16.
// 64x64 tiles via padded LDS; fully coalesced both sides.
// ---------------------------------------------------------------------------
__global__ __launch_bounds__(256) void split_x(
    const float* __restrict__ x,
    _Float16* __restrict__ xhT, _Float16* __restrict__ xlT)
{
    __shared__ float t[64][65];
    int n0 = blockIdx.x * 64, k0 = blockIdx.y * 64, b = blockIdx.z;
    int tid = threadIdx.x;
    const float* xb = x + ((size_t)b * KD + k0) * NSP + n0;
    #pragma unroll
    for (int it = 0; it < 16; ++it) {
        int idx = tid + it * 256;
        t[idx >> 6][idx & 63] = xb[(size_t)(idx >> 6) * NSP + (idx & 63)];
    }
    __syncthreads();
    #pragma unroll
    for (int it = 0; it < 2; ++it) {
        int gid = tid + it * 256;          // 512 granules: n row, k-granule
        int n = gid >> 3, g = gid & 7;
        f16x8 hi, lo;
        #pragma unroll
        for (int u = 0; u < 8; ++u) {
            float f = t[g * 8 + u][n];
            _Float16 hh = (_Float16)f;
            hi[u] = hh;
            lo[u] = (_Float16)(f - (float)hh);
        }
        size_t off = ((size_t)b * NSP + n0 + n) * KD + k0 + g * 8;
        *(f16x8*)&xhT[off] = hi;
        *(f16x8*)&xlT[off] = lo;
    }
}

// ---------------------------------------------------------------------------
// v projection: single-pass fp16 MFMA GEMM (fp32 accum), gload_lds staging.
// v16[b,m,n] = sum_k Wv[m,k] xhT[n,k] + bias[m]  -> (B,C,HW) fp16
// ---------------------------------------------------------------------------
__global__ __launch_bounds__(256, 2) void gemm_v(
    const _Float16* __restrict__ xhT,
    const _Float16* __restrict__ Wh,
    const float* __restrict__ bias,
    _Float16* __restrict__ out16)
{
    __shared__ _Float16 smem[8192];     // [W 128x32 | X 128x32] = 16 KB, linear
    const int W_OFF = 0, X_OFF = 4096;

    int tid = threadIdx.x;
    int n0 = blockIdx.x * 128, m0 = blockIdx.y * 128, b = blockIdx.z;
    int lane = tid & 63, wave = tid >> 6;
    int wr = wave >> 1, wc = wave & 1;
    int l15 = lane & 15, l4 = lane >> 4;

    // granule (row = tid>>2, kcol = (tid&3)*8); +64 rows for round 2
    int grow = tid >> 2, gcol = (tid & 3) * 8;
    const _Float16* pW = Wh + (size_t)(m0 + grow) * KD + gcol;
    const _Float16* pX = xhT + ((size_t)b * NSP + n0 + grow) * KD + gcol;
    const size_t half = (size_t)64 * KD;
    int ldsW0 = W_OFF + wave * 512;          // halves: (wave*64 granules)*8
    int ldsW1 = W_OFF + 2048 + wave * 512;
    int ldsX0 = X_OFF + wave * 512;
    int ldsX1 = X_OFF + 2048 + wave * 512;

    f32x4 acc[4][4];
    #pragma unroll
    for (int i = 0; i < 4; ++i)
        #pragma unroll
        for (int j = 0; j < 4; ++j)
            acc[i][j] = (f32x4){0.f, 0.f, 0.f, 0.f};

    for (int k0 = 0; k0 < KD; k0 += 32) {
        gload16(pW + k0,        &smem[ldsW0]);
        gload16(pW + half + k0, &smem[ldsW1]);
        gload16(pX + k0,        &smem[ldsX0]);
        gload16(pX + half + k0, &smem[ldsX1]);
        __syncthreads();

        f16x8 af[4], bf[4];
        #pragma unroll
        for (int f = 0; f < 4; ++f) {
            af[f] = *(const f16x8*)&smem[W_OFF + (wr * 64 + f * 16 + l15) * 32 + l4 * 8];
            bf[f] = *(const f16x8*)&smem[X_OFF + (wc * 64 + f * 16 + l15) * 32 + l4 * 8];
        }
        #pragma unroll
        for (int i = 0; i < 4; ++i)
            #pragma unroll
            for (int j = 0; j < 4; ++j)
                acc[i][j] = __builtin_amdgcn_mfma_f32_16x16x32_f16(af[i], bf[j], acc[i][j], 0, 0, 0);
        __syncthreads();
    }

    #pragma unroll
    for (int i = 0; i < 4; ++i)
        #pragma unroll
        for (int r = 0; r < 4; ++r) {
            int row = m0 + wr * 64 + i * 16 + l4 * 4 + r;
            float bv = bias[row];
            #pragma unroll
            for (int j = 0; j < 4; ++j) {
                int col = n0 + wc * 64 + j * 16 + l15;
                out16[((size_t)b * C + row) * NSP + col] = (_Float16)(acc[i][j][r] + bv);
            }
        }
}

// ---------------------------------------------------------------------------
// q/k projection: 3-pass fp16 (Ah*Bh + Ah*Bl + Al*Bh; dropped Al*Bl ~2^-24).
// q/k[b,n,m] = sum_k x[k,n] Wqk[m,k] + bias  -> fp16 hi/lo pairs (B,HW,64)
// ---------------------------------------------------------------------------
__global__ __launch_bounds__(256, 2) void gemm_qk(
    const _Float16* __restrict__ xhT, const _Float16* __restrict__ xlT,
    const _Float16* __restrict__ Wqh, const _Float16* __restrict__ Wql,
    const float* __restrict__ bias0, const float* __restrict__ bias1,
    _Float16* __restrict__ qh, _Float16* __restrict__ ql,
    _Float16* __restrict__ kh, _Float16* __restrict__ kl)
{
    __shared__ _Float16 smem[16384];    // [XH|XL|WH|WL] each 128x32 = 32 KB
    const int XH = 0, XL = 4096, WHo = 8192, WLo = 12288;

    int tid = threadIdx.x;
    int n0 = blockIdx.x * 128, b = blockIdx.z;
    int lane = tid & 63, wave = tid >> 6;
    int wr = wave >> 1, wc = wave & 1;
    int l15 = lane & 15, l4 = lane >> 4;

    int grow = tid >> 2, gcol = (tid & 3) * 8;
    const _Float16* pXh = xhT + ((size_t)b * NSP + n0 + grow) * KD + gcol;
    const _Float16* pXl = xlT + ((size_t)b * NSP + n0 + grow) * KD + gcol;
    const _Float16* pWh = Wqh + (size_t)grow * KD + gcol;
    const _Float16* pWl = Wql + (size_t)grow * KD + gcol;
    const size_t half = (size_t)64 * KD;
    int base0 = wave * 512, base1 = 2048 + wave * 512;

    f32x4 acc[4][4];
    #pragma unroll
    for (int i = 0; i < 4; ++i)
        #pragma unroll
        for (int j = 0; j < 4; ++j)
            acc[i][j] = (f32x4){0.f, 0.f, 0.f, 0.f};

    for (int k0 = 0; k0 < KD; k0 += 32) {
        gload16(pXh + k0,        &smem[XH + base0]);
        gload16(pXh + half + k0, &smem[XH + base1]);
        gload16(pXl + k0,        &smem[XL + base0]);
        gload16(pXl + half + k0, &smem[XL + base1]);
        gload16(pWh + k0,        &smem[WHo + base0]);
        gload16(pWh + half + k0, &smem[WHo + base1]);
        gload16(pWl + k0,        &smem[WLo + base0]);
        gload16(pWl + half + k0, &smem[WLo + base1]);
        __syncthreads();

        f16x8 axh[4], axl[4], bwh[4], bwl[4];
        #pragma unroll
        for (int f = 0; f < 4; ++f) {
            int ra = (wr * 64 + f * 16 + l15) * 32 + l4 * 8;   // X rows (n)
            int rb = (wc * 64 + f * 16 + l15) * 32 + l4 * 8;   // W rows (m)
            axh[f] = *(const f16x8*)&smem[XH + ra];
            axl[f] = *(const f16x8*)&smem[XL + ra];
            bwh[f] = *(const f16x8*)&smem[WHo + rb];
            bwl[f] = *(const f16x8*)&smem[WLo + rb];
        }
        #pragma unroll
        for (int i = 0; i < 4; ++i)
            #pragma unroll
            for (int j = 0; j < 4; ++j)
                acc[i][j] = __builtin_amdgcn_mfma_f32_16x16x32_f16(axh[i], bwh[j], acc[i][j], 0, 0, 0);
        #pragma unroll
        for (int i = 0; i < 4; ++i)
            #pragma unroll
            for (int j = 0; j < 4; ++j)
                acc[i][j] = __builtin_amdgcn_mfma_f32_16x16x32_f16(axh[i], bwl[j], acc[i][j], 0, 0, 0);
        #pragma unroll
        for (int i = 0; i < 4; ++i)
            #pragma unroll
            for (int j = 0; j < 4; ++j)
                acc[i][j] = __builtin_amdgcn_mfma_f32_16x16x32_f16(axl[i], bwh[j], acc[i][j], 0, 0, 0);
        __syncthreads();
    }

    #pragma unroll
    for (int i = 0; i < 4; ++i)
        #pragma unroll
        for (int r = 0; r < 4; ++r) {
            int sp = n0 + wr * 64 + i * 16 + l4 * 4 + r;
            #pragma unroll
            for (int j = 0; j < 4; ++j) {
                int wcol = wc * 64 + j * 16 + l15;
                float val = acc[i][j][r] + (wcol < 64 ? bias0[wcol] : bias1[wcol - 64]);
                _Float16 hi = (_Float16)val;
                _Float16 lo = (_Float16)(val - (float)hi);
                size_t off = ((size_t)b * NSP + sp) * 64 + (wcol & 63);
                if (wcol < 64) { qh[off] = hi; ql[off] = lo; }
                else           { kh[off] = hi; kl[off] = lo; }
            }
        }
}

// ---------------------------------------------------------------------------
// Energy MFMA: 3-pass fp16. E[row,col] = q_panel[row,:] . k_panel[col,:]
// ---------------------------------------------------------------------------
__global__ __launch_bounds__(256, 2) void energy_mfma(
    const _Float16* __restrict__ qh, const _Float16* __restrict__ ql,
    const _Float16* __restrict__ kh, const _Float16* __restrict__ kl,
    float* __restrict__ out, int pMul, int rMul)
{
    __shared__ _Float16 sm[4 * 96 * 64];   // 48 KB
    const int T_QH = 0, T_QL = 6144, T_KH = 12288, T_KL = 18432;
    int p = blockIdx.x, b = blockIdx.y;
    int tid = threadIdx.x;
    size_t base = ((size_t)b * HW + (size_t)p * pMul) * 64;
    size_t rstride = (size_t)rMul * 64;

    #pragma unroll
    for (int tile = 0; tile < 4; ++tile) {
        const _Float16* src = (tile == 0) ? qh : (tile == 1) ? ql : (tile == 2) ? kh : kl;
        int tb = tile * 6144;
        #pragma unroll
        for (int sub = 0; sub < 3; ++sub) {
            int s = sub * 256 + tid;
            int row = s >> 3, g = s & 7;
            f16x8 d = *(const f16x8*)&src[base + row * rstride + g * 8];
            *(f16x8*)&sm[tb + tidx64(row, g)] = d;
        }
    }
    __syncthreads();

    int lane = tid & 63, wave = tid >> 6;
    int wr = wave >> 1, wc = wave & 1;
    int l15 = lane & 15, l4 = lane >> 4;

    f32x4 acc[3][3];
    #pragma unroll
    for (int i = 0; i < 3; ++i)
        #pragma unroll
        for (int j = 0; j < 3; ++j)
            acc[i][j] = (f32x4){0.f, 0.f, 0.f, 0.f};

    #pragma unroll
    for (int ks = 0; ks < 2; ++ks) {
        f16x8 Ah[3], Al[3], Bh[3], Bl[3];
        int gr = ks * 4 + l4;
        #pragma unroll
        for (int i = 0; i < 3; ++i) {
            int sa = tidx64(wr * 48 + i * 16 + l15, gr);
            Ah[i] = *(const f16x8*)&sm[T_QH + sa];
            Al[i] = *(const f16x8*)&sm[T_QL + sa];
            int sb = tidx64(wc * 48 + i * 16 + l15, gr);
            Bh[i] = *(const f16x8*)&sm[T_KH + sb];
            Bl[i] = *(const f16x8*)&sm[T_KL + sb];
        }
        #pragma unroll
        for (int i = 0; i < 3; ++i)
            #pragma unroll
            for (int j = 0; j < 3; ++j) {
                acc[i][j] = __builtin_amdgcn_mfma_f32_16x16x32_f16(Ah[i], Bh[j], acc[i][j], 0, 0, 0);
                acc[i][j] = __builtin_amdgcn_mfma_f32_16x16x32_f16(Ah[i], Bl[j], acc[i][j], 0, 0, 0);
                acc[i][j] = __builtin_amdgcn_mfma_f32_16x16x32_f16(Al[i], Bh[j], acc[i][j], 0, 0, 0);
            }
    }

    size_t ob = (size_t)(b * 96 + p) * 9216;
    #pragma unroll
    for (int i = 0; i < 3; ++i)
        #pragma unroll
        for (int r = 0; r < 4; ++r) {
            int row = wr * 48 + i * 16 + l4 * 4 + r;
            #pragma unroll
            for (int j = 0; j < 3; ++j)
                out[ob + (size_t)row * 96 + wc * 48 + j * 16 + l15] = acc[i][j][r];
        }
}

// ---------------------------------------------------------------------------
// Joint softmax max/sum (unchanged)
// ---------------------------------------------------------------------------
__global__ __launch_bounds__(256) void maxsum(
    const float* __restrict__ EW, const float* __restrict__ EH,
    const float* __restrict__ gamma, float* __restrict__ ms)
{
    int gw = (blockIdx.x * 256 + threadIdx.x) >> 6;
    int lane = threadIdx.x & 63;
    int b = gw / HW, hw = gw % HW;
    int h = hw / 96, w = hw % 96;
    const float* ew = &EW[((size_t)(b * 96 + h) * 96 + w) * 96];
    const float* eh = &EH[((size_t)(b * 96 + w) * 96 + h) * 96];
    float v0 = ew[lane];
    float v1 = (lane < 32) ? ew[64 + lane] : eh[lane - 32];
    float v2 = eh[32 + lane];
    float m = fmaxf(fmaxf(v0, v1), v2);
    #pragma unroll
    for (int s = 32; s; s >>= 1) m = fmaxf(m, __shfl_xor(m, s));
    float pp = __expf(v0 - m) + __expf(v1 - m) + __expf(v2 - m);
    #pragma unroll
    for (int s = 32; s; s >>= 1) pp += __shfl_xor(pp, s);
    if (lane == 0) {
        ms[(size_t)gw * 2]     = m;
        ms[(size_t)gw * 2 + 1] = gamma[0] / pp;
    }
}

// ---------------------------------------------------------------------------
// MFMA aggregation (unchanged from R7): P staged once, v direct-from-global.
// ---------------------------------------------------------------------------
template<int OUT16>
__global__ __launch_bounds__(256) void agg_mfma(
    const float* __restrict__ E, const float* __restrict__ ms,
    const _Float16* __restrict__ v16,
    float* __restrict__ dstF, _Float16* __restrict__ dstH, int msMode)
{
    __shared__ _Float16 satt[3][96 * 32];   // 18 KB

    int r = blockIdx.x, b = blockIdx.y;
    int tid = threadIdx.x;
    int lane = tid & 63, wave = tid >> 6;
    int l15 = lane & 15, l4 = lane >> 4;

    const float* Eb = &E[(size_t)(b * 96 + r) * 9216];
    int msBase = b * HW;
    #pragma unroll
    for (int it = 0; it < 5; ++it) {
        int g_id = tid + it * 256;
        if (g_id < 1152) {
            int s = g_id / 12, gj = g_id % 12;
            int mi = msMode ? (msBase + s * 96 + r) : (msBase + r * 96 + s);
            float m  = ms[(size_t)mi * 2];
            float sc = ms[(size_t)mi * 2 + 1];
            float4 e0 = *(const float4*)&Eb[s * 96 + gj * 8];
            float4 e1 = *(const float4*)&Eb[s * 96 + gj * 8 + 4];
            float pv[8] = {e0.x, e0.y, e0.z, e0.w, e1.x, e1.y, e1.z, e1.w};
            f16x8 ph;
            #pragma unroll
            for (int u = 0; u < 8; ++u)
                ph[u] = (_Float16)(__expf(pv[u] - m) * sc);
            *(f16x8*)&satt[gj >> 2][tidx(s, gj & 3)] = ph;
        }
    }
    __syncthreads();

    const _Float16* vb = v16 + (size_t)b * C * 9216 + r * 96;

    for (int cc = 0; cc < 4; ++cc) {
        int cbase = cc * 128 + wave * 32;
        f32x4 acc[2][6];
        #pragma unroll
        for (int i = 0; i < 2; ++i)
            #pragma unroll
            for (int n = 0; n < 6; ++n)
                acc[i][n] = (f32x4){0.f, 0.f, 0.f, 0.f};

        #pragma unroll
        for (int kc = 0; kc < 3; ++kc) {
            f16x8 af[2];
            #pragma unroll
            for (int i = 0; i < 2; ++i)
                af[i] = *(const f16x8*)&vb[(size_t)(cbase + i * 16 + l15) * 9216 + kc * 32 + l4 * 8];
            f16x8 Bp[6];
            #pragma unroll
            for (int n = 0; n < 6; ++n)
                Bp[n] = *(const f16x8*)&satt[kc][tidx(n * 16 + l15, l4)];
            #pragma unroll
            for (int i = 0; i < 2; ++i)
                #pragma unroll
                for (int n = 0; n < 6; ++n)
                    acc[i][n] = __builtin_amdgcn_mfma_f32_16x16x32_f16(af[i], Bp[n], acc[i][n], 0, 0, 0);
        }

        #pragma unroll
        for (int i = 0; i < 2; ++i)
            #pragma unroll
            for (int r4 = 0; r4 < 4; ++r4) {
                int cl = cbase + i * 16 + l4 * 4 + r4;
                size_t rowb = ((size_t)b * C + cl) * 9216 + r * 96;
                #pragma unroll
                for (int n = 0; n < 6; ++n) {
                    int s = n * 16 + l15;
                    if (OUT16) dstH[rowb + s] = (_Float16)acc[i][n][r4];
                    else       dstF[rowb + s] = acc[i][n][r4];
                }
            }
    }
}

// ---------------------------------------------------------------------------
__global__ __launch_bounds__(256) void transpose_f16(
    const _Float16* __restrict__ src, _Float16* __restrict__ dst)
{
    size_t base = (size_t)blockIdx.x * (96 * 96);
    __shared__ _Float16 t[96][97];
    int tid = threadIdx.x;
    for (int i = tid; i < 96 * 96; i += 256) t[i / 96][i % 96] = src[base + i];
    __syncthreads();
    for (int i = tid; i < 96 * 96; i += 256) dst[base + i] = t[i % 96][i / 96];
}

__global__ __launch_bounds__(256) void transpose_add(
    const _Float16* __restrict__ srcT, float* __restrict__ out)
{
    size_t base = (size_t)blockIdx.x * (96 * 96);
    __shared__ _Float16 t[96][97];
    int tid = threadIdx.x;
    for (int i = tid; i < 96 * 96; i += 256) t[i / 96][i % 96] = srcT[base + i];
    __syncthreads();
    for (int i = tid; i < 96 * 96; i += 256) out[base + i] += (float)t[i % 96][i / 96];
}

// out = w16 + transpose(hT)  (single write, no RMW)
__global__ __launch_bounds__(256) void combine(
    const _Float16* __restrict__ w16, const _Float16* __restrict__ hT,
    float* __restrict__ out)
{
    size_t base = (size_t)blockIdx.x * (96 * 96);
    __shared__ _Float16 t[96][97];
    int tid = threadIdx.x;
    for (int i = tid; i < 96 * 96; i += 256) t[i / 96][i % 96] = hT[base + i];
    __syncthreads();
    for (int i = tid; i < 96 * 96; i += 256)
        out[base + i] = (float)w16[base + i] + (float)t[i % 96][i / 96];
}

// ---------------------------------------------------------------------------
extern "C" void kernel_launch(void* const* d_in, const int* in_sizes, int n_in,
                              void* d_out, int out_size, void* d_ws, size_t ws_size,
                              hipStream_t stream)
{
    const float* x     = (const float*)d_in[0];
    const float* Wq    = (const float*)d_in[1];
    const float* bq    = (const float*)d_in[2];
    const float* Wk    = (const float*)d_in[3];
    const float* bk    = (const float*)d_in[4];
    const float* Wv    = (const float*)d_in[5];
    const float* bv    = (const float*)d_in[6];
    const float* gamma = (const float*)d_in[7];
    float* out = (float*)d_out;

    // Region plan (245.37 MB total, proven budget):
    // R1 75.5MB: xhT            -> vB (after gemm_v)
    // R2 75.5MB: xlT            -> vA (after gemm_qk) -> outHT (after agg_W)
    // R3 37.7MB: q/k hi-lo      -> ms (after energy)
    // R4 28.3MB: W splits       -> EH (after gemms)
    // R5 28.3MB: EW
    const size_t NK = (size_t)B * NSP * KD;        // 37.75M elems
    _Float16* xhT = (_Float16*)d_ws;                         // R1
    _Float16* xlT = xhT + NK;                                // R2
    _Float16* qh  = xlT + NK;                                // R3
    _Float16* ql  = qh + (size_t)B * HW * 64;
    _Float16* kh  = ql + (size_t)B * HW * 64;
    _Float16* kl  = kh + (size_t)B * HW * 64;
    float* EHp = (float*)(kl + (size_t)B * HW * 64);         // R4
    float* EWp = EHp + (size_t)B * HW * 96;                  // R5
    float* ms  = (float*)qh;                                 // R3 after energies
    _Float16* vA  = xlT;                                     // R2 after gemm_qk
    _Float16* vB  = xhT;                                     // R1 after gemm_v
    _Float16* outHT = xlT;                                   // R2 after agg_W

    _Float16* Wv_h  = (_Float16*)EHp;                        // R4 until energies
    _Float16* Wqk_h = Wv_h + (size_t)C * C;
    _Float16* Wqk_l = Wqk_h + (size_t)128 * C;

    const size_t NEED = 245366784ull;
    bool bigws = ws_size >= NEED + NK * sizeof(_Float16);
    _Float16* outW16 = (_Float16*)((char*)d_ws + NEED);      // only if bigws

    dim3 blk(256);

    split_w<<<dim3((C*C + 255)/256), blk, 0, stream>>>(Wv, Wq, Wk, Wv_h, Wqk_h, Wqk_l);
    split_x<<<dim3(NSP/64, KD/64, B), blk, 0, stream>>>(x, xhT, xlT);

    // qk first (consumes xlT), then v (overwrites xlT slot with vA)
    gemm_qk<<<dim3(NSP/128, 1, B), blk, 0, stream>>>(xhT, xlT, Wqk_h, Wqk_l, bq, bk, qh, ql, kh, kl);
    gemm_v<<<dim3(NSP/128, C/128, B), blk, 0, stream>>>(xhT, Wv_h, bv, vA);

    energy_mfma<<<dim3(96, B), blk, 0, stream>>>(qh, ql, kh, kl, EWp, 96, 1);
    energy_mfma<<<dim3(96, B), blk, 0, stream>>>(qh, ql, kh, kl, EHp, 1, 96);

    maxsum<<<dim3(B*HW/4), blk, 0, stream>>>(EWp, EHp, gamma, ms);

    // vB = transpose(vA) (vA in R2, vB overwrites xhT in R1 — xhT dead now)
    transpose_f16<<<dim3(B*C), blk, 0, stream>>>(vA, vB);

    if (bigws) {
        agg_mfma<1><<<dim3(96, B), blk, 0, stream>>>(EWp, ms, vA, nullptr, outW16, 0);
        agg_mfma<1><<<dim3(96, B), blk, 0, stream>>>(EHp, ms, vB, nullptr, outHT, 1);
        combine<<<dim3(B*C), blk, 0, stream>>>(outW16, outHT, out);
    } else {
        agg_mfma<0><<<dim3(96, B), blk, 0, stream>>>(EWp, ms, vA, out, nullptr, 0);
        agg_mfma<1><<<dim3(96, B), blk, 0, stream>>>(EHp, ms, vB, nullptr, outHT, 1);
        transpose_add<<<dim3(B*C), blk, 0, stream>>>(outHT, out);
    }
}

// Round 9
// 378.230 us; speedup vs baseline: 5.2401x; 1.0103x over previous
//
#include <hip/hip_runtime.h>

#define B 8
#define C 512
#define H 96
#define W 96
#define HW (H*W)       // 9216
#define KD 512
#define NSP 9216

typedef __attribute__((ext_vector_type(4))) float f32x4;
typedef __attribute__((ext_vector_type(8))) _Float16 f16x8;

// global -> LDS async copy, 16B per lane.
typedef __attribute__((address_space(3))) unsigned int lds_u32;
typedef const __attribute__((address_space(1))) unsigned int glb_u32;
static __device__ __forceinline__ void gload16(const void* gsrc, void* ldst) {
    __builtin_amdgcn_global_load_lds((glb_u32*)gsrc, (lds_u32*)ldst, 16, 0, 0);
}

// swizzle for [rows][32-elem] tiles (64B rows, 4 granules of 8) — agg satt only
static __device__ __forceinline__ int tidx(int row, int kgrp) {
    return row * 32 + ((kgrp ^ ((row >> 2) & 3)) << 3);
}
// swizzle for [rows][64-elem] tiles (128B rows, 8 granules) — energy kernel
static __device__ __forceinline__ int tidx64(int row, int gr) {
    return row * 64 + ((gr ^ (row & 7)) << 3);
}

// ---------------------------------------------------------------------------
// Split weights to fp16: Wv single; Wqk = [Wq;Wk] hi/lo pairs.
// ---------------------------------------------------------------------------
__global__ __launch_bounds__(256) void split_w(
    const float* __restrict__ Wv, const float* __restrict__ Wq, const float* __restrict__ Wk,
    _Float16* __restrict__ Wv_h,
    _Float16* __restrict__ Wqk_h, _Float16* __restrict__ Wqk_l)
{
    int i = blockIdx.x * 256 + threadIdx.x;
    if (i < C * C) Wv_h[i] = (_Float16)Wv[i];
    if (i < 128 * C) {
        int m = i / C, k = i % C;
        float f = (m < 64) ? Wq[m * C + k] : Wk[(m - 64) * C + k];
        _Float16 h = (_Float16)f;
        Wqk_h[i] = h;
        Wqk_l[i] = (_Float16)(f - (float)h);
    }
}

// ---------------------------------------------------------------------------
// Global transpose+split of x: (B,K,N) fp32 -> xhT/xlT (B,N,K) fp16.
// float4 reads; scalar LDS stores/column reads are conflict-free (65-pad).
// ---------------------------------------------------------------------------
__global__ __launch_bounds__(256) void split_x(
    const float* __restrict__ x,
    _Float16* __restrict__ xhT, _Float16* __restrict__ xlT)
{
    __shared__ float t[64][65];
    int n0 = blockIdx.x * 64, k0 = blockIdx.y * 64, b = blockIdx.z;
    int tid = threadIdx.x;
    const float* xb = x + ((size_t)b * KD + k0) * NSP + n0;
    #pragma unroll
    for (int it = 0; it < 4; ++it) {
        int idx = tid + it * 256;           // 1024 quads: (kr, nq)
        int kr = idx >> 4, nq = idx & 15;
        float4 v = *(const float4*)&xb[(size_t)kr * NSP + nq * 4];
        t[kr][nq * 4 + 0] = v.x;
        t[kr][nq * 4 + 1] = v.y;
        t[kr][nq * 4 + 2] = v.z;
        t[kr][nq * 4 + 3] = v.w;
    }
    __syncthreads();
    #pragma unroll
    for (int it = 0; it < 2; ++it) {
        int gid = tid + it * 256;          // 512 granules: n row, k-granule
        int n = gid >> 3, g = gid & 7;
        f16x8 hi, lo;
        #pragma unroll
        for (int u = 0; u < 8; ++u) {
            float f = t[g * 8 + u][n];
            _Float16 hh = (_Float16)f;
            hi[u] = hh;
            lo[u] = (_Float16)(f - (float)hh);
        }
        size_t off = ((size_t)b * NSP + n0 + n) * KD + k0 + g * 8;
        *(f16x8*)&xhT[off] = hi;
        *(f16x8*)&xlT[off] = lo;
    }
}

// ---------------------------------------------------------------------------
// v projection: single-pass fp16 MFMA GEMM (fp32 accum), gload_lds staging.
// ---------------------------------------------------------------------------
__global__ __launch_bounds__(256, 2) void gemm_v(
    const _Float16* __restrict__ xhT,
    const _Float16* __restrict__ Wh,
    const float* __restrict__ bias,
    _Float16* __restrict__ out16)
{
    __shared__ _Float16 smem[8192];     // [W 128x32 | X 128x32] = 16 KB, linear
    const int W_OFF = 0, X_OFF = 4096;

    int tid = threadIdx.x;
    int n0 = blockIdx.x * 128, m0 = blockIdx.y * 128, b = blockIdx.z;
    int lane = tid & 63, wave = tid >> 6;
    int wr = wave >> 1, wc = wave & 1;
    int l15 = lane & 15, l4 = lane >> 4;

    int grow = tid >> 2, gcol = (tid & 3) * 8;
    const _Float16* pW = Wh + (size_t)(m0 + grow) * KD + gcol;
    const _Float16* pX = xhT + ((size_t)b * NSP + n0 + grow) * KD + gcol;
    const size_t half = (size_t)64 * KD;
    int ldsW0 = W_OFF + wave * 512;
    int ldsW1 = W_OFF + 2048 + wave * 512;
    int ldsX0 = X_OFF + wave * 512;
    int ldsX1 = X_OFF + 2048 + wave * 512;

    f32x4 acc[4][4];
    #pragma unroll
    for (int i = 0; i < 4; ++i)
        #pragma unroll
        for (int j = 0; j < 4; ++j)
            acc[i][j] = (f32x4){0.f, 0.f, 0.f, 0.f};

    for (int k0 = 0; k0 < KD; k0 += 32) {
        gload16(pW + k0,        &smem[ldsW0]);
        gload16(pW + half + k0, &smem[ldsW1]);
        gload16(pX + k0,        &smem[ldsX0]);
        gload16(pX + half + k0, &smem[ldsX1]);
        __syncthreads();

        f16x8 af[4], bf[4];
        #pragma unroll
        for (int f = 0; f < 4; ++f) {
            af[f] = *(const f16x8*)&smem[W_OFF + (wr * 64 + f * 16 + l15) * 32 + l4 * 8];
            bf[f] = *(const f16x8*)&smem[X_OFF + (wc * 64 + f * 16 + l15) * 32 + l4 * 8];
        }
        #pragma unroll
        for (int i = 0; i < 4; ++i)
            #pragma unroll
            for (int j = 0; j < 4; ++j)
                acc[i][j] = __builtin_amdgcn_mfma_f32_16x16x32_f16(af[i], bf[j], acc[i][j], 0, 0, 0);
        __syncthreads();
    }

    #pragma unroll
    for (int i = 0; i < 4; ++i)
        #pragma unroll
        for (int r = 0; r < 4; ++r) {
            int row = m0 + wr * 64 + i * 16 + l4 * 4 + r;
            float bv = bias[row];
            #pragma unroll
            for (int j = 0; j < 4; ++j) {
                int col = n0 + wc * 64 + j * 16 + l15;
                out16[((size_t)b * C + row) * NSP + col] = (_Float16)(acc[i][j][r] + bv);
            }
        }
}

// ---------------------------------------------------------------------------
// q/k projection: 3-pass fp16 (Ah*Bh + Ah*Bl + Al*Bh).
// ---------------------------------------------------------------------------
__global__ __launch_bounds__(256, 2) void gemm_qk(
    const _Float16* __restrict__ xhT, const _Float16* __restrict__ xlT,
    const _Float16* __restrict__ Wqh, const _Float16* __restrict__ Wql,
    const float* __restrict__ bias0, const float* __restrict__ bias1,
    _Float16* __restrict__ qh, _Float16* __restrict__ ql,
    _Float16* __restrict__ kh, _Float16* __restrict__ kl)
{
    __shared__ _Float16 smem[16384];    // [XH|XL|WH|WL] each 128x32 = 32 KB
    const int XH = 0, XL = 4096, WHo = 8192, WLo = 12288;

    int tid = threadIdx.x;
    int n0 = blockIdx.x * 128, b = blockIdx.z;
    int lane = tid & 63, wave = tid >> 6;
    int wr = wave >> 1, wc = wave & 1;
    int l15 = lane & 15, l4 = lane >> 4;

    int grow = tid >> 2, gcol = (tid & 3) * 8;
    const _Float16* pXh = xhT + ((size_t)b * NSP + n0 + grow) * KD + gcol;
    const _Float16* pXl = xlT + ((size_t)b * NSP + n0 + grow) * KD + gcol;
    const _Float16* pWh = Wqh + (size_t)grow * KD + gcol;
    const _Float16* pWl = Wql + (size_t)grow * KD + gcol;
    const size_t half = (size_t)64 * KD;
    int base0 = wave * 512, base1 = 2048 + wave * 512;

    f32x4 acc[4][4];
    #pragma unroll
    for (int i = 0; i < 4; ++i)
        #pragma unroll
        for (int j = 0; j < 4; ++j)
            acc[i][j] = (f32x4){0.f, 0.f, 0.f, 0.f};

    for (int k0 = 0; k0 < KD; k0 += 32) {
        gload16(pXh + k0,        &smem[XH + base0]);
        gload16(pXh + half + k0, &smem[XH + base1]);
        gload16(pXl + k0,        &smem[XL + base0]);
        gload16(pXl + half + k0, &smem[XL + base1]);
        gload16(pWh + k0,        &smem[WHo + base0]);
        gload16(pWh + half + k0, &smem[WHo + base1]);
        gload16(pWl + k0,        &smem[WLo + base0]);
        gload16(pWl + half + k0, &smem[WLo + base1]);
        __syncthreads();

        f16x8 axh[4], axl[4], bwh[4], bwl[4];
        #pragma unroll
        for (int f = 0; f < 4; ++f) {
            int ra = (wr * 64 + f * 16 + l15) * 32 + l4 * 8;
            int rb = (wc * 64 + f * 16 + l15) * 32 + l4 * 8;
            axh[f] = *(const f16x8*)&smem[XH + ra];
            axl[f] = *(const f16x8*)&smem[XL + ra];
            bwh[f] = *(const f16x8*)&smem[WHo + rb];
            bwl[f] = *(const f16x8*)&smem[WLo + rb];
        }
        #pragma unroll
        for (int i = 0; i < 4; ++i)
            #pragma unroll
            for (int j = 0; j < 4; ++j)
                acc[i][j] = __builtin_amdgcn_mfma_f32_16x16x32_f16(axh[i], bwh[j], acc[i][j], 0, 0, 0);
        #pragma unroll
        for (int i = 0; i < 4; ++i)
            #pragma unroll
            for (int j = 0; j < 4; ++j)
                acc[i][j] = __builtin_amdgcn_mfma_f32_16x16x32_f16(axh[i], bwl[j], acc[i][j], 0, 0, 0);
        #pragma unroll
        for (int i = 0; i < 4; ++i)
            #pragma unroll
            for (int j = 0; j < 4; ++j)
                acc[i][j] = __builtin_amdgcn_mfma_f32_16x16x32_f16(axl[i], bwh[j], acc[i][j], 0, 0, 0);
        __syncthreads();
    }

    #pragma unroll
    for (int i = 0; i < 4; ++i)
        #pragma unroll
        for (int r = 0; r < 4; ++r) {
            int sp = n0 + wr * 64 + i * 16 + l4 * 4 + r;
            #pragma unroll
            for (int j = 0; j < 4; ++j) {
                int wcol = wc * 64 + j * 16 + l15;
                float val = acc[i][j][r] + (wcol < 64 ? bias0[wcol] : bias1[wcol - 64]);
                _Float16 hi = (_Float16)val;
                _Float16 lo = (_Float16)(val - (float)hi);
                size_t off = ((size_t)b * NSP + sp) * 64 + (wcol & 63);
                if (wcol < 64) { qh[off] = hi; ql[off] = lo; }
                else           { kh[off] = hi; kl[off] = lo; }
            }
        }
}

// ---------------------------------------------------------------------------
// Energy MFMA: 3-pass fp16 + FUSED per-row (max, sum-exp) partials.
// Block (p,b) owns full rows -> exact row stats, written to part[].
// ---------------------------------------------------------------------------
__global__ __launch_bounds__(256, 2) void energy_mfma(
    const _Float16* __restrict__ qh, const _Float16* __restrict__ ql,
    const _Float16* __restrict__ kh, const _Float16* __restrict__ kl,
    float* __restrict__ out, float* __restrict__ part, int pMul, int rMul)
{
    __shared__ _Float16 sm[4 * 96 * 64];   // 48 KB
    const int T_QH = 0, T_QL = 6144, T_KH = 12288, T_KL = 18432;
    int p = blockIdx.x, b = blockIdx.y;
    int tid = threadIdx.x;
    size_t base = ((size_t)b * HW + (size_t)p * pMul) * 64;
    size_t rstride = (size_t)rMul * 64;

    #pragma unroll
    for (int tile = 0; tile < 4; ++tile) {
        const _Float16* src = (tile == 0) ? qh : (tile == 1) ? ql : (tile == 2) ? kh : kl;
        int tb = tile * 6144;
        #pragma unroll
        for (int sub = 0; sub < 3; ++sub) {
            int s = sub * 256 + tid;
            int row = s >> 3, g = s & 7;
            f16x8 d = *(const f16x8*)&src[base + row * rstride + g * 8];
            *(f16x8*)&sm[tb + tidx64(row, g)] = d;
        }
    }
    __syncthreads();

    int lane = tid & 63, wave = tid >> 6;
    int wr = wave >> 1, wc = wave & 1;
    int l15 = lane & 15, l4 = lane >> 4;

    f32x4 acc[3][3];
    #pragma unroll
    for (int i = 0; i < 3; ++i)
        #pragma unroll
        for (int j = 0; j < 3; ++j)
            acc[i][j] = (f32x4){0.f, 0.f, 0.f, 0.f};

    #pragma unroll
    for (int ks = 0; ks < 2; ++ks) {
        f16x8 Ah[3], Al[3], Bh[3], Bl[3];
        int gr = ks * 4 + l4;
        #pragma unroll
        for (int i = 0; i < 3; ++i) {
            int sa = tidx64(wr * 48 + i * 16 + l15, gr);
            Ah[i] = *(const f16x8*)&sm[T_QH + sa];
            Al[i] = *(const f16x8*)&sm[T_QL + sa];
            int sb = tidx64(wc * 48 + i * 16 + l15, gr);
            Bh[i] = *(const f16x8*)&sm[T_KH + sb];
            Bl[i] = *(const f16x8*)&sm[T_KL + sb];
        }
        #pragma unroll
        for (int i = 0; i < 3; ++i)
            #pragma unroll
            for (int j = 0; j < 3; ++j) {
                acc[i][j] = __builtin_amdgcn_mfma_f32_16x16x32_f16(Ah[i], Bh[j], acc[i][j], 0, 0, 0);
                acc[i][j] = __builtin_amdgcn_mfma_f32_16x16x32_f16(Ah[i], Bl[j], acc[i][j], 0, 0, 0);
                acc[i][j] = __builtin_amdgcn_mfma_f32_16x16x32_f16(Al[i], Bh[j], acc[i][j], 0, 0, 0);
            }
    }

    // ---- write E ----
    size_t ob = (size_t)(b * 96 + p) * 9216;
    #pragma unroll
    for (int i = 0; i < 3; ++i)
        #pragma unroll
        for (int r = 0; r < 4; ++r) {
            int row = wr * 48 + i * 16 + l4 * 4 + r;
            #pragma unroll
            for (int j = 0; j < 3; ++j)
                out[ob + (size_t)row * 96 + wc * 48 + j * 16 + l15] = acc[i][j][r];
        }

    // ---- fused per-row (max, sum-exp) ----
    __syncthreads();                    // all fragment ds_reads done -> reuse sm
    float* scr = (float*)sm;            // 96 rows x [mW0,s0,m1,s1]
    #pragma unroll
    for (int i = 0; i < 3; ++i)
        #pragma unroll
        for (int r = 0; r < 4; ++r) {
            int row = wr * 48 + i * 16 + l4 * 4 + r;
            float m3 = fmaxf(fmaxf(acc[i][0][r], acc[i][1][r]), acc[i][2][r]);
            #pragma unroll
            for (int mk = 1; mk < 16; mk <<= 1) m3 = fmaxf(m3, __shfl_xor(m3, mk));
            float s = __expf(acc[i][0][r] - m3) + __expf(acc[i][1][r] - m3) + __expf(acc[i][2][r] - m3);
            #pragma unroll
            for (int mk = 1; mk < 16; mk <<= 1) s += __shfl_xor(s, mk);
            if (l15 == 0) {
                scr[row * 4 + wc * 2]     = m3;
                scr[row * 4 + wc * 2 + 1] = s;
            }
        }
    __syncthreads();
    if (tid < 96) {
        float m0 = scr[tid * 4], s0 = scr[tid * 4 + 1];
        float m1 = scr[tid * 4 + 2], s1 = scr[tid * 4 + 3];
        float M = fmaxf(m0, m1);
        float S = s0 * __expf(m0 - M) + s1 * __expf(m1 - M);
        size_t idx = (pMul == 96) ? ((size_t)b * HW + p * 96 + tid)
                                  : ((size_t)b * HW + tid * 96 + p);
        part[idx * 2]     = M;
        part[idx * 2 + 1] = S;
    }
}

// ---------------------------------------------------------------------------
// Combine W/H partial stats -> ms (max, gamma/sum) per row. Tiny.
// ---------------------------------------------------------------------------
__global__ __launch_bounds__(256) void combine_ms(
    const float* __restrict__ pW, const float* __restrict__ pH,
    const float* __restrict__ gamma, float* __restrict__ ms)
{
    int row = blockIdx.x * 256 + threadIdx.x;
    float mW = pW[row * 2], sW = pW[row * 2 + 1];
    float mH = pH[row * 2], sH = pH[row * 2 + 1];
    float M = fmaxf(mW, mH);
    float S = sW * __expf(mW - M) + sH * __expf(mH - M);
    ms[row * 2]     = M;
    ms[row * 2 + 1] = gamma[0] / S;
}

// ---------------------------------------------------------------------------
// MFMA aggregation: P staged once, v direct-from-global.
// ---------------------------------------------------------------------------
template<int OUT16>
__global__ __launch_bounds__(256) void agg_mfma(
    const float* __restrict__ E, const float* __restrict__ ms,
    const _Float16* __restrict__ v16,
    float* __restrict__ dstF, _Float16* __restrict__ dstH, int msMode)
{
    __shared__ _Float16 satt[3][96 * 32];   // 18 KB

    int r = blockIdx.x, b = blockIdx.y;
    int tid = threadIdx.x;
    int lane = tid & 63, wave = tid >> 6;
    int l15 = lane & 15, l4 = lane >> 4;

    const float* Eb = &E[(size_t)(b * 96 + r) * 9216];
    int msBase = b * HW;
    #pragma unroll
    for (int it = 0; it < 5; ++it) {
        int g_id = tid + it * 256;
        if (g_id < 1152) {
            int s = g_id / 12, gj = g_id % 12;
            int mi = msMode ? (msBase + s * 96 + r) : (msBase + r * 96 + s);
            float m  = ms[(size_t)mi * 2];
            float sc = ms[(size_t)mi * 2 + 1];
            float4 e0 = *(const float4*)&Eb[s * 96 + gj * 8];
            float4 e1 = *(const float4*)&Eb[s * 96 + gj * 8 + 4];
            float pv[8] = {e0.x, e0.y, e0.z, e0.w, e1.x, e1.y, e1.z, e1.w};
            f16x8 ph;
            #pragma unroll
            for (int u = 0; u < 8; ++u)
                ph[u] = (_Float16)(__expf(pv[u] - m) * sc);
            *(f16x8*)&satt[gj >> 2][tidx(s, gj & 3)] = ph;
        }
    }
    __syncthreads();

    const _Float16* vb = v16 + (size_t)b * C * 9216 + r * 96;

    for (int cc = 0; cc < 4; ++cc) {
        int cbase = cc * 128 + wave * 32;
        f32x4 acc[2][6];
        #pragma unroll
        for (int i = 0; i < 2; ++i)
            #pragma unroll
            for (int n = 0; n < 6; ++n)
                acc[i][n] = (f32x4){0.f, 0.f, 0.f, 0.f};

        #pragma unroll
        for (int kc = 0; kc < 3; ++kc) {
            f16x8 af[2];
            #pragma unroll
            for (int i = 0; i < 2; ++i)
                af[i] = *(const f16x8*)&vb[(size_t)(cbase + i * 16 + l15) * 9216 + kc * 32 + l4 * 8];
            f16x8 Bp[6];
            #pragma unroll
            for (int n = 0; n < 6; ++n)
                Bp[n] = *(const f16x8*)&satt[kc][tidx(n * 16 + l15, l4)];
            #pragma unroll
            for (int i = 0; i < 2; ++i)
                #pragma unroll
                for (int n = 0; n < 6; ++n)
                    acc[i][n] = __builtin_amdgcn_mfma_f32_16x16x32_f16(af[i], Bp[n], acc[i][n], 0, 0, 0);
        }

        #pragma unroll
        for (int i = 0; i < 2; ++i)
            #pragma unroll
            for (int r4 = 0; r4 < 4; ++r4) {
                int cl = cbase + i * 16 + l4 * 4 + r4;
                size_t rowb = ((size_t)b * C + cl) * 9216 + r * 96;
                #pragma unroll
                for (int n = 0; n < 6; ++n) {
                    int s = n * 16 + l15;
                    if (OUT16) dstH[rowb + s] = (_Float16)acc[i][n][r4];
                    else       dstF[rowb + s] = acc[i][n][r4];
                }
            }
    }
}

// ---------------------------------------------------------------------------
__global__ __launch_bounds__(256) void transpose_f16(
    const _Float16* __restrict__ src, _Float16* __restrict__ dst)
{
    size_t base = (size_t)blockIdx.x * (96 * 96);
    __shared__ _Float16 t[96][97];
    int tid = threadIdx.x;
    for (int i = tid; i < 96 * 96; i += 256) t[i / 96][i % 96] = src[base + i];
    __syncthreads();
    for (int i = tid; i < 96 * 96; i += 256) dst[base + i] = t[i % 96][i / 96];
}

__global__ __launch_bounds__(256) void transpose_add(
    const _Float16* __restrict__ srcT, float* __restrict__ out)
{
    size_t base = (size_t)blockIdx.x * (96 * 96);
    __shared__ _Float16 t[96][97];
    int tid = threadIdx.x;
    for (int i = tid; i < 96 * 96; i += 256) t[i / 96][i % 96] = srcT[base + i];
    __syncthreads();
    for (int i = tid; i < 96 * 96; i += 256) out[base + i] += (float)t[i % 96][i / 96];
}

// out = w16 + transpose(hT)  (single write, no RMW)
__global__ __launch_bounds__(256) void combine(
    const _Float16* __restrict__ w16, const _Float16* __restrict__ hT,
    float* __restrict__ out)
{
    size_t base = (size_t)blockIdx.x * (96 * 96);
    __shared__ _Float16 t[96][97];
    int tid = threadIdx.x;
    for (int i = tid; i < 96 * 96; i += 256) t[i / 96][i % 96] = hT[base + i];
    __syncthreads();
    for (int i = tid; i < 96 * 96; i += 256)
        out[base + i] = (float)w16[base + i] + (float)t[i % 96][i / 96];
}

// ---------------------------------------------------------------------------
extern "C" void kernel_launch(void* const* d_in, const int* in_sizes, int n_in,
                              void* d_out, int out_size, void* d_ws, size_t ws_size,
                              hipStream_t stream)
{
    const float* x     = (const float*)d_in[0];
    const float* Wq    = (const float*)d_in[1];
    const float* bq    = (const float*)d_in[2];
    const float* Wk    = (const float*)d_in[3];
    const float* bk    = (const float*)d_in[4];
    const float* Wv    = (const float*)d_in[5];
    const float* bv    = (const float*)d_in[6];
    const float* gamma = (const float*)d_in[7];
    float* out = (float*)d_out;

    // Region plan (245.37 MB):
    // R1 75.5MB: xhT -> pW/pH (during energies) -> vB (after combine_ms)
    // R2 75.5MB: xlT -> vA (gemm_v out) -> outHT (after agg_W)
    // R3 37.7MB: q/k hi-lo -> ms (after energies)
    // R4 28.3MB: W splits -> EH
    // R5 28.3MB: EW
    const size_t NK = (size_t)B * NSP * KD;
    _Float16* xhT = (_Float16*)d_ws;                         // R1
    _Float16* xlT = xhT + NK;                                // R2
    _Float16* qh  = xlT + NK;                                // R3
    _Float16* ql  = qh + (size_t)B * HW * 64;
    _Float16* kh  = ql + (size_t)B * HW * 64;
    _Float16* kl  = kh + (size_t)B * HW * 64;
    float* EHp = (float*)(kl + (size_t)B * HW * 64);         // R4
    float* EWp = EHp + (size_t)B * HW * 96;                  // R5
    float* ms  = (float*)qh;                                 // R3 after energies
    _Float16* vA  = xlT;                                     // R2 after gemm_v
    _Float16* vB  = xhT;                                     // R1 after combine_ms
    _Float16* outHT = xlT;                                   // R2 after agg_W
    float* pW = (float*)xhT;                                 // R1 during energies
    float* pH = pW + (size_t)2 * B * HW;

    _Float16* Wv_h  = (_Float16*)EHp;                        // R4 until energies
    _Float16* Wqk_h = Wv_h + (size_t)C * C;
    _Float16* Wqk_l = Wqk_h + (size_t)128 * C;

    const size_t NEED = 245366784ull;
    bool bigws = ws_size >= NEED + NK * sizeof(_Float16);
    _Float16* outW16 = (_Float16*)((char*)d_ws + NEED);      // only if bigws

    dim3 blk(256);

    split_w<<<dim3((C*C + 255)/256), blk, 0, stream>>>(Wv, Wq, Wk, Wv_h, Wqk_h, Wqk_l);
    split_x<<<dim3(NSP/64, KD/64, B), blk, 0, stream>>>(x, xhT, xlT);

    // qk first (consumes xlT), then v (overwrites xlT slot with vA)
    gemm_qk<<<dim3(NSP/128, 1, B), blk, 0, stream>>>(xhT, xlT, Wqk_h, Wqk_l, bq, bk, qh, ql, kh, kl);
    gemm_v<<<dim3(NSP/128, C/128, B), blk, 0, stream>>>(xhT, Wv_h, bv, vA);

    // energies + fused row stats (partials land in dead R1)
    energy_mfma<<<dim3(96, B), blk, 0, stream>>>(qh, ql, kh, kl, EWp, pW, 96, 1);
    energy_mfma<<<dim3(96, B), blk, 0, stream>>>(qh, ql, kh, kl, EHp, pH, 1, 96);
    combine_ms<<<dim3(B*HW/256), blk, 0, stream>>>(pW, pH, gamma, ms);

    // vB = transpose(vA) (overwrites R1 — partials consumed)
    transpose_f16<<<dim3(B*C), blk, 0, stream>>>(vA, vB);

    if (bigws) {
        agg_mfma<1><<<dim3(96, B), blk, 0, stream>>>(EWp, ms, vA, nullptr, outW16, 0);
        agg_mfma<1><<<dim3(96, B), blk, 0, stream>>>(EHp, ms, vB, nullptr, outHT, 1);
        combine<<<dim3(B*C), blk, 0, stream>>>(outW16, outHT, out);
    } else {
        agg_mfma<0><<<dim3(96, B), blk, 0, stream>>>(EWp, ms, vA, out, nullptr, 0);
        agg_mfma<1><<<dim3(96, B), blk, 0, stream>>>(EHp, ms, vB, nullptr, outHT, 1);
        transpose_add<<<dim3(B*C), blk, 0, stream>>>(outHT, out);
    }
}